// Round 1
// baseline (324.610 us; speedup 1.0000x reference)
//
#include <hip/hip_runtime.h>
#include <hip/hip_bf16.h>
#include <math.h>

#define BB 16
#define TT 512
#define NN 128
#define PREDN 256
#define DMC 32
#define LL 768
constexpr float EPSF = 1e-5f;
using bf16 = __hip_bfloat16;
using frag_ab = __attribute__((ext_vector_type(8))) short;   // 8 bf16
using frag_cd = __attribute__((ext_vector_type(4))) float;   // 4 f32

__device__ __forceinline__ unsigned pbf2(float a, float b){
  union { bf16 h; unsigned short u; } x, y;
  x.h = __float2bfloat16(a); y.h = __float2bfloat16(b);
  return (unsigned)x.u | ((unsigned)y.u << 16);
}

__device__ __forceinline__ unsigned short bf16b(float v){
  union { bf16 h; unsigned short u; } x;
  x.h = __float2bfloat16(v);
  return x.u;
}

__device__ __forceinline__ float gelu_fast(float s){
  float s2v = s*s;
  float e = exp2f(s*fmaf(s2v, 0.10294396f, 2.30211806f));
  return s*e*__builtin_amdgcn_rcpf(e + 1.f);
}

// ---------------- K_pre: stats partials + weight fold + conv weight transposes ----------------
__global__ void k_pre(const float* __restrict__ bx, const float* __restrict__ v0,
                      const float* __restrict__ v1, const float* __restrict__ w1c,
                      const float* __restrict__ w2c, float* __restrict__ sp,
                      float* __restrict__ s2p, float* __restrict__ vwsT,
                      float* __restrict__ wT1, float* __restrict__ wT2){
  int blk = blockIdx.x;
  if(blk < 64){
    int b = blk >> 2, tq = blk & 3, n = threadIdx.x;
    const float* p = bx + (size_t)b*TT*NN + (size_t)tq*128*NN + n;
    float s = 0.f, s2 = 0.f;
    for(int t=0;t<128;t++){ float v = p[(size_t)t*NN]; s += v; s2 += v*v; }
    sp[tq*2048 + b*NN + n] = s;
    s2p[tq*2048 + b*NN + n] = s2;
  } else if(blk == 64){
    for(int i=threadIdx.x; i<9*DMC; i+=blockDim.x){
      int tap = i/DMC, c = i%DMC;
      float wv = 0.5f*v1[c*9 + tap];
      if(tap == 4) wv += 0.5f*v0[c];
      vwsT[i] = wv;
    }
  } else if(blk <= 192){
    int o = blk - 65;
    for(int k=threadIdx.x; k<1536; k+=blockDim.x)
      wT1[(size_t)k*NN + o] = w1c[(size_t)o*1536 + k];
  } else {
    int o = blk - 193;
    for(int k=threadIdx.x; k<512; k+=blockDim.x)
      wT2[(size_t)k*NN + o] = w2c[(size_t)o*512 + k];
  }
}

// ---------------- K1: GEMM1 via bf16 MFMA 16x16x32, 64x64 tile, fused norm + dual store ----------------
__global__ __launch_bounds__(256) void k_gemm1(const float* __restrict__ bx, const float* __restrict__ lew,
    const float* __restrict__ leb, const float* __restrict__ sp, const float* __restrict__ s2p,
    float* __restrict__ x, float* __restrict__ a0){
  __shared__ unsigned Asu[64*20];
  __shared__ unsigned Bsu[64*20];
  int tid = threadIdx.x;
  int row0 = blockIdx.x*64, l0 = blockIdx.y*64;
  int b = row0 >> 7, n0 = row0 & 127;
  int lane = tid & 63, wv = tid >> 6;
  frag_cd acc[4] = {};
  int an = tid & 63, akq = (tid >> 6)*8;
  float mu_a, rs_a;
  {
    int rowa = row0 + an;
    float ssum = 0.f, s2sum = 0.f;
    #pragma unroll
    for(int tq=0;tq<4;tq++){ ssum += sp[tq*2048 + rowa]; s2sum += s2p[tq*2048 + rowa]; }
    mu_a = ssum*(1.f/512.f);
    rs_a = 1.f/sqrtf(fmaxf(s2sum*(1.f/512.f) - mu_a*mu_a, 0.f) + EPSF);
  }
  int btk = tid & 15, blc = tid >> 4;
  unsigned ra[4], rbq[4];
  #pragma unroll
  for(int u=0;u<4;u++){
    float v0 = (bx[((size_t)b*TT + akq + 2*u)*NN + n0 + an] - mu_a)*rs_a;
    float v1 = (bx[((size_t)b*TT + akq + 2*u + 1)*NN + n0 + an] - mu_a)*rs_a;
    ra[u] = pbf2(v0, v1);
    const float* lp = lew + (size_t)(l0 + blc + 16*u)*TT + 2*btk;
    rbq[u] = pbf2(lp[0], lp[1]);
  }
  int fr = wv*16 + (lane & 15);
  int fq = (lane >> 4)*4;
  for(int k0=0;k0<TT;k0+=32){
    *(uint4*)&Asu[an*20 + (akq>>1)] = make_uint4(ra[0], ra[1], ra[2], ra[3]);
    #pragma unroll
    for(int p=0;p<4;p++) Bsu[(blc + 16*p)*20 + btk] = rbq[p];
    __syncthreads();
    if(k0 + 32 < TT){
      #pragma unroll
      for(int u=0;u<4;u++){
        float v0 = (bx[((size_t)b*TT + k0 + 32 + akq + 2*u)*NN + n0 + an] - mu_a)*rs_a;
        float v1 = (bx[((size_t)b*TT + k0 + 32 + akq + 2*u + 1)*NN + n0 + an] - mu_a)*rs_a;
        ra[u] = pbf2(v0, v1);
        const float* lp = lew + (size_t)(l0 + blc + 16*u)*TT + k0 + 32 + 2*btk;
        rbq[u] = pbf2(lp[0], lp[1]);
      }
    }
    frag_ab af = *(const frag_ab*)&Asu[fr*20 + fq];
    #pragma unroll
    for(int nt=0;nt<4;nt++){
      frag_ab bf = *(const frag_ab*)&Bsu[(nt*16 + (lane & 15))*20 + fq];
      acc[nt] = __builtin_amdgcn_mfma_f32_16x16x32_bf16(af, bf, acc[nt], 0, 0, 0);
    }
    __syncthreads();
  }
  int col = lane & 15, quad = lane >> 4;
  #pragma unroll
  for(int nt=0;nt<4;nt++){
    int l = l0 + nt*16 + col;
    float lb = leb[l];
    #pragma unroll
    for(int r=0;r<4;r++){
      int m = wv*16 + quad*4 + r;
      x[(size_t)(row0 + m)*LL + l] = acc[nt][r] + lb;
    }
    float4 st;
    st.x = acc[nt][0] + lb;
    st.y = acc[nt][1] + lb;
    st.z = acc[nt][2] + lb;
    st.w = acc[nt][3] + lb;
    *(float4*)&a0[((size_t)b*LL + l)*NN + n0 + wv*16 + quad*4] = st;
  }
}

// ---------------- K3: conv1 (coalesced wT, 4 j per block) ----------------
__global__ __launch_bounds__(512) void k_conv1(const float* __restrict__ x, const float* __restrict__ wT,
                                               const float* __restrict__ bias, float* __restrict__ t1){
  __shared__ alignas(16) float xs[NN*48];
  int jt = blockIdx.x, b = blockIdx.y;
  int tid = threadIdx.x;
  int o = tid & 127, jj = tid >> 7;
  for(int i=tid;i<NN*48;i+=512){
    int ci = i/48, kk = i%48;
    xs[i] = x[((size_t)b*NN + ci)*LL + jt*48 + kk];
  }
  __syncthreads();
  float a0 = 0.f, a1 = 0.f, a2 = 0.f, a3 = 0.f;
  for(int ci=0;ci<NN;ci++){
    const float* xc = xs + ci*48 + jj*12;
    const float* wc = wT + (size_t)(ci*12)*NN + o;
    #pragma unroll
    for(int kk=0;kk<12;kk+=4){
      a0 = fmaf(xc[kk+0], wc[(size_t)(kk+0)*NN], a0);
      a1 = fmaf(xc[kk+1], wc[(size_t)(kk+1)*NN], a1);
      a2 = fmaf(xc[kk+2], wc[(size_t)(kk+2)*NN], a2);
      a3 = fmaf(xc[kk+3], wc[(size_t)(kk+3)*NN], a3);
    }
  }
  int j = jt*4 + jj;
  t1[((size_t)b*NN + o)*64 + j] = (a0 + a1) + (a2 + a3) + bias[o];
}

// ---------------- K4: BN stats per channel ----------------
__global__ void k_bnstats(const float* __restrict__ t, const float* __restrict__ g, const float* __restrict__ bb,
                          int Bcnt, int Jcnt, float* __restrict__ scale, float* __restrict__ shift){
  int o = blockIdx.x;
  int tot = Bcnt*Jcnt;
  float s = 0.f, s2 = 0.f;
  for(int i=threadIdx.x; i<tot; i+=blockDim.x){
    int b = i / Jcnt, j = i % Jcnt;
    float v = t[((size_t)b*NN + o)*Jcnt + j];
    s += v; s2 += v*v;
  }
  __shared__ float rs[256], rs2[256];
  rs[threadIdx.x] = s; rs2[threadIdx.x] = s2;
  __syncthreads();
  for(int st=128; st>0; st>>=1){
    if(threadIdx.x < st){ rs[threadIdx.x] += rs[threadIdx.x+st]; rs2[threadIdx.x] += rs2[threadIdx.x+st]; }
    __syncthreads();
  }
  if(threadIdx.x == 0){
    float mu = rs[0]/tot;
    float var = fmaxf(rs2[0]/tot - mu*mu, 0.f);
    float sc = g[o] * rsqrtf(var + EPSF);
    scale[o] = sc; shift[o] = bb[o] - mu*sc;
  }
}

// ---------------- K5: BN apply + ELU + transpose ----------------
__global__ void k_bnelu_t(const float* __restrict__ t, const float* __restrict__ scale,
                          const float* __restrict__ shift, int Jcnt, float* __restrict__ tt){
  int j = blockIdx.x, b = blockIdx.y, o = threadIdx.x;
  float v = t[((size_t)b*NN + o)*Jcnt + j]*scale[o] + shift[o];
  v = v > 0.f ? v : (expf(v) - 1.f);
  tt[((size_t)b*Jcnt + j)*NN + o] = v;
}

// ---------------- K6: spline tridiagonal solve (Thomas) ----------------
template<int LK>
__global__ void k_spline_solve(const float* __restrict__ y, float* __restrict__ M){
  constexpr int m = LK-2;
  const float Kc = 6.f*(LK-1)*(LK-1);
  __shared__ float cp[m];
  __shared__ float dp[m][NN];
  int b = blockIdx.x, c = threadIdx.x;
  if(c == 0){
    float cv = 0.25f; cp[0] = cv;
    for(int i=1;i<m;i++){ cv = 1.f/(4.f - cv); cp[i] = cv; }
  }
  __syncthreads();
  const float* yb = y + (size_t)b*LK*NN + c;
  float y0 = yb[0], y1 = yb[NN];
  float dprev = 0.f;
  for(int i=0;i<m;i++){
    float y2 = yb[(size_t)(i+2)*NN];
    float r = (y2 - 2.f*y1 + y0)*Kc;
    float d = (i == 0) ? r*0.25f : (r - dprev)*cp[i];
    dp[i][c] = d; dprev = d;
    y0 = y1; y1 = y2;
  }
  float* Mb = M + (size_t)b*LK*NN + c;
  float xv = dp[m-1][c];
  Mb[(size_t)m*NN] = xv;
  for(int i=m-2;i>=0;i--){
    xv = dp[i][c] - cp[i]*xv;
    Mb[(size_t)(i+1)*NN] = xv;
  }
  Mb[0] = 0.f;
  Mb[(size_t)(LK-1)*NN] = 0.f;
}

// ---------------- spline point evaluation (device) ----------------
__device__ __forceinline__ float spline_pt(const float* __restrict__ y, const float* __restrict__ M,
                                           int LK, int l, int b, int c){
  float hh = 1.f/(LK-1);
  float q = (float)l * (1.f/(LL-1));
  int idx = (int)floorf(q*(LK-1));
  if(idx > LK-2) idx = LK-2;
  float s = q - idx*hh;
  float u = hh - s;
  const float* yb = y + ((size_t)b*LK + idx)*NN + c;
  const float* Mb = M + ((size_t)b*LK + idx)*NN + c;
  float yi = yb[0], yi1 = yb[NN], M0 = Mb[0], M1 = Mb[NN];
  float hh6 = hh*hh/6.f;
  return (M0*u*u*u + M1*s*s*s)*(1.f/(6.f*hh))
       + (yi  - M0*hh6)*(u*(1.f/hh))
       + (yi1 - M1*hh6)*(s*(1.f/hh));
}

// ---------------- K8: conv2 (coalesced wT, 4 j per block) ----------------
__global__ __launch_bounds__(512) void k_conv2(const float* __restrict__ tt, const float* __restrict__ wT,
                                               const float* __restrict__ bias, float* __restrict__ t2){
  __shared__ alignas(16) float ts[16*NN];
  int jt = blockIdx.x, b = blockIdx.y;
  int tid = threadIdx.x;
  int o = tid & 127, jj = tid >> 7;
  for(int i=tid;i<16*NN;i+=512)
    ts[i] = tt[((size_t)b*64 + jt*16)*NN + i];
  __syncthreads();
  float a0 = 0.f, a1 = 0.f, a2 = 0.f, a3 = 0.f;
  for(int ci=0;ci<NN;ci++){
    const float* wc = wT + (size_t)(ci*4)*NN + o;
    const float* tc2 = ts + (jj*4)*NN + ci;
    a0 = fmaf(tc2[0*NN], wc[0*NN], a0);
    a1 = fmaf(tc2[1*NN], wc[1*NN], a1);
    a2 = fmaf(tc2[2*NN], wc[2*NN], a2);
    a3 = fmaf(tc2[3*NN], wc[3*NN], a3);
  }
  int j = jt*4 + jj;
  t2[((size_t)b*NN + o)*16 + j] = (a0 + a1) + (a2 + a3) + bias[o];
}

// ---------------- helpers for fused h1+h2 ----------------
__device__ __forceinline__ float2 bf2f2(unsigned u){
  float2 r;
  r.x = __uint_as_float(u << 16);
  r.y = __uint_as_float(u & 0xffff0000u);
  return r;
}

__device__ __forceinline__ void load6(float* w, const float* p, bool tail){
  float4 r4 = *(const float4*)p;
  w[0]=r4.x; w[1]=r4.y; w[2]=r4.z; w[3]=r4.w;
  if(!tail){
    float2 r2 = *(const float2*)(p+4);
    w[4]=r2.x; w[5]=r2.y;
  } else {
    w[4]=0.f; w[5]=0.f;
  }
}

// ---------------- K_h12: fused stage-1 conv + GELU (h1 in LDS, bf16) + stage-2 conv + residual ----------------
// Per block: 8x32 output tile of h2 (+ residual) -> co.
// Needs h1 tile 10x34 x 32ch, which needs a-tile 3ch x 12x36.
// Numerically identical to k_h1 -> h1g(bf16) -> k_h2: h1 rounded to bf16 before stage-2.
__global__ __launch_bounds__(256) void k_h12(const float* __restrict__ a0,
    const float* __restrict__ y64, const float* __restrict__ M64,
    const float* __restrict__ y16, const float* __restrict__ M16,
    const float* __restrict__ w0, const float* __restrict__ b0,
    const float* __restrict__ w1, const float* __restrict__ b1,
    const float* __restrict__ vwsT, const float* __restrict__ vb0,
    const float* __restrict__ vb1, float* __restrict__ co){
  constexpr int AR = 12, AC = 36;
  __shared__ alignas(16) float as[3][AR][AC];     // a-tile, rows l0-2..l0+9, cols n0-2..n0+33
  __shared__ unsigned h1s[10][34][17];            // h1 tile bf16-pairs, rows l0-1..l0+8, cols n0-1..n0+32
  int tid = threadIdx.x;
  int l0 = blockIdx.x*8, n0 = blockIdx.y*32, b = blockIdx.z;

  // ---- Phase A: stage a-tile (ch0 = a0, ch1/ch2 = spline evals) ----
  float* asf = &as[0][0][0];
  for(int i=tid; i<3*AR*AC; i+=256){
    int ch = i/(AR*AC), rem = i%(AR*AC), yy = rem/AC, xx = rem%AC;
    int gl = l0 + yy - 2, gn = n0 + xx - 2;
    float v = 0.f;
    if(gl >= 0 && gl < LL && gn >= 0 && gn < NN){
      if(ch == 0)      v = a0[((size_t)b*LL + gl)*NN + gn];
      else if(ch == 1) v = spline_pt(y64, M64, 64, gl, b, gn);
      else             v = spline_pt(y16, M16, 16, gl, b, gn);
    }
    asf[i] = v;
  }

  // ---- per-thread stage-1 weights (channel c) ----
  int c = tid & 31, qg = tid >> 5;
  float wr[3][3][3];
  #pragma unroll
  for(int ci=0;ci<3;ci++)
    #pragma unroll
    for(int dy=0;dy<3;dy++)
      #pragma unroll
      for(int dx=0;dx<3;dx++){
        float wv = 0.5f*w1[((c*3+ci)*3+dy)*3+dx];
        if(dy==1 && dx==1) wv += 0.5f*w0[c*3+ci];
        wr[ci][dy][dx] = wv;
      }
  float br = 0.5f*(b0[c] + b1[c]);
  __syncthreads();

  // ---- Phase B: h1 conv + GELU -> bf16 in LDS. Column groups of 4; group 8 (2 cols) on qg==0. ----
  unsigned short* h1h = (unsigned short*)&h1s[0][0][0];
  for(int xg = qg; xg < 9; xg += 8){
    int xx0 = xg*4;              // h1 col base, 0..32
    bool tail = (xg == 8);       // only cols 32,33 valid
    float win[3][3][6];          // [ch][row-slot ar%3][6 cols]
    #pragma unroll
    for(int ci=0;ci<3;ci++){
      load6(win[ci][0], &as[ci][0][xx0], tail);
      load6(win[ci][1], &as[ci][1][xx0], tail);
    }
    #pragma unroll
    for(int yy=0; yy<10; yy++){
      // slide: load a-row yy+2 into slot (yy+2)%3
      #pragma unroll
      for(int ci=0;ci<3;ci++)
        load6(win[ci][(yy+2)%3], &as[ci][yy+2][xx0], tail);
      int gl1 = l0 - 1 + yy;
      #pragma unroll
      for(int p=0;p<4;p++){
        int xx = xx0 + p;
        float s = br;
        #pragma unroll
        for(int ci=0;ci<3;ci++)
          #pragma unroll
          for(int dy=0;dy<3;dy++)
            #pragma unroll
            for(int dx=0;dx<3;dx++)
              s = fmaf(wr[ci][dy][dx], win[ci][(yy+dy)%3][p+dx], s);
        if(xx < 34){
          int gn1 = n0 - 1 + xx;
          bool ok = ((unsigned)gl1 < (unsigned)LL) && ((unsigned)gn1 < (unsigned)NN);
          unsigned short st = ok ? bf16b(gelu_fast(s)) : (unsigned short)0;
          h1h[(yy*34 + xx)*34 + c] = st;   // uint stride 17 -> ushort stride 34 per px
        }
      }
    }
  }
  __syncthreads();

  // ---- Phase C: stage-2 3x3x32 conv over LDS h1 + residual -> co ----
  int oy = tid >> 5, ox = tid & 31;
  float acc = 0.f;
  #pragma unroll
  for(int dy=0;dy<3;dy++)
    #pragma unroll
    for(int dx=0;dx<3;dx++){
      const unsigned* hp = &h1s[oy+dy][ox+dx][0];
      const float4* wt = (const float4*)(vwsT + (dy*3+dx)*DMC);
      #pragma unroll
      for(int cg=0;cg<8;cg++){
        unsigned u0 = hp[cg*2], u1 = hp[cg*2+1];
        float2 f0 = bf2f2(u0), f1 = bf2f2(u1);
        float4 wv = wt[cg];
        acc = fmaf(f0.x, wv.x, acc);
        acc = fmaf(f0.y, wv.y, acc);
        acc = fmaf(f1.x, wv.z, acc);
        acc = fmaf(f1.y, wv.w, acc);
      }
    }
  size_t idx = ((size_t)b*LL + l0 + oy)*NN + n0 + ox;
  co[idx] = acc + vb0[0] + vb1[0] + a0[idx];
}

// ---------------- K15: GEMM2 via bf16 MFMA 16x16x32, 64x64 tile + de-normalize ----------------
// A[m=(b,n)][k=l] = co[b][l][n], B[n'=p][k=l] = ldw[p][l]
__global__ __launch_bounds__(256) void k_gemm2(const float* __restrict__ a0, const float* __restrict__ ldw,
    const float* __restrict__ ldb, const float* __restrict__ sp, const float* __restrict__ s2p,
    float* __restrict__ out){
  __shared__ unsigned Asu[64*20];
  __shared__ unsigned Bsu[64*20];
  int tid = threadIdx.x;
  int row0 = blockIdx.x*64, p0 = blockIdx.y*64;
  int b = row0 >> 7, n0 = row0 & 127;
  int lane = tid & 63, wv = tid >> 6;
  frag_cd acc[4] = {};
  int an = tid & 63, akq = (tid >> 6)*8;
  int btk = tid & 15, blc = tid >> 4;
  unsigned ra[4], rbq[4];
  #pragma unroll
  for(int u=0;u<4;u++){
    float v0 = a0[((size_t)b*LL + akq + 2*u)*NN + n0 + an];
    float v1 = a0[((size_t)b*LL + akq + 2*u + 1)*NN + n0 + an];
    ra[u] = pbf2(v0, v1);
    const float* lp = ldw + (size_t)(p0 + blc + 16*u)*LL + 2*btk;
    rbq[u] = pbf2(lp[0], lp[1]);
  }
  int fr = wv*16 + (lane & 15);
  int fq = (lane >> 4)*4;
  for(int k0=0;k0<LL;k0+=32){
    *(uint4*)&Asu[an*20 + (akq>>1)] = make_uint4(ra[0], ra[1], ra[2], ra[3]);
    #pragma unroll
    for(int p=0;p<4;p++) Bsu[(blc + 16*p)*20 + btk] = rbq[p];
    __syncthreads();
    if(k0 + 32 < LL){
      #pragma unroll
      for(int u=0;u<4;u++){
        float v0 = a0[((size_t)b*LL + k0 + 32 + akq + 2*u)*NN + n0 + an];
        float v1 = a0[((size_t)b*LL + k0 + 32 + akq + 2*u + 1)*NN + n0 + an];
        ra[u] = pbf2(v0, v1);
        const float* lp = ldw + (size_t)(p0 + blc + 16*u)*LL + k0 + 32 + 2*btk;
        rbq[u] = pbf2(lp[0], lp[1]);
      }
    }
    frag_ab af = *(const frag_ab*)&Asu[fr*20 + fq];
    #pragma unroll
    for(int nt=0;nt<4;nt++){
      frag_ab bf = *(const frag_ab*)&Bsu[(nt*16 + (lane & 15))*20 + fq];
      acc[nt] = __builtin_amdgcn_mfma_f32_16x16x32_bf16(af, bf, acc[nt], 0, 0, 0);
    }
    __syncthreads();
  }
  int col = lane & 15, quad = lane >> 4;
  // de-norm constants for the 4 rows this lane owns
  float mu_r[4], sd_r[4];
  #pragma unroll
  for(int r=0;r<4;r++){
    int row = row0 + wv*16 + quad*4 + r;
    float ssum = 0.f, s2sum = 0.f;
    #pragma unroll
    for(int tq=0;tq<4;tq++){ ssum += sp[tq*2048 + row]; s2sum += s2p[tq*2048 + row]; }
    float mu = ssum*(1.f/512.f);
    float var = fmaxf(s2sum*(1.f/512.f) - mu*mu, 0.f);
    mu_r[r] = mu; sd_r[r] = sqrtf(var + EPSF);
  }
  #pragma unroll
  for(int nt=0;nt<4;nt++){
    int p = p0 + nt*16 + col;
    float lb = ldb[p];
    float4 st;
    st.x = (acc[nt][0] + lb)*sd_r[0] + mu_r[0];
    st.y = (acc[nt][1] + lb)*sd_r[1] + mu_r[1];
    st.z = (acc[nt][2] + lb)*sd_r[2] + mu_r[2];
    st.w = (acc[nt][3] + lb)*sd_r[3] + mu_r[3];
    *(float4*)&out[((size_t)b*PREDN + p)*NN + n0 + wv*16 + quad*4] = st;
  }
}

extern "C" void kernel_launch(void* const* d_in, const int* in_sizes, int n_in,
                              void* d_out, int out_size, void* d_ws, size_t ws_size,
                              hipStream_t stream){
  (void)in_sizes; (void)n_in; (void)out_size; (void)ws_size;
  const float* batch_x = (const float*)d_in[0];
  const float* le_w  = (const float*)d_in[4];
  const float* le_b  = (const float*)d_in[5];
  const float* c1_w  = (const float*)d_in[6];
  const float* c1_b  = (const float*)d_in[7];
  const float* bn1_g = (const float*)d_in[8];
  const float* bn1_b = (const float*)d_in[9];
  const float* c2_w  = (const float*)d_in[10];
  const float* c2_b  = (const float*)d_in[11];
  const float* bn2_g = (const float*)d_in[12];
  const float* bn2_b = (const float*)d_in[13];
  const float* i1_w0 = (const float*)d_in[14];
  const float* i1_b0 = (const float*)d_in[15];
  const float* i1_w1 = (const float*)d_in[16];
  const float* i1_b1 = (const float*)d_in[17];
  const float* i2_w0 = (const float*)d_in[18];
  const float* i2_b0 = (const float*)d_in[19];
  const float* i2_w1 = (const float*)d_in[20];
  const float* i2_b1 = (const float*)d_in[21];
  const float* ld_w  = (const float*)d_in[22];
  const float* ld_b  = (const float*)d_in[23];
  float* out = (float*)d_out;

  float* ws   = (float*)d_ws;
  float* sp   = ws;                        // 8192
  float* s2p  = sp + 8192;                 // 8192
  float* vwsT = s2p + 8192;                // 288 (+pad)
  float* wT1  = vwsT + 320;                // 196,608
  float* wT2  = wT1 + 196608;              // 65,536
  float* x    = wT2 + 65536;               // 1,572,864
  float* a0   = x + (size_t)BB*NN*LL;      // 1,572,864
  float* t1   = a0 + (size_t)BB*LL*NN;     // 131,072
  float* t1t  = t1 + (size_t)BB*NN*64;     // 131,072
  float* sc1  = t1t + (size_t)BB*64*NN;    // 128
  float* sh1  = sc1 + NN;                  // 128
  float* Msp1 = sh1 + NN;                  // 131,072
  float* t2   = Msp1 + (size_t)BB*64*NN;   // 32,768
  float* t2t  = t2 + (size_t)BB*NN*16;     // 32,768
  float* sc2  = t2t + (size_t)BB*16*NN;    // 128
  float* sh2  = sc2 + NN;                  // 128
  float* Msp2 = sh2 + NN;                  // 32,768
  float* co   = Msp2 + (size_t)BB*16*NN;   // 1,572,864 (h2 output + residual)

  k_pre<<<321, 128, 0, stream>>>(batch_x, i2_w0, i2_w1, c1_w, c2_w, sp, s2p, vwsT, wT1, wT2);
  k_gemm1<<<dim3(32,12), 256, 0, stream>>>(batch_x, le_w, le_b, sp, s2p, x, a0);
  k_conv1<<<dim3(16,BB), 512, 0, stream>>>(x, wT1, c1_b, t1);
  k_bnstats<<<NN, 256, 0, stream>>>(t1, bn1_g, bn1_b, BB, 64, sc1, sh1);
  k_bnelu_t<<<dim3(64,BB), NN, 0, stream>>>(t1, sc1, sh1, 64, t1t);
  k_spline_solve<64><<<BB, NN, 0, stream>>>(t1t, Msp1);
  k_conv2<<<dim3(4,BB), 512, 0, stream>>>(t1t, wT2, c2_b, t2);
  k_bnstats<<<NN, 256, 0, stream>>>(t2, bn2_g, bn2_b, BB, 16, sc2, sh2);
  k_bnelu_t<<<dim3(16,BB), NN, 0, stream>>>(t2, sc2, sh2, 16, t2t);
  k_spline_solve<16><<<BB, NN, 0, stream>>>(t2t, Msp2);
  k_h12<<<dim3(96,4,BB), 256, 0, stream>>>(a0, t1t, Msp1, t2t, Msp2,
                                           i1_w0, i1_b0, i1_w1, i1_b1,
                                           vwsT, i2_b0, i2_b1, co);
  k_gemm2<<<dim3(32,4), 256, 0, stream>>>(co, ld_w, ld_b, sp, s2p, out);
}

// Round 2
// 311.902 us; speedup vs baseline: 1.0407x; 1.0407x over previous
//
#include <hip/hip_runtime.h>
#include <hip/hip_bf16.h>
#include <math.h>

#define BB 16
#define TT 512
#define NN 128
#define PREDN 256
#define DMC 32
#define LL 768
constexpr float EPSF = 1e-5f;
using bf16 = __hip_bfloat16;
using frag_ab = __attribute__((ext_vector_type(8))) short;   // 8 bf16
using frag_cd = __attribute__((ext_vector_type(4))) float;   // 4 f32

__device__ __forceinline__ unsigned pbf2(float a, float b){
  union { bf16 h; unsigned short u; } x, y;
  x.h = __float2bfloat16(a); y.h = __float2bfloat16(b);
  return (unsigned)x.u | ((unsigned)y.u << 16);
}

__device__ __forceinline__ unsigned short bf16b(float v){
  union { bf16 h; unsigned short u; } x;
  x.h = __float2bfloat16(v);
  return x.u;
}

__device__ __forceinline__ float gelu_fast(float s){
  float s2v = s*s;
  float e = exp2f(s*fmaf(s2v, 0.10294396f, 2.30211806f));
  return s*e*__builtin_amdgcn_rcpf(e + 1.f);
}

// ---------------- K_pre: stats partials + weight fold + conv weight transposes ----------------
__global__ void k_pre(const float* __restrict__ bx, const float* __restrict__ v0,
                      const float* __restrict__ v1, const float* __restrict__ w1c,
                      const float* __restrict__ w2c, float* __restrict__ sp,
                      float* __restrict__ s2p, float* __restrict__ vwsT,
                      float* __restrict__ wT1, float* __restrict__ wT2){
  int blk = blockIdx.x;
  if(blk < 64){
    int b = blk >> 2, tq = blk & 3, n = threadIdx.x;
    const float* p = bx + (size_t)b*TT*NN + (size_t)tq*128*NN + n;
    float s = 0.f, s2 = 0.f;
    for(int t=0;t<128;t++){ float v = p[(size_t)t*NN]; s += v; s2 += v*v; }
    sp[tq*2048 + b*NN + n] = s;
    s2p[tq*2048 + b*NN + n] = s2;
  } else if(blk == 64){
    for(int i=threadIdx.x; i<9*DMC; i+=blockDim.x){
      int tap = i/DMC, c = i%DMC;
      float wv = 0.5f*v1[c*9 + tap];
      if(tap == 4) wv += 0.5f*v0[c];
      vwsT[i] = wv;
    }
  } else if(blk <= 192){
    int o = blk - 65;
    for(int k=threadIdx.x; k<1536; k+=blockDim.x)
      wT1[(size_t)k*NN + o] = w1c[(size_t)o*1536 + k];
  } else {
    int o = blk - 193;
    for(int k=threadIdx.x; k<512; k+=blockDim.x)
      wT2[(size_t)k*NN + o] = w2c[(size_t)o*512 + k];
  }
}

// ---------------- K1: GEMM1 via bf16 MFMA 16x16x32, 64x64 tile, fused norm + dual store ----------------
__global__ __launch_bounds__(256) void k_gemm1(const float* __restrict__ bx, const float* __restrict__ lew,
    const float* __restrict__ leb, const float* __restrict__ sp, const float* __restrict__ s2p,
    float* __restrict__ x, float* __restrict__ a0){
  __shared__ unsigned Asu[64*20];
  __shared__ unsigned Bsu[64*20];
  int tid = threadIdx.x;
  int row0 = blockIdx.x*64, l0 = blockIdx.y*64;
  int b = row0 >> 7, n0 = row0 & 127;
  int lane = tid & 63, wv = tid >> 6;
  frag_cd acc[4] = {};
  int an = tid & 63, akq = (tid >> 6)*8;
  float mu_a, rs_a;
  {
    int rowa = row0 + an;
    float ssum = 0.f, s2sum = 0.f;
    #pragma unroll
    for(int tq=0;tq<4;tq++){ ssum += sp[tq*2048 + rowa]; s2sum += s2p[tq*2048 + rowa]; }
    mu_a = ssum*(1.f/512.f);
    rs_a = 1.f/sqrtf(fmaxf(s2sum*(1.f/512.f) - mu_a*mu_a, 0.f) + EPSF);
  }
  int btk = tid & 15, blc = tid >> 4;
  unsigned ra[4], rbq[4];
  #pragma unroll
  for(int u=0;u<4;u++){
    float v0 = (bx[((size_t)b*TT + akq + 2*u)*NN + n0 + an] - mu_a)*rs_a;
    float v1 = (bx[((size_t)b*TT + akq + 2*u + 1)*NN + n0 + an] - mu_a)*rs_a;
    ra[u] = pbf2(v0, v1);
    const float* lp = lew + (size_t)(l0 + blc + 16*u)*TT + 2*btk;
    rbq[u] = pbf2(lp[0], lp[1]);
  }
  int fr = wv*16 + (lane & 15);
  int fq = (lane >> 4)*4;
  for(int k0=0;k0<TT;k0+=32){
    *(uint4*)&Asu[an*20 + (akq>>1)] = make_uint4(ra[0], ra[1], ra[2], ra[3]);
    #pragma unroll
    for(int p=0;p<4;p++) Bsu[(blc + 16*p)*20 + btk] = rbq[p];
    __syncthreads();
    if(k0 + 32 < TT){
      #pragma unroll
      for(int u=0;u<4;u++){
        float v0 = (bx[((size_t)b*TT + k0 + 32 + akq + 2*u)*NN + n0 + an] - mu_a)*rs_a;
        float v1 = (bx[((size_t)b*TT + k0 + 32 + akq + 2*u + 1)*NN + n0 + an] - mu_a)*rs_a;
        ra[u] = pbf2(v0, v1);
        const float* lp = lew + (size_t)(l0 + blc + 16*u)*TT + k0 + 32 + 2*btk;
        rbq[u] = pbf2(lp[0], lp[1]);
      }
    }
    frag_ab af = *(const frag_ab*)&Asu[fr*20 + fq];
    #pragma unroll
    for(int nt=0;nt<4;nt++){
      frag_ab bf = *(const frag_ab*)&Bsu[(nt*16 + (lane & 15))*20 + fq];
      acc[nt] = __builtin_amdgcn_mfma_f32_16x16x32_bf16(af, bf, acc[nt], 0, 0, 0);
    }
    __syncthreads();
  }
  int col = lane & 15, quad = lane >> 4;
  #pragma unroll
  for(int nt=0;nt<4;nt++){
    int l = l0 + nt*16 + col;
    float lb = leb[l];
    #pragma unroll
    for(int r=0;r<4;r++){
      int m = wv*16 + quad*4 + r;
      x[(size_t)(row0 + m)*LL + l] = acc[nt][r] + lb;
    }
    float4 st;
    st.x = acc[nt][0] + lb;
    st.y = acc[nt][1] + lb;
    st.z = acc[nt][2] + lb;
    st.w = acc[nt][3] + lb;
    *(float4*)&a0[((size_t)b*LL + l)*NN + n0 + wv*16 + quad*4] = st;
  }
}

// ---------------- K3: conv1 (coalesced wT, 4 j per block) ----------------
__global__ __launch_bounds__(512) void k_conv1(const float* __restrict__ x, const float* __restrict__ wT,
                                               const float* __restrict__ bias, float* __restrict__ t1){
  __shared__ alignas(16) float xs[NN*48];
  int jt = blockIdx.x, b = blockIdx.y;
  int tid = threadIdx.x;
  int o = tid & 127, jj = tid >> 7;
  for(int i=tid;i<NN*48;i+=512){
    int ci = i/48, kk = i%48;
    xs[i] = x[((size_t)b*NN + ci)*LL + jt*48 + kk];
  }
  __syncthreads();
  float a0 = 0.f, a1 = 0.f, a2 = 0.f, a3 = 0.f;
  for(int ci=0;ci<NN;ci++){
    const float* xc = xs + ci*48 + jj*12;
    const float* wc = wT + (size_t)(ci*12)*NN + o;
    #pragma unroll
    for(int kk=0;kk<12;kk+=4){
      a0 = fmaf(xc[kk+0], wc[(size_t)(kk+0)*NN], a0);
      a1 = fmaf(xc[kk+1], wc[(size_t)(kk+1)*NN], a1);
      a2 = fmaf(xc[kk+2], wc[(size_t)(kk+2)*NN], a2);
      a3 = fmaf(xc[kk+3], wc[(size_t)(kk+3)*NN], a3);
    }
  }
  int j = jt*4 + jj;
  t1[((size_t)b*NN + o)*64 + j] = (a0 + a1) + (a2 + a3) + bias[o];
}

// ---------------- K4: BN stats per channel ----------------
__global__ void k_bnstats(const float* __restrict__ t, const float* __restrict__ g, const float* __restrict__ bb,
                          int Bcnt, int Jcnt, float* __restrict__ scale, float* __restrict__ shift){
  int o = blockIdx.x;
  int tot = Bcnt*Jcnt;
  float s = 0.f, s2 = 0.f;
  for(int i=threadIdx.x; i<tot; i+=blockDim.x){
    int b = i / Jcnt, j = i % Jcnt;
    float v = t[((size_t)b*NN + o)*Jcnt + j];
    s += v; s2 += v*v;
  }
  __shared__ float rs[256], rs2[256];
  rs[threadIdx.x] = s; rs2[threadIdx.x] = s2;
  __syncthreads();
  for(int st=128; st>0; st>>=1){
    if(threadIdx.x < st){ rs[threadIdx.x] += rs[threadIdx.x+st]; rs2[threadIdx.x] += rs2[threadIdx.x+st]; }
    __syncthreads();
  }
  if(threadIdx.x == 0){
    float mu = rs[0]/tot;
    float var = fmaxf(rs2[0]/tot - mu*mu, 0.f);
    float sc = g[o] * rsqrtf(var + EPSF);
    scale[o] = sc; shift[o] = bb[o] - mu*sc;
  }
}

// ---------------- K5: BN apply + ELU + transpose ----------------
__global__ void k_bnelu_t(const float* __restrict__ t, const float* __restrict__ scale,
                          const float* __restrict__ shift, int Jcnt, float* __restrict__ tt){
  int j = blockIdx.x, b = blockIdx.y, o = threadIdx.x;
  float v = t[((size_t)b*NN + o)*Jcnt + j]*scale[o] + shift[o];
  v = v > 0.f ? v : (expf(v) - 1.f);
  tt[((size_t)b*Jcnt + j)*NN + o] = v;
}

// ---------------- K6: spline tridiagonal solve (Thomas) ----------------
template<int LK>
__global__ void k_spline_solve(const float* __restrict__ y, float* __restrict__ M){
  constexpr int m = LK-2;
  const float Kc = 6.f*(LK-1)*(LK-1);
  __shared__ float cp[m];
  __shared__ float dp[m][NN];
  int b = blockIdx.x, c = threadIdx.x;
  if(c == 0){
    float cv = 0.25f; cp[0] = cv;
    for(int i=1;i<m;i++){ cv = 1.f/(4.f - cv); cp[i] = cv; }
  }
  __syncthreads();
  const float* yb = y + (size_t)b*LK*NN + c;
  float y0 = yb[0], y1 = yb[NN];
  float dprev = 0.f;
  for(int i=0;i<m;i++){
    float y2 = yb[(size_t)(i+2)*NN];
    float r = (y2 - 2.f*y1 + y0)*Kc;
    float d = (i == 0) ? r*0.25f : (r - dprev)*cp[i];
    dp[i][c] = d; dprev = d;
    y0 = y1; y1 = y2;
  }
  float* Mb = M + (size_t)b*LK*NN + c;
  float xv = dp[m-1][c];
  Mb[(size_t)m*NN] = xv;
  for(int i=m-2;i>=0;i--){
    xv = dp[i][c] - cp[i]*xv;
    Mb[(size_t)(i+1)*NN] = xv;
  }
  Mb[0] = 0.f;
  Mb[(size_t)(LK-1)*NN] = 0.f;
}

// ---------------- spline point evaluation (device) ----------------
__device__ __forceinline__ float spline_pt(const float* __restrict__ y, const float* __restrict__ M,
                                           int LK, int l, int b, int c){
  float hh = 1.f/(LK-1);
  float q = (float)l * (1.f/(LL-1));
  int idx = (int)floorf(q*(LK-1));
  if(idx > LK-2) idx = LK-2;
  float s = q - idx*hh;
  float u = hh - s;
  const float* yb = y + ((size_t)b*LK + idx)*NN + c;
  const float* Mb = M + ((size_t)b*LK + idx)*NN + c;
  float yi = yb[0], yi1 = yb[NN], M0 = Mb[0], M1 = Mb[NN];
  float hh6 = hh*hh/6.f;
  return (M0*u*u*u + M1*s*s*s)*(1.f/(6.f*hh))
       + (yi  - M0*hh6)*(u*(1.f/hh))
       + (yi1 - M1*hh6)*(s*(1.f/hh));
}

// ---------------- K8: conv2 (coalesced wT, 4 j per block) ----------------
__global__ __launch_bounds__(512) void k_conv2(const float* __restrict__ tt, const float* __restrict__ wT,
                                               const float* __restrict__ bias, float* __restrict__ t2){
  __shared__ alignas(16) float ts[16*NN];
  int jt = blockIdx.x, b = blockIdx.y;
  int tid = threadIdx.x;
  int o = tid & 127, jj = tid >> 7;
  for(int i=tid;i<16*NN;i+=512)
    ts[i] = tt[((size_t)b*64 + jt*16)*NN + i];
  __syncthreads();
  float a0 = 0.f, a1 = 0.f, a2 = 0.f, a3 = 0.f;
  for(int ci=0;ci<NN;ci++){
    const float* wc = wT + (size_t)(ci*4)*NN + o;
    const float* tc2 = ts + (jj*4)*NN + ci;
    a0 = fmaf(tc2[0*NN], wc[0*NN], a0);
    a1 = fmaf(tc2[1*NN], wc[1*NN], a1);
    a2 = fmaf(tc2[2*NN], wc[2*NN], a2);
    a3 = fmaf(tc2[3*NN], wc[3*NN], a3);
  }
  int j = jt*4 + jj;
  t2[((size_t)b*NN + o)*16 + j] = (a0 + a1) + (a2 + a3) + bias[o];
}

// ---------------- helpers for fused h1+h2 ----------------
__device__ __forceinline__ float2 bf2f2(unsigned u){
  float2 r;
  r.x = __uint_as_float(u << 16);
  r.y = __uint_as_float(u & 0xffff0000u);
  return r;
}

// tap offset table for im2col: k = ci*9 + dy*3 + dx -> offset into as[3][12][36]
constexpr int KOFF[27] = {
    0,   1,   2,  36,  37,  38,  72,  73,  74,
  432, 433, 434, 468, 469, 470, 504, 505, 506,
  864, 865, 866, 900, 901, 902, 936, 937, 938
};

// ---------------- K_h12: fused stage-1 conv (MFMA im2col) + GELU + stage-2 conv + residual ----------------
// Per block: 8x32 output tile of h2 (+ residual) -> co.
// h1 tile = 10x34 px (340, padded to 352 = 22 m-tiles), 32 ch. a-tile 3ch x 12x36.
// Stage-1: h1[px][c] = gelu( patch[px][k<=27] x W[k][c] ) via mfma 16x16x32 (K zero-padded to 32).
// A-buffer rows (stride 20 uints) are reused: im2col bf16 patches in, gelu'd bf16 h1 out (per-wave
// disjoint m-tiles => no cross-wave aliasing).
__global__ __launch_bounds__(256) void k_h12(const float* __restrict__ a0,
    const float* __restrict__ y64, const float* __restrict__ M64,
    const float* __restrict__ y16, const float* __restrict__ M16,
    const float* __restrict__ w0, const float* __restrict__ b0,
    const float* __restrict__ w1, const float* __restrict__ b1,
    const float* __restrict__ vwsT, const float* __restrict__ vb0,
    const float* __restrict__ vb1, float* __restrict__ co){
  constexpr int AR = 12, AC = 36;
  __shared__ alignas(16) float as[3][AR][AC];     // a-tile, rows l0-2..l0+9, cols n0-2..n0+33
  __shared__ alignas(16) unsigned Au[352*20];     // im2col A then h1 (bf16 pairs), stride 20 uints
  int tid = threadIdx.x;
  int l0 = blockIdx.x*8, n0 = blockIdx.y*32, b = blockIdx.z;
  int lane = tid & 63, wv = tid >> 6;

  // ---- Phase A: stage a-tile (ch0 = a0, ch1/ch2 = spline evals) ----
  float* asf = &as[0][0][0];
  for(int i=tid; i<3*AR*AC; i+=256){
    int ch = i/(AR*AC), rem = i%(AR*AC), yy = rem/AC, xx = rem%AC;
    int gl = l0 + yy - 2, gn = n0 + xx - 2;
    float v = 0.f;
    if(gl >= 0 && gl < LL && gn >= 0 && gn < NN){
      if(ch == 0)      v = a0[((size_t)b*LL + gl)*NN + gn];
      else if(ch == 1) v = spline_pt(y64, M64, 64, gl, b, gn);
      else             v = spline_pt(y16, M16, 16, gl, b, gn);
    }
    asf[i] = v;
  }

  // ---- stage-1 weight B-fragments (bias folded separately): B[c][k], k = ci*9+dy*3+dx, pad k>=27 = 0 ----
  int colB = lane & 15, kq = (lane >> 4)*8;
  union { uint4 q; frag_ab f; } bw0, bw1;
  {
    float w8[2][8];
    #pragma unroll
    for(int nt=0;nt<2;nt++){
      #pragma unroll
      for(int j=0;j<8;j++){
        int k = kq + j;
        float w = 0.f;
        if(k < 27){
          int ci = k/9, r9 = k - ci*9, dy = r9/3, dx = r9 - dy*3;
          int c = nt*16 + colB;
          w = 0.5f*w1[((c*3+ci)*3+dy)*3+dx];
          if(dy==1 && dx==1) w += 0.5f*w0[c*3+ci];
        }
        w8[nt][j] = w;
      }
    }
    bw0.q = make_uint4(pbf2(w8[0][0],w8[0][1]), pbf2(w8[0][2],w8[0][3]),
                       pbf2(w8[0][4],w8[0][5]), pbf2(w8[0][6],w8[0][7]));
    bw1.q = make_uint4(pbf2(w8[1][0],w8[1][1]), pbf2(w8[1][2],w8[1][3]),
                       pbf2(w8[1][4],w8[1][5]), pbf2(w8[1][6],w8[1][7]));
  }
  float br = 0.5f*(b0[lane & 31] + b1[lane & 31]);  // bias for ch = lane&31 (used post-MFMA; ch = nt*16+colB)
  float br0 = 0.5f*(b0[colB] + b1[colB]);
  float br1 = 0.5f*(b0[16 + colB] + b1[16 + colB]);
  (void)br;
  __syncthreads();

  // ---- Phase B1: im2col build A[px][32k] bf16 (2 threads per px, 8 uints each) ----
  for(int base=0; base<352; base+=128){
    int px = base + (tid >> 1);
    int half = tid & 1;
    if(px < 352){
      uint4 oA, oB;
      if(px < 340){
        int yy = px/34, xx = px - yy*34;
        const float* bp = asf + yy*AC + xx;
        if(half == 0){
          oA.x = pbf2(bp[KOFF[0]],  bp[KOFF[1]]);
          oA.y = pbf2(bp[KOFF[2]],  bp[KOFF[3]]);
          oA.z = pbf2(bp[KOFF[4]],  bp[KOFF[5]]);
          oA.w = pbf2(bp[KOFF[6]],  bp[KOFF[7]]);
          oB.x = pbf2(bp[KOFF[8]],  bp[KOFF[9]]);
          oB.y = pbf2(bp[KOFF[10]], bp[KOFF[11]]);
          oB.z = pbf2(bp[KOFF[12]], bp[KOFF[13]]);
          oB.w = pbf2(bp[KOFF[14]], bp[KOFF[15]]);
        } else {
          oA.x = pbf2(bp[KOFF[16]], bp[KOFF[17]]);
          oA.y = pbf2(bp[KOFF[18]], bp[KOFF[19]]);
          oA.z = pbf2(bp[KOFF[20]], bp[KOFF[21]]);
          oA.w = pbf2(bp[KOFF[22]], bp[KOFF[23]]);
          oB.x = pbf2(bp[KOFF[24]], bp[KOFF[25]]);
          oB.y = pbf2(bp[KOFF[26]], 0.f);
          oB.z = 0u; oB.w = 0u;
        }
      } else {
        oA = make_uint4(0u,0u,0u,0u);
        oB = make_uint4(0u,0u,0u,0u);
      }
      *(uint4*)&Au[px*20 + half*8]     = oA;
      *(uint4*)&Au[px*20 + half*8 + 4] = oB;
    }
  }
  __syncthreads();

  // ---- Phase B2: MFMA per m-tile, gelu, pack bf16 back into same rows ----
  unsigned short* h1h = (unsigned short*)Au;
  frag_cd zac = {0.f, 0.f, 0.f, 0.f};
  for(int t = wv; t < 22; t += 4){
    int arow = t*16 + colB;
    union { uint4 q; frag_ab f; } av;
    av.q = *(const uint4*)&Au[arow*20 + (lane>>4)*4];
    frag_cd d0 = __builtin_amdgcn_mfma_f32_16x16x32_bf16(av.f, bw0.f, zac, 0, 0, 0);
    frag_cd d1 = __builtin_amdgcn_mfma_f32_16x16x32_bf16(av.f, bw1.f, zac, 0, 0, 0);
    int px0 = t*16 + (lane>>4)*4;
    #pragma unroll
    for(int r=0;r<4;r++){
      int px = px0 + r;
      h1h[px*40 + colB]      = bf16b(gelu_fast(d0[r] + br0));
      h1h[px*40 + 16 + colB] = bf16b(gelu_fast(d1[r] + br1));
    }
  }
  __syncthreads();

  // ---- Phase B3: zero h1 at invalid borders (conv zero-padding semantics of stage 2) ----
  if(n0 == 0){
    for(int i=tid;i<10*32;i+=256){ int yy=i>>5, ch=i&31; h1h[(yy*34)*40 + ch] = 0; }
  }
  if(n0 == 96){
    for(int i=tid;i<10*32;i+=256){ int yy=i>>5, ch=i&31; h1h[(yy*34+33)*40 + ch] = 0; }
  }
  if(l0 == 0){
    for(int i=tid;i<34*32;i+=256){ int xx=i>>5, ch=i&31; h1h[xx*40 + ch] = 0; }
  }
  if(l0 == 760){
    for(int i=tid;i<34*32;i+=256){ int xx=i>>5, ch=i&31; h1h[(9*34+xx)*40 + ch] = 0; }
  }
  __syncthreads();

  // ---- Phase C: stage-2 3x3x32 conv over LDS h1 + residual -> co ----
  int oy = tid >> 5, ox = tid & 31;
  float acc = 0.f;
  #pragma unroll
  for(int dy=0;dy<3;dy++)
    #pragma unroll
    for(int dx=0;dx<3;dx++){
      const unsigned* hp = &Au[((oy+dy)*34 + (ox+dx))*20];
      const float4* wt = (const float4*)(vwsT + (dy*3+dx)*DMC);
      #pragma unroll
      for(int g=0; g<4; g++){
        uint4 q = *(const uint4*)(hp + g*4);
        float4 wa = wt[g*2], wb = wt[g*2+1];
        float2 f0 = bf2f2(q.x), f1 = bf2f2(q.y), f2 = bf2f2(q.z), f3 = bf2f2(q.w);
        acc = fmaf(f0.x, wa.x, acc); acc = fmaf(f0.y, wa.y, acc);
        acc = fmaf(f1.x, wa.z, acc); acc = fmaf(f1.y, wa.w, acc);
        acc = fmaf(f2.x, wb.x, acc); acc = fmaf(f2.y, wb.y, acc);
        acc = fmaf(f3.x, wb.z, acc); acc = fmaf(f3.y, wb.w, acc);
      }
    }
  float res = as[0][oy+2][ox+2];
  size_t idx = ((size_t)b*LL + l0 + oy)*NN + n0 + ox;
  co[idx] = acc + vb0[0] + vb1[0] + res;
}

// ---------------- K15: GEMM2 via bf16 MFMA 16x16x32, 64x64 tile + de-normalize ----------------
// A[m=(b,n)][k=l] = co[b][l][n], B[n'=p][k=l] = ldw[p][l]
__global__ __launch_bounds__(256) void k_gemm2(const float* __restrict__ a0, const float* __restrict__ ldw,
    const float* __restrict__ ldb, const float* __restrict__ sp, const float* __restrict__ s2p,
    float* __restrict__ out){
  __shared__ unsigned Asu[64*20];
  __shared__ unsigned Bsu[64*20];
  int tid = threadIdx.x;
  int row0 = blockIdx.x*64, p0 = blockIdx.y*64;
  int b = row0 >> 7, n0 = row0 & 127;
  int lane = tid & 63, wv = tid >> 6;
  frag_cd acc[4] = {};
  int an = tid & 63, akq = (tid >> 6)*8;
  int btk = tid & 15, blc = tid >> 4;
  unsigned ra[4], rbq[4];
  #pragma unroll
  for(int u=0;u<4;u++){
    float v0 = a0[((size_t)b*LL + akq + 2*u)*NN + n0 + an];
    float v1 = a0[((size_t)b*LL + akq + 2*u + 1)*NN + n0 + an];
    ra[u] = pbf2(v0, v1);
    const float* lp = ldw + (size_t)(p0 + blc + 16*u)*LL + 2*btk;
    rbq[u] = pbf2(lp[0], lp[1]);
  }
  int fr = wv*16 + (lane & 15);
  int fq = (lane >> 4)*4;
  for(int k0=0;k0<LL;k0+=32){
    *(uint4*)&Asu[an*20 + (akq>>1)] = make_uint4(ra[0], ra[1], ra[2], ra[3]);
    #pragma unroll
    for(int p=0;p<4;p++) Bsu[(blc + 16*p)*20 + btk] = rbq[p];
    __syncthreads();
    if(k0 + 32 < LL){
      #pragma unroll
      for(int u=0;u<4;u++){
        float v0 = a0[((size_t)b*LL + k0 + 32 + akq + 2*u)*NN + n0 + an];
        float v1 = a0[((size_t)b*LL + k0 + 32 + akq + 2*u + 1)*NN + n0 + an];
        ra[u] = pbf2(v0, v1);
        const float* lp = ldw + (size_t)(p0 + blc + 16*u)*LL + k0 + 32 + 2*btk;
        rbq[u] = pbf2(lp[0], lp[1]);
      }
    }
    frag_ab af = *(const frag_ab*)&Asu[fr*20 + fq];
    #pragma unroll
    for(int nt=0;nt<4;nt++){
      frag_ab bf = *(const frag_ab*)&Bsu[(nt*16 + (lane & 15))*20 + fq];
      acc[nt] = __builtin_amdgcn_mfma_f32_16x16x32_bf16(af, bf, acc[nt], 0, 0, 0);
    }
    __syncthreads();
  }
  int col = lane & 15, quad = lane >> 4;
  // de-norm constants for the 4 rows this lane owns
  float mu_r[4], sd_r[4];
  #pragma unroll
  for(int r=0;r<4;r++){
    int row = row0 + wv*16 + quad*4 + r;
    float ssum = 0.f, s2sum = 0.f;
    #pragma unroll
    for(int tq=0;tq<4;tq++){ ssum += sp[tq*2048 + row]; s2sum += s2p[tq*2048 + row]; }
    float mu = ssum*(1.f/512.f);
    float var = fmaxf(s2sum*(1.f/512.f) - mu*mu, 0.f);
    mu_r[r] = mu; sd_r[r] = sqrtf(var + EPSF);
  }
  #pragma unroll
  for(int nt=0;nt<4;nt++){
    int p = p0 + nt*16 + col;
    float lb = ldb[p];
    float4 st;
    st.x = (acc[nt][0] + lb)*sd_r[0] + mu_r[0];
    st.y = (acc[nt][1] + lb)*sd_r[1] + mu_r[1];
    st.z = (acc[nt][2] + lb)*sd_r[2] + mu_r[2];
    st.w = (acc[nt][3] + lb)*sd_r[3] + mu_r[3];
    *(float4*)&out[((size_t)b*PREDN + p)*NN + n0 + wv*16 + quad*4] = st;
  }
}

extern "C" void kernel_launch(void* const* d_in, const int* in_sizes, int n_in,
                              void* d_out, int out_size, void* d_ws, size_t ws_size,
                              hipStream_t stream){
  (void)in_sizes; (void)n_in; (void)out_size; (void)ws_size;
  const float* batch_x = (const float*)d_in[0];
  const float* le_w  = (const float*)d_in[4];
  const float* le_b  = (const float*)d_in[5];
  const float* c1_w  = (const float*)d_in[6];
  const float* c1_b  = (const float*)d_in[7];
  const float* bn1_g = (const float*)d_in[8];
  const float* bn1_b = (const float*)d_in[9];
  const float* c2_w  = (const float*)d_in[10];
  const float* c2_b  = (const float*)d_in[11];
  const float* bn2_g = (const float*)d_in[12];
  const float* bn2_b = (const float*)d_in[13];
  const float* i1_w0 = (const float*)d_in[14];
  const float* i1_b0 = (const float*)d_in[15];
  const float* i1_w1 = (const float*)d_in[16];
  const float* i1_b1 = (const float*)d_in[17];
  const float* i2_w0 = (const float*)d_in[18];
  const float* i2_b0 = (const float*)d_in[19];
  const float* i2_w1 = (const float*)d_in[20];
  const float* i2_b1 = (const float*)d_in[21];
  const float* ld_w  = (const float*)d_in[22];
  const float* ld_b  = (const float*)d_in[23];
  float* out = (float*)d_out;

  float* ws   = (float*)d_ws;
  float* sp   = ws;                        // 8192
  float* s2p  = sp + 8192;                 // 8192
  float* vwsT = s2p + 8192;                // 288 (+pad)
  float* wT1  = vwsT + 320;                // 196,608
  float* wT2  = wT1 + 196608;              // 65,536
  float* x    = wT2 + 65536;               // 1,572,864
  float* a0   = x + (size_t)BB*NN*LL;      // 1,572,864
  float* t1   = a0 + (size_t)BB*LL*NN;     // 131,072
  float* t1t  = t1 + (size_t)BB*NN*64;     // 131,072
  float* sc1  = t1t + (size_t)BB*64*NN;    // 128
  float* sh1  = sc1 + NN;                  // 128
  float* Msp1 = sh1 + NN;                  // 131,072
  float* t2   = Msp1 + (size_t)BB*64*NN;   // 32,768
  float* t2t  = t2 + (size_t)BB*NN*16;     // 32,768
  float* sc2  = t2t + (size_t)BB*16*NN;    // 128
  float* sh2  = sc2 + NN;                  // 128
  float* Msp2 = sh2 + NN;                  // 32,768
  float* co   = Msp2 + (size_t)BB*16*NN;   // 1,572,864 (h2 output + residual)

  k_pre<<<321, 128, 0, stream>>>(batch_x, i2_w0, i2_w1, c1_w, c2_w, sp, s2p, vwsT, wT1, wT2);
  k_gemm1<<<dim3(32,12), 256, 0, stream>>>(batch_x, le_w, le_b, sp, s2p, x, a0);
  k_conv1<<<dim3(16,BB), 512, 0, stream>>>(x, wT1, c1_b, t1);
  k_bnstats<<<NN, 256, 0, stream>>>(t1, bn1_g, bn1_b, BB, 64, sc1, sh1);
  k_bnelu_t<<<dim3(64,BB), NN, 0, stream>>>(t1, sc1, sh1, 64, t1t);
  k_spline_solve<64><<<BB, NN, 0, stream>>>(t1t, Msp1);
  k_conv2<<<dim3(4,BB), 512, 0, stream>>>(t1t, wT2, c2_b, t2);
  k_bnstats<<<NN, 256, 0, stream>>>(t2, bn2_g, bn2_b, BB, 16, sc2, sh2);
  k_bnelu_t<<<dim3(16,BB), NN, 0, stream>>>(t2, sc2, sh2, 16, t2t);
  k_spline_solve<16><<<BB, NN, 0, stream>>>(t2t, Msp2);
  k_h12<<<dim3(96,4,BB), 256, 0, stream>>>(a0, t1t, Msp1, t2t, Msp2,
                                           i1_w0, i1_b0, i1_w1, i1_b1,
                                           vwsT, i2_b0, i2_b1, co);
  k_gemm2<<<dim3(32,4), 256, 0, stream>>>(co, ld_w, ld_b, sp, s2p, out);
}

// Round 3
// 310.698 us; speedup vs baseline: 1.0448x; 1.0039x over previous
//
#include <hip/hip_runtime.h>
#include <hip/hip_bf16.h>
#include <math.h>

#define BB 16
#define TT 512
#define NN 128
#define PREDN 256
#define DMC 32
#define LL 768
constexpr float EPSF = 1e-5f;
using bf16 = __hip_bfloat16;
using frag_ab = __attribute__((ext_vector_type(8))) short;   // 8 bf16
using frag_cd = __attribute__((ext_vector_type(4))) float;   // 4 f32

__device__ __forceinline__ unsigned pbf2(float a, float b){
  union { bf16 h; unsigned short u; } x, y;
  x.h = __float2bfloat16(a); y.h = __float2bfloat16(b);
  return (unsigned)x.u | ((unsigned)y.u << 16);
}

__device__ __forceinline__ unsigned short bf16b(float v){
  union { bf16 h; unsigned short u; } x;
  x.h = __float2bfloat16(v);
  return x.u;
}

__device__ __forceinline__ float gelu_fast(float s){
  float s2v = s*s;
  float e = exp2f(s*fmaf(s2v, 0.10294396f, 2.30211806f));
  return s*e*__builtin_amdgcn_rcpf(e + 1.f);
}

// ---------------- K_pre: stats partials + weight fold + conv weight transposes ----------------
__global__ void k_pre(const float* __restrict__ bx, const float* __restrict__ v0,
                      const float* __restrict__ v1, const float* __restrict__ w1c,
                      const float* __restrict__ w2c, float* __restrict__ sp,
                      float* __restrict__ s2p, float* __restrict__ vwsT,
                      float* __restrict__ wT1, float* __restrict__ wT2){
  int blk = blockIdx.x;
  if(blk < 64){
    int b = blk >> 2, tq = blk & 3, n = threadIdx.x;
    const float* p = bx + (size_t)b*TT*NN + (size_t)tq*128*NN + n;
    float s = 0.f, s2 = 0.f;
    for(int t=0;t<128;t++){ float v = p[(size_t)t*NN]; s += v; s2 += v*v; }
    sp[tq*2048 + b*NN + n] = s;
    s2p[tq*2048 + b*NN + n] = s2;
  } else if(blk == 64){
    for(int i=threadIdx.x; i<9*DMC; i+=blockDim.x){
      int tap = i/DMC, c = i%DMC;
      float wv = 0.5f*v1[c*9 + tap];
      if(tap == 4) wv += 0.5f*v0[c];
      vwsT[i] = wv;
    }
  } else if(blk <= 192){
    int o = blk - 65;
    for(int k=threadIdx.x; k<1536; k+=blockDim.x)
      wT1[(size_t)k*NN + o] = w1c[(size_t)o*1536 + k];
  } else {
    int o = blk - 193;
    for(int k=threadIdx.x; k<512; k+=blockDim.x)
      wT2[(size_t)k*NN + o] = w2c[(size_t)o*512 + k];
  }
}

// ---------------- K1: GEMM1 via bf16 MFMA 16x16x32, 64x64 tile, fused norm + dual store ----------------
__global__ __launch_bounds__(256) void k_gemm1(const float* __restrict__ bx, const float* __restrict__ lew,
    const float* __restrict__ leb, const float* __restrict__ sp, const float* __restrict__ s2p,
    float* __restrict__ x, float* __restrict__ a0){
  __shared__ unsigned Asu[64*20];
  __shared__ unsigned Bsu[64*20];
  int tid = threadIdx.x;
  int row0 = blockIdx.x*64, l0 = blockIdx.y*64;
  int b = row0 >> 7, n0 = row0 & 127;
  int lane = tid & 63, wv = tid >> 6;
  frag_cd acc[4] = {};
  int an = tid & 63, akq = (tid >> 6)*8;
  float mu_a, rs_a;
  {
    int rowa = row0 + an;
    float ssum = 0.f, s2sum = 0.f;
    #pragma unroll
    for(int tq=0;tq<4;tq++){ ssum += sp[tq*2048 + rowa]; s2sum += s2p[tq*2048 + rowa]; }
    mu_a = ssum*(1.f/512.f);
    rs_a = 1.f/sqrtf(fmaxf(s2sum*(1.f/512.f) - mu_a*mu_a, 0.f) + EPSF);
  }
  int btk = tid & 15, blc = tid >> 4;
  unsigned ra[4], rbq[4];
  #pragma unroll
  for(int u=0;u<4;u++){
    float v0 = (bx[((size_t)b*TT + akq + 2*u)*NN + n0 + an] - mu_a)*rs_a;
    float v1 = (bx[((size_t)b*TT + akq + 2*u + 1)*NN + n0 + an] - mu_a)*rs_a;
    ra[u] = pbf2(v0, v1);
    const float* lp = lew + (size_t)(l0 + blc + 16*u)*TT + 2*btk;
    rbq[u] = pbf2(lp[0], lp[1]);
  }
  int fr = wv*16 + (lane & 15);
  int fq = (lane >> 4)*4;
  for(int k0=0;k0<TT;k0+=32){
    *(uint4*)&Asu[an*20 + (akq>>1)] = make_uint4(ra[0], ra[1], ra[2], ra[3]);
    #pragma unroll
    for(int p=0;p<4;p++) Bsu[(blc + 16*p)*20 + btk] = rbq[p];
    __syncthreads();
    if(k0 + 32 < TT){
      #pragma unroll
      for(int u=0;u<4;u++){
        float v0 = (bx[((size_t)b*TT + k0 + 32 + akq + 2*u)*NN + n0 + an] - mu_a)*rs_a;
        float v1 = (bx[((size_t)b*TT + k0 + 32 + akq + 2*u + 1)*NN + n0 + an] - mu_a)*rs_a;
        ra[u] = pbf2(v0, v1);
        const float* lp = lew + (size_t)(l0 + blc + 16*u)*TT + k0 + 32 + 2*btk;
        rbq[u] = pbf2(lp[0], lp[1]);
      }
    }
    frag_ab af = *(const frag_ab*)&Asu[fr*20 + fq];
    #pragma unroll
    for(int nt=0;nt<4;nt++){
      frag_ab bf = *(const frag_ab*)&Bsu[(nt*16 + (lane & 15))*20 + fq];
      acc[nt] = __builtin_amdgcn_mfma_f32_16x16x32_bf16(af, bf, acc[nt], 0, 0, 0);
    }
    __syncthreads();
  }
  int col = lane & 15, quad = lane >> 4;
  #pragma unroll
  for(int nt=0;nt<4;nt++){
    int l = l0 + nt*16 + col;
    float lb = leb[l];
    #pragma unroll
    for(int r=0;r<4;r++){
      int m = wv*16 + quad*4 + r;
      x[(size_t)(row0 + m)*LL + l] = acc[nt][r] + lb;
    }
    float4 st;
    st.x = acc[nt][0] + lb;
    st.y = acc[nt][1] + lb;
    st.z = acc[nt][2] + lb;
    st.w = acc[nt][3] + lb;
    *(float4*)&a0[((size_t)b*LL + l)*NN + n0 + wv*16 + quad*4] = st;
  }
}

// ---------------- K3: conv1 (coalesced wT, 4 j per block) ----------------
__global__ __launch_bounds__(512) void k_conv1(const float* __restrict__ x, const float* __restrict__ wT,
                                               const float* __restrict__ bias, float* __restrict__ t1){
  __shared__ alignas(16) float xs[NN*48];
  int jt = blockIdx.x, b = blockIdx.y;
  int tid = threadIdx.x;
  int o = tid & 127, jj = tid >> 7;
  for(int i=tid;i<NN*48;i+=512){
    int ci = i/48, kk = i%48;
    xs[i] = x[((size_t)b*NN + ci)*LL + jt*48 + kk];
  }
  __syncthreads();
  float a0 = 0.f, a1 = 0.f, a2 = 0.f, a3 = 0.f;
  for(int ci=0;ci<NN;ci++){
    const float* xc = xs + ci*48 + jj*12;
    const float* wc = wT + (size_t)(ci*12)*NN + o;
    #pragma unroll
    for(int kk=0;kk<12;kk+=4){
      a0 = fmaf(xc[kk+0], wc[(size_t)(kk+0)*NN], a0);
      a1 = fmaf(xc[kk+1], wc[(size_t)(kk+1)*NN], a1);
      a2 = fmaf(xc[kk+2], wc[(size_t)(kk+2)*NN], a2);
      a3 = fmaf(xc[kk+3], wc[(size_t)(kk+3)*NN], a3);
    }
  }
  int j = jt*4 + jj;
  t1[((size_t)b*NN + o)*64 + j] = (a0 + a1) + (a2 + a3) + bias[o];
}

// ---------------- K4: BN stats per channel ----------------
__global__ void k_bnstats(const float* __restrict__ t, const float* __restrict__ g, const float* __restrict__ bb,
                          int Bcnt, int Jcnt, float* __restrict__ scale, float* __restrict__ shift){
  int o = blockIdx.x;
  int tot = Bcnt*Jcnt;
  float s = 0.f, s2 = 0.f;
  for(int i=threadIdx.x; i<tot; i+=blockDim.x){
    int b = i / Jcnt, j = i % Jcnt;
    float v = t[((size_t)b*NN + o)*Jcnt + j];
    s += v; s2 += v*v;
  }
  __shared__ float rs[256], rs2[256];
  rs[threadIdx.x] = s; rs2[threadIdx.x] = s2;
  __syncthreads();
  for(int st=128; st>0; st>>=1){
    if(threadIdx.x < st){ rs[threadIdx.x] += rs[threadIdx.x+st]; rs2[threadIdx.x] += rs2[threadIdx.x+st]; }
    __syncthreads();
  }
  if(threadIdx.x == 0){
    float mu = rs[0]/tot;
    float var = fmaxf(rs2[0]/tot - mu*mu, 0.f);
    float sc = g[o] * rsqrtf(var + EPSF);
    scale[o] = sc; shift[o] = bb[o] - mu*sc;
  }
}

// ---------------- K5: BN apply + ELU + transpose ----------------
__global__ void k_bnelu_t(const float* __restrict__ t, const float* __restrict__ scale,
                          const float* __restrict__ shift, int Jcnt, float* __restrict__ tt){
  int j = blockIdx.x, b = blockIdx.y, o = threadIdx.x;
  float v = t[((size_t)b*NN + o)*Jcnt + j]*scale[o] + shift[o];
  v = v > 0.f ? v : (expf(v) - 1.f);
  tt[((size_t)b*Jcnt + j)*NN + o] = v;
}

// ---------------- K6: spline tridiagonal solve (Thomas) ----------------
template<int LK>
__global__ void k_spline_solve(const float* __restrict__ y, float* __restrict__ M){
  constexpr int m = LK-2;
  const float Kc = 6.f*(LK-1)*(LK-1);
  __shared__ float cp[m];
  __shared__ float dp[m][NN];
  int b = blockIdx.x, c = threadIdx.x;
  if(c == 0){
    float cv = 0.25f; cp[0] = cv;
    for(int i=1;i<m;i++){ cv = 1.f/(4.f - cv); cp[i] = cv; }
  }
  __syncthreads();
  const float* yb = y + (size_t)b*LK*NN + c;
  float y0 = yb[0], y1 = yb[NN];
  float dprev = 0.f;
  for(int i=0;i<m;i++){
    float y2 = yb[(size_t)(i+2)*NN];
    float r = (y2 - 2.f*y1 + y0)*Kc;
    float d = (i == 0) ? r*0.25f : (r - dprev)*cp[i];
    dp[i][c] = d; dprev = d;
    y0 = y1; y1 = y2;
  }
  float* Mb = M + (size_t)b*LK*NN + c;
  float xv = dp[m-1][c];
  Mb[(size_t)m*NN] = xv;
  for(int i=m-2;i>=0;i--){
    xv = dp[i][c] - cp[i]*xv;
    Mb[(size_t)(i+1)*NN] = xv;
  }
  Mb[0] = 0.f;
  Mb[(size_t)(LK-1)*NN] = 0.f;
}

// ---------------- spline point evaluation (device) ----------------
__device__ __forceinline__ float spline_pt(const float* __restrict__ y, const float* __restrict__ M,
                                           int LK, int l, int b, int c){
  float hh = 1.f/(LK-1);
  float q = (float)l * (1.f/(LL-1));
  int idx = (int)floorf(q*(LK-1));
  if(idx > LK-2) idx = LK-2;
  float s = q - idx*hh;
  float u = hh - s;
  const float* yb = y + ((size_t)b*LK + idx)*NN + c;
  const float* Mb = M + ((size_t)b*LK + idx)*NN + c;
  float yi = yb[0], yi1 = yb[NN], M0 = Mb[0], M1 = Mb[NN];
  float hh6 = hh*hh/6.f;
  return (M0*u*u*u + M1*s*s*s)*(1.f/(6.f*hh))
       + (yi  - M0*hh6)*(u*(1.f/hh))
       + (yi1 - M1*hh6)*(s*(1.f/hh));
}

// ---------------- K8: conv2 (coalesced wT, 4 j per block) ----------------
__global__ __launch_bounds__(512) void k_conv2(const float* __restrict__ tt, const float* __restrict__ wT,
                                               const float* __restrict__ bias, float* __restrict__ t2){
  __shared__ alignas(16) float ts[16*NN];
  int jt = blockIdx.x, b = blockIdx.y;
  int tid = threadIdx.x;
  int o = tid & 127, jj = tid >> 7;
  for(int i=tid;i<16*NN;i+=512)
    ts[i] = tt[((size_t)b*64 + jt*16)*NN + i];
  __syncthreads();
  float a0 = 0.f, a1 = 0.f, a2 = 0.f, a3 = 0.f;
  for(int ci=0;ci<NN;ci++){
    const float* wc = wT + (size_t)(ci*4)*NN + o;
    const float* tc2 = ts + (jj*4)*NN + ci;
    a0 = fmaf(tc2[0*NN], wc[0*NN], a0);
    a1 = fmaf(tc2[1*NN], wc[1*NN], a1);
    a2 = fmaf(tc2[2*NN], wc[2*NN], a2);
    a3 = fmaf(tc2[3*NN], wc[3*NN], a3);
  }
  int j = jt*4 + jj;
  t2[((size_t)b*NN + o)*16 + j] = (a0 + a1) + (a2 + a3) + bias[o];
}

// tap offset table for im2col: k = ci*9 + dy*3 + dx -> offset into as[3][12][36]
constexpr int KOFF[27] = {
    0,   1,   2,  36,  37,  38,  72,  73,  74,
  432, 433, 434, 468, 469, 470, 504, 505, 506,
  864, 865, 866, 900, 901, 902, 936, 937, 938
};

// ---------------- K_h12: fully-MFMA fused stage-1 conv + GELU + stage-2 conv + residual ----------------
// Per block: 8x32 output tile of h2 (+ residual) -> co.
// h1 tile = 10x34 px (340, padded to 352 = 22 m-tiles), 32 ch. a-tile 3ch x 12x36.
// Stage-1: h1[px][c] = gelu( patch1[px][k27] x W1[k][c] ) via mfma (K padded to 32); result packed
//          bf16 back into the same stride-20 LDS rows (per-wave disjoint m-tiles).
// Stage-2: out[px] = patch2[px][k=9x32] x w2[k] via mfma with A=weights (row 0 only), B=pixels.
//          B-frags read DIRECTLY from the h1 rows (row=px, 32ch contiguous) -> im2col is free.
__global__ __launch_bounds__(256) void k_h12(const float* __restrict__ a0,
    const float* __restrict__ y64, const float* __restrict__ M64,
    const float* __restrict__ y16, const float* __restrict__ M16,
    const float* __restrict__ w0, const float* __restrict__ b0,
    const float* __restrict__ w1, const float* __restrict__ b1,
    const float* __restrict__ vwsT, const float* __restrict__ vb0,
    const float* __restrict__ vb1, float* __restrict__ co){
  constexpr int AR = 12, AC = 36;
  __shared__ alignas(16) float as[3][AR][AC];     // a-tile, rows l0-2..l0+9, cols n0-2..n0+33
  __shared__ alignas(16) unsigned Au[352*20];     // im2col A then h1 (bf16 pairs), stride 20 uints
  int tid = threadIdx.x;
  int l0 = blockIdx.x*8, n0 = blockIdx.y*32, b = blockIdx.z;
  int lane = tid & 63, wv = tid >> 6;

  // ---- Phase A: stage a-tile (ch0 = a0, ch1/ch2 = spline evals) ----
  float* asf = &as[0][0][0];
  for(int i=tid; i<3*AR*AC; i+=256){
    int ch = i/(AR*AC), rem = i%(AR*AC), yy = rem/AC, xx = rem%AC;
    int gl = l0 + yy - 2, gn = n0 + xx - 2;
    float v = 0.f;
    if(gl >= 0 && gl < LL && gn >= 0 && gn < NN){
      if(ch == 0)      v = a0[((size_t)b*LL + gl)*NN + gn];
      else if(ch == 1) v = spline_pt(y64, M64, 64, gl, b, gn);
      else             v = spline_pt(y16, M16, 16, gl, b, gn);
    }
    asf[i] = v;
  }

  // ---- stage-1 weight B-fragments: B[c][k], k = ci*9+dy*3+dx, pad k>=27 = 0 ----
  int colB = lane & 15, kq = (lane >> 4)*8;
  union { uint4 q; frag_ab f; } bw0, bw1;
  {
    float w8[2][8];
    #pragma unroll
    for(int nt=0;nt<2;nt++){
      #pragma unroll
      for(int j=0;j<8;j++){
        int k = kq + j;
        float w = 0.f;
        if(k < 27){
          int ci = k/9, r9 = k - ci*9, dy = r9/3, dx = r9 - dy*3;
          int c = nt*16 + colB;
          w = 0.5f*w1[((c*3+ci)*3+dy)*3+dx];
          if(dy==1 && dx==1) w += 0.5f*w0[c*3+ci];
        }
        w8[nt][j] = w;
      }
    }
    bw0.q = make_uint4(pbf2(w8[0][0],w8[0][1]), pbf2(w8[0][2],w8[0][3]),
                       pbf2(w8[0][4],w8[0][5]), pbf2(w8[0][6],w8[0][7]));
    bw1.q = make_uint4(pbf2(w8[1][0],w8[1][1]), pbf2(w8[1][2],w8[1][3]),
                       pbf2(w8[1][4],w8[1][5]), pbf2(w8[1][6],w8[1][7]));
  }
  float br0 = 0.5f*(b0[colB] + b1[colB]);
  float br1 = 0.5f*(b0[16 + colB] + b1[16 + colB]);
  __syncthreads();

  // ---- Phase B1: im2col build A[px][32k] bf16 (2 threads per px, 8 uints each) ----
  for(int base=0; base<352; base+=128){
    int px = base + (tid >> 1);
    int half = tid & 1;
    if(px < 352){
      uint4 oA, oB;
      if(px < 340){
        int yy = px/34, xx = px - yy*34;
        const float* bp = asf + yy*AC + xx;
        if(half == 0){
          oA.x = pbf2(bp[KOFF[0]],  bp[KOFF[1]]);
          oA.y = pbf2(bp[KOFF[2]],  bp[KOFF[3]]);
          oA.z = pbf2(bp[KOFF[4]],  bp[KOFF[5]]);
          oA.w = pbf2(bp[KOFF[6]],  bp[KOFF[7]]);
          oB.x = pbf2(bp[KOFF[8]],  bp[KOFF[9]]);
          oB.y = pbf2(bp[KOFF[10]], bp[KOFF[11]]);
          oB.z = pbf2(bp[KOFF[12]], bp[KOFF[13]]);
          oB.w = pbf2(bp[KOFF[14]], bp[KOFF[15]]);
        } else {
          oA.x = pbf2(bp[KOFF[16]], bp[KOFF[17]]);
          oA.y = pbf2(bp[KOFF[18]], bp[KOFF[19]]);
          oA.z = pbf2(bp[KOFF[20]], bp[KOFF[21]]);
          oA.w = pbf2(bp[KOFF[22]], bp[KOFF[23]]);
          oB.x = pbf2(bp[KOFF[24]], bp[KOFF[25]]);
          oB.y = pbf2(bp[KOFF[26]], 0.f);
          oB.z = 0u; oB.w = 0u;
        }
      } else {
        oA = make_uint4(0u,0u,0u,0u);
        oB = make_uint4(0u,0u,0u,0u);
      }
      *(uint4*)&Au[px*20 + half*8]     = oA;
      *(uint4*)&Au[px*20 + half*8 + 4] = oB;
    }
  }
  __syncthreads();

  // ---- Phase B2: stage-1 MFMA per m-tile, gelu, pack bf16 back into same rows ----
  unsigned short* h1h = (unsigned short*)Au;
  frag_cd zac = {0.f, 0.f, 0.f, 0.f};
  for(int t = wv; t < 22; t += 4){
    int arow = t*16 + colB;
    union { uint4 q; frag_ab f; } av;
    av.q = *(const uint4*)&Au[arow*20 + (lane>>4)*4];
    frag_cd d0 = __builtin_amdgcn_mfma_f32_16x16x32_bf16(av.f, bw0.f, zac, 0, 0, 0);
    frag_cd d1 = __builtin_amdgcn_mfma_f32_16x16x32_bf16(av.f, bw1.f, zac, 0, 0, 0);
    int px0 = t*16 + (lane>>4)*4;
    #pragma unroll
    for(int r=0;r<4;r++){
      int px = px0 + r;
      h1h[px*40 + colB]      = bf16b(gelu_fast(d0[r] + br0));
      h1h[px*40 + 16 + colB] = bf16b(gelu_fast(d1[r] + br1));
    }
  }
  __syncthreads();

  // ---- Phase B3: zero h1 at invalid borders (conv zero-padding semantics of stage 2) ----
  if(n0 == 0){
    for(int i=tid;i<10*32;i+=256){ int yy=i>>5, ch=i&31; h1h[(yy*34)*40 + ch] = 0; }
  }
  if(n0 == 96){
    for(int i=tid;i<10*32;i+=256){ int yy=i>>5, ch=i&31; h1h[(yy*34+33)*40 + ch] = 0; }
  }
  if(l0 == 0){
    for(int i=tid;i<34*32;i+=256){ int xx=i>>5, ch=i&31; h1h[xx*40 + ch] = 0; }
  }
  if(l0 == 760){
    for(int i=tid;i<34*32;i+=256){ int xx=i>>5, ch=i&31; h1h[(9*34+xx)*40 + ch] = 0; }
  }

  // ---- stage-2 weight A-fragments: A[m][c], only m==0 valid = w2[tap][c] ----
  union { uint4 q; frag_ab f; } aw[9];
  {
    bool wlane = (lane & 15) == 0;
    int c8 = (lane >> 4)*8;
    #pragma unroll
    for(int tap=0; tap<9; tap++){
      const float* wp = vwsT + tap*DMC + c8;
      float4 wa = *(const float4*)wp;
      float4 wb = *(const float4*)(wp+4);
      if(!wlane){ wa = make_float4(0.f,0.f,0.f,0.f); wb = make_float4(0.f,0.f,0.f,0.f); }
      aw[tap].q = make_uint4(pbf2(wa.x,wa.y), pbf2(wa.z,wa.w), pbf2(wb.x,wb.y), pbf2(wb.z,wb.w));
    }
  }
  float vbsum = vb0[0] + vb1[0];
  __syncthreads();

  // ---- Phase C: stage-2 conv via MFMA. A=weights (row 0), B=pixel patches direct from h1 rows ----
  frag_cd cacc[4] = {};
  int kq4 = (lane >> 4)*4;
  int baseoff[4];
  #pragma unroll
  for(int tt=0; tt<4; tt++){
    int px = (wv*4 + tt)*16 + (lane & 15);
    int yy = px >> 5, xx = px & 31;
    baseoff[tt] = (yy*34 + xx)*20 + kq4;
  }
  #pragma unroll
  for(int dy=0; dy<3; dy++)
    #pragma unroll
    for(int dx=0; dx<3; dx++){
      int tap = dy*3 + dx;
      int off = (dy*34 + dx)*20;
      #pragma unroll
      for(int tt=0; tt<4; tt++){
        union { uint4 q; frag_ab f; } bv;
        bv.q = *(const uint4*)&Au[baseoff[tt] + off];
        cacc[tt] = __builtin_amdgcn_mfma_f32_16x16x32_bf16(aw[tap].f, bv.f, cacc[tt], 0, 0, 0);
      }
    }
  // D row 0 (= output channel 0) lives in lanes 0..15, reg 0
  if(lane < 16){
    #pragma unroll
    for(int tt=0; tt<4; tt++){
      int px = (wv*4 + tt)*16 + lane;
      int yy = px >> 5, xx = px & 31;
      float res = as[0][yy+2][xx+2];
      size_t idx = ((size_t)b*LL + l0 + yy)*NN + n0 + xx;
      co[idx] = cacc[tt][0] + vbsum + res;
    }
  }
}

// ---------------- K15: GEMM2 via bf16 MFMA 16x16x32, 64x64 tile + de-normalize ----------------
// A[m=(b,n)][k=l] = co[b][l][n], B[n'=p][k=l] = ldw[p][l]
__global__ __launch_bounds__(256) void k_gemm2(const float* __restrict__ a0, const float* __restrict__ ldw,
    const float* __restrict__ ldb, const float* __restrict__ sp, const float* __restrict__ s2p,
    float* __restrict__ out){
  __shared__ unsigned Asu[64*20];
  __shared__ unsigned Bsu[64*20];
  int tid = threadIdx.x;
  int row0 = blockIdx.x*64, p0 = blockIdx.y*64;
  int b = row0 >> 7, n0 = row0 & 127;
  int lane = tid & 63, wv = tid >> 6;
  frag_cd acc[4] = {};
  int an = tid & 63, akq = (tid >> 6)*8;
  int btk = tid & 15, blc = tid >> 4;
  unsigned ra[4], rbq[4];
  #pragma unroll
  for(int u=0;u<4;u++){
    float v0 = a0[((size_t)b*LL + akq + 2*u)*NN + n0 + an];
    float v1 = a0[((size_t)b*LL + akq + 2*u + 1)*NN + n0 + an];
    ra[u] = pbf2(v0, v1);
    const float* lp = ldw + (size_t)(p0 + blc + 16*u)*LL + 2*btk;
    rbq[u] = pbf2(lp[0], lp[1]);
  }
  int fr = wv*16 + (lane & 15);
  int fq = (lane >> 4)*4;
  for(int k0=0;k0<LL;k0+=32){
    *(uint4*)&Asu[an*20 + (akq>>1)] = make_uint4(ra[0], ra[1], ra[2], ra[3]);
    #pragma unroll
    for(int p=0;p<4;p++) Bsu[(blc + 16*p)*20 + btk] = rbq[p];
    __syncthreads();
    if(k0 + 32 < LL){
      #pragma unroll
      for(int u=0;u<4;u++){
        float v0 = a0[((size_t)b*LL + k0 + 32 + akq + 2*u)*NN + n0 + an];
        float v1 = a0[((size_t)b*LL + k0 + 32 + akq + 2*u + 1)*NN + n0 + an];
        ra[u] = pbf2(v0, v1);
        const float* lp = ldw + (size_t)(p0 + blc + 16*u)*LL + k0 + 32 + 2*btk;
        rbq[u] = pbf2(lp[0], lp[1]);
      }
    }
    frag_ab af = *(const frag_ab*)&Asu[fr*20 + fq];
    #pragma unroll
    for(int nt=0;nt<4;nt++){
      frag_ab bf = *(const frag_ab*)&Bsu[(nt*16 + (lane & 15))*20 + fq];
      acc[nt] = __builtin_amdgcn_mfma_f32_16x16x32_bf16(af, bf, acc[nt], 0, 0, 0);
    }
    __syncthreads();
  }
  int col = lane & 15, quad = lane >> 4;
  // de-norm constants for the 4 rows this lane owns
  float mu_r[4], sd_r[4];
  #pragma unroll
  for(int r=0;r<4;r++){
    int row = row0 + wv*16 + quad*4 + r;
    float ssum = 0.f, s2sum = 0.f;
    #pragma unroll
    for(int tq=0;tq<4;tq++){ ssum += sp[tq*2048 + row]; s2sum += s2p[tq*2048 + row]; }
    float mu = ssum*(1.f/512.f);
    float var = fmaxf(s2sum*(1.f/512.f) - mu*mu, 0.f);
    mu_r[r] = mu; sd_r[r] = sqrtf(var + EPSF);
  }
  #pragma unroll
  for(int nt=0;nt<4;nt++){
    int p = p0 + nt*16 + col;
    float lb = ldb[p];
    float4 st;
    st.x = (acc[nt][0] + lb)*sd_r[0] + mu_r[0];
    st.y = (acc[nt][1] + lb)*sd_r[1] + mu_r[1];
    st.z = (acc[nt][2] + lb)*sd_r[2] + mu_r[2];
    st.w = (acc[nt][3] + lb)*sd_r[3] + mu_r[3];
    *(float4*)&out[((size_t)b*PREDN + p)*NN + n0 + wv*16 + quad*4] = st;
  }
}

extern "C" void kernel_launch(void* const* d_in, const int* in_sizes, int n_in,
                              void* d_out, int out_size, void* d_ws, size_t ws_size,
                              hipStream_t stream){
  (void)in_sizes; (void)n_in; (void)out_size; (void)ws_size;
  const float* batch_x = (const float*)d_in[0];
  const float* le_w  = (const float*)d_in[4];
  const float* le_b  = (const float*)d_in[5];
  const float* c1_w  = (const float*)d_in[6];
  const float* c1_b  = (const float*)d_in[7];
  const float* bn1_g = (const float*)d_in[8];
  const float* bn1_b = (const float*)d_in[9];
  const float* c2_w  = (const float*)d_in[10];
  const float* c2_b  = (const float*)d_in[11];
  const float* bn2_g = (const float*)d_in[12];
  const float* bn2_b = (const float*)d_in[13];
  const float* i1_w0 = (const float*)d_in[14];
  const float* i1_b0 = (const float*)d_in[15];
  const float* i1_w1 = (const float*)d_in[16];
  const float* i1_b1 = (const float*)d_in[17];
  const float* i2_w0 = (const float*)d_in[18];
  const float* i2_b0 = (const float*)d_in[19];
  const float* i2_w1 = (const float*)d_in[20];
  const float* i2_b1 = (const float*)d_in[21];
  const float* ld_w  = (const float*)d_in[22];
  const float* ld_b  = (const float*)d_in[23];
  float* out = (float*)d_out;

  float* ws   = (float*)d_ws;
  float* sp   = ws;                        // 8192
  float* s2p  = sp + 8192;                 // 8192
  float* vwsT = s2p + 8192;                // 288 (+pad)
  float* wT1  = vwsT + 320;                // 196,608
  float* wT2  = wT1 + 196608;              // 65,536
  float* x    = wT2 + 65536;               // 1,572,864
  float* a0   = x + (size_t)BB*NN*LL;      // 1,572,864
  float* t1   = a0 + (size_t)BB*LL*NN;     // 131,072
  float* t1t  = t1 + (size_t)BB*NN*64;     // 131,072
  float* sc1  = t1t + (size_t)BB*64*NN;    // 128
  float* sh1  = sc1 + NN;                  // 128
  float* Msp1 = sh1 + NN;                  // 131,072
  float* t2   = Msp1 + (size_t)BB*64*NN;   // 32,768
  float* t2t  = t2 + (size_t)BB*NN*16;     // 32,768
  float* sc2  = t2t + (size_t)BB*16*NN;    // 128
  float* sh2  = sc2 + NN;                  // 128
  float* Msp2 = sh2 + NN;                  // 32,768
  float* co   = Msp2 + (size_t)BB*16*NN;   // 1,572,864 (h2 output + residual)

  k_pre<<<321, 128, 0, stream>>>(batch_x, i2_w0, i2_w1, c1_w, c2_w, sp, s2p, vwsT, wT1, wT2);
  k_gemm1<<<dim3(32,12), 256, 0, stream>>>(batch_x, le_w, le_b, sp, s2p, x, a0);
  k_conv1<<<dim3(16,BB), 512, 0, stream>>>(x, wT1, c1_b, t1);
  k_bnstats<<<NN, 256, 0, stream>>>(t1, bn1_g, bn1_b, BB, 64, sc1, sh1);
  k_bnelu_t<<<dim3(64,BB), NN, 0, stream>>>(t1, sc1, sh1, 64, t1t);
  k_spline_solve<64><<<BB, NN, 0, stream>>>(t1t, Msp1);
  k_conv2<<<dim3(4,BB), 512, 0, stream>>>(t1t, wT2, c2_b, t2);
  k_bnstats<<<NN, 256, 0, stream>>>(t2, bn2_g, bn2_b, BB, 16, sc2, sh2);
  k_bnelu_t<<<dim3(16,BB), NN, 0, stream>>>(t2, sc2, sh2, 16, t2t);
  k_spline_solve<16><<<BB, NN, 0, stream>>>(t2t, Msp2);
  k_h12<<<dim3(96,4,BB), 256, 0, stream>>>(a0, t1t, Msp1, t2t, Msp2,
                                           i1_w0, i1_b0, i1_w1, i1_b1,
                                           vwsT, i2_b0, i2_b1, co);
  k_gemm2<<<dim3(32,4), 256, 0, stream>>>(co, ld_w, ld_b, sp, s2p, out);
}

// Round 4
// 299.571 us; speedup vs baseline: 1.0836x; 1.0371x over previous
//
#include <hip/hip_runtime.h>
#include <hip/hip_bf16.h>
#include <math.h>

#define BB 16
#define TT 512
#define NN 128
#define PREDN 256
#define DMC 32
#define LL 768
constexpr float EPSF = 1e-5f;
using bf16 = __hip_bfloat16;
using frag_ab = __attribute__((ext_vector_type(8))) short;   // 8 bf16
using frag_cd = __attribute__((ext_vector_type(4))) float;   // 4 f32

__device__ __forceinline__ unsigned pbf2(float a, float b){
  union { bf16 h; unsigned short u; } x, y;
  x.h = __float2bfloat16(a); y.h = __float2bfloat16(b);
  return (unsigned)x.u | ((unsigned)y.u << 16);
}

__device__ __forceinline__ unsigned short bf16b(float v){
  union { bf16 h; unsigned short u; } x;
  x.h = __float2bfloat16(v);
  return x.u;
}

__device__ __forceinline__ float gelu_fast(float s){
  float s2v = s*s;
  float e = exp2f(s*fmaf(s2v, 0.10294396f, 2.30211806f));
  return s*e*__builtin_amdgcn_rcpf(e + 1.f);
}

// ---------------- K_pre: stats partials + weight fold + conv weight transposes ----------------
__global__ void k_pre(const float* __restrict__ bx, const float* __restrict__ v0,
                      const float* __restrict__ v1, const float* __restrict__ w1c,
                      const float* __restrict__ w2c, float* __restrict__ sp,
                      float* __restrict__ s2p, float* __restrict__ vwsT,
                      float* __restrict__ wT1, float* __restrict__ wT2){
  int blk = blockIdx.x;
  if(blk < 64){
    int b = blk >> 2, tq = blk & 3, n = threadIdx.x;
    const float* p = bx + (size_t)b*TT*NN + (size_t)tq*128*NN + n;
    float s = 0.f, s2 = 0.f;
    for(int t=0;t<128;t++){ float v = p[(size_t)t*NN]; s += v; s2 += v*v; }
    sp[tq*2048 + b*NN + n] = s;
    s2p[tq*2048 + b*NN + n] = s2;
  } else if(blk == 64){
    for(int i=threadIdx.x; i<9*DMC; i+=blockDim.x){
      int tap = i/DMC, c = i%DMC;
      float wv = 0.5f*v1[c*9 + tap];
      if(tap == 4) wv += 0.5f*v0[c];
      vwsT[i] = wv;
    }
  } else if(blk <= 192){
    int o = blk - 65;
    for(int k=threadIdx.x; k<1536; k+=blockDim.x)
      wT1[(size_t)k*NN + o] = w1c[(size_t)o*1536 + k];
  } else {
    int o = blk - 193;
    for(int k=threadIdx.x; k<512; k+=blockDim.x)
      wT2[(size_t)k*NN + o] = w2c[(size_t)o*512 + k];
  }
}

// ---------------- K1: GEMM1 via bf16 MFMA 16x16x32, 64x64 tile, fused norm + dual store ----------------
__global__ __launch_bounds__(256) void k_gemm1(const float* __restrict__ bx, const float* __restrict__ lew,
    const float* __restrict__ leb, const float* __restrict__ sp, const float* __restrict__ s2p,
    float* __restrict__ x, float* __restrict__ a0){
  __shared__ unsigned Asu[64*20];
  __shared__ unsigned Bsu[64*20];
  int tid = threadIdx.x;
  int row0 = blockIdx.x*64, l0 = blockIdx.y*64;
  int b = row0 >> 7, n0 = row0 & 127;
  int lane = tid & 63, wv = tid >> 6;
  frag_cd acc[4] = {};
  int an = tid & 63, akq = (tid >> 6)*8;
  float mu_a, rs_a;
  {
    int rowa = row0 + an;
    float ssum = 0.f, s2sum = 0.f;
    #pragma unroll
    for(int tq=0;tq<4;tq++){ ssum += sp[tq*2048 + rowa]; s2sum += s2p[tq*2048 + rowa]; }
    mu_a = ssum*(1.f/512.f);
    rs_a = 1.f/sqrtf(fmaxf(s2sum*(1.f/512.f) - mu_a*mu_a, 0.f) + EPSF);
  }
  int btk = tid & 15, blc = tid >> 4;
  unsigned ra[4], rbq[4];
  #pragma unroll
  for(int u=0;u<4;u++){
    float v0 = (bx[((size_t)b*TT + akq + 2*u)*NN + n0 + an] - mu_a)*rs_a;
    float v1 = (bx[((size_t)b*TT + akq + 2*u + 1)*NN + n0 + an] - mu_a)*rs_a;
    ra[u] = pbf2(v0, v1);
    const float* lp = lew + (size_t)(l0 + blc + 16*u)*TT + 2*btk;
    rbq[u] = pbf2(lp[0], lp[1]);
  }
  int fr = wv*16 + (lane & 15);
  int fq = (lane >> 4)*4;
  for(int k0=0;k0<TT;k0+=32){
    *(uint4*)&Asu[an*20 + (akq>>1)] = make_uint4(ra[0], ra[1], ra[2], ra[3]);
    #pragma unroll
    for(int p=0;p<4;p++) Bsu[(blc + 16*p)*20 + btk] = rbq[p];
    __syncthreads();
    if(k0 + 32 < TT){
      #pragma unroll
      for(int u=0;u<4;u++){
        float v0 = (bx[((size_t)b*TT + k0 + 32 + akq + 2*u)*NN + n0 + an] - mu_a)*rs_a;
        float v1 = (bx[((size_t)b*TT + k0 + 32 + akq + 2*u + 1)*NN + n0 + an] - mu_a)*rs_a;
        ra[u] = pbf2(v0, v1);
        const float* lp = lew + (size_t)(l0 + blc + 16*u)*TT + k0 + 32 + 2*btk;
        rbq[u] = pbf2(lp[0], lp[1]);
      }
    }
    frag_ab af = *(const frag_ab*)&Asu[fr*20 + fq];
    #pragma unroll
    for(int nt=0;nt<4;nt++){
      frag_ab bf = *(const frag_ab*)&Bsu[(nt*16 + (lane & 15))*20 + fq];
      acc[nt] = __builtin_amdgcn_mfma_f32_16x16x32_bf16(af, bf, acc[nt], 0, 0, 0);
    }
    __syncthreads();
  }
  int col = lane & 15, quad = lane >> 4;
  #pragma unroll
  for(int nt=0;nt<4;nt++){
    int l = l0 + nt*16 + col;
    float lb = leb[l];
    #pragma unroll
    for(int r=0;r<4;r++){
      int m = wv*16 + quad*4 + r;
      x[(size_t)(row0 + m)*LL + l] = acc[nt][r] + lb;
    }
    float4 st;
    st.x = acc[nt][0] + lb;
    st.y = acc[nt][1] + lb;
    st.z = acc[nt][2] + lb;
    st.w = acc[nt][3] + lb;
    *(float4*)&a0[((size_t)b*LL + l)*NN + n0 + wv*16 + quad*4] = st;
  }
}

// ---------------- K3: conv1 (coalesced wT, 4 j per block) ----------------
__global__ __launch_bounds__(512) void k_conv1(const float* __restrict__ x, const float* __restrict__ wT,
                                               const float* __restrict__ bias, float* __restrict__ t1){
  __shared__ alignas(16) float xs[NN*48];
  int jt = blockIdx.x, b = blockIdx.y;
  int tid = threadIdx.x;
  int o = tid & 127, jj = tid >> 7;
  for(int i=tid;i<NN*48;i+=512){
    int ci = i/48, kk = i%48;
    xs[i] = x[((size_t)b*NN + ci)*LL + jt*48 + kk];
  }
  __syncthreads();
  float a0 = 0.f, a1 = 0.f, a2 = 0.f, a3 = 0.f;
  for(int ci=0;ci<NN;ci++){
    const float* xc = xs + ci*48 + jj*12;
    const float* wc = wT + (size_t)(ci*12)*NN + o;
    #pragma unroll
    for(int kk=0;kk<12;kk+=4){
      a0 = fmaf(xc[kk+0], wc[(size_t)(kk+0)*NN], a0);
      a1 = fmaf(xc[kk+1], wc[(size_t)(kk+1)*NN], a1);
      a2 = fmaf(xc[kk+2], wc[(size_t)(kk+2)*NN], a2);
      a3 = fmaf(xc[kk+3], wc[(size_t)(kk+3)*NN], a3);
    }
  }
  int j = jt*4 + jj;
  t1[((size_t)b*NN + o)*64 + j] = (a0 + a1) + (a2 + a3) + bias[o];
}

// ---------------- K4: BN stats per channel ----------------
__global__ void k_bnstats(const float* __restrict__ t, const float* __restrict__ g, const float* __restrict__ bb,
                          int Bcnt, int Jcnt, float* __restrict__ scale, float* __restrict__ shift){
  int o = blockIdx.x;
  int tot = Bcnt*Jcnt;
  float s = 0.f, s2 = 0.f;
  for(int i=threadIdx.x; i<tot; i+=blockDim.x){
    int b = i / Jcnt, j = i % Jcnt;
    float v = t[((size_t)b*NN + o)*Jcnt + j];
    s += v; s2 += v*v;
  }
  __shared__ float rs[256], rs2[256];
  rs[threadIdx.x] = s; rs2[threadIdx.x] = s2;
  __syncthreads();
  for(int st=128; st>0; st>>=1){
    if(threadIdx.x < st){ rs[threadIdx.x] += rs[threadIdx.x+st]; rs2[threadIdx.x] += rs2[threadIdx.x+st]; }
    __syncthreads();
  }
  if(threadIdx.x == 0){
    float mu = rs[0]/tot;
    float var = fmaxf(rs2[0]/tot - mu*mu, 0.f);
    float sc = g[o] * rsqrtf(var + EPSF);
    scale[o] = sc; shift[o] = bb[o] - mu*sc;
  }
}

// ---------------- K5: BN apply + ELU + transpose ----------------
__global__ void k_bnelu_t(const float* __restrict__ t, const float* __restrict__ scale,
                          const float* __restrict__ shift, int Jcnt, float* __restrict__ tt){
  int j = blockIdx.x, b = blockIdx.y, o = threadIdx.x;
  float v = t[((size_t)b*NN + o)*Jcnt + j]*scale[o] + shift[o];
  v = v > 0.f ? v : (expf(v) - 1.f);
  tt[((size_t)b*Jcnt + j)*NN + o] = v;
}

// ---------------- K6: spline tridiagonal solve (Thomas) ----------------
template<int LK>
__global__ void k_spline_solve(const float* __restrict__ y, float* __restrict__ M){
  constexpr int m = LK-2;
  const float Kc = 6.f*(LK-1)*(LK-1);
  __shared__ float cp[m];
  __shared__ float dp[m][NN];
  int b = blockIdx.x, c = threadIdx.x;
  if(c == 0){
    float cv = 0.25f; cp[0] = cv;
    for(int i=1;i<m;i++){ cv = 1.f/(4.f - cv); cp[i] = cv; }
  }
  __syncthreads();
  const float* yb = y + (size_t)b*LK*NN + c;
  float y0 = yb[0], y1 = yb[NN];
  float dprev = 0.f;
  for(int i=0;i<m;i++){
    float y2 = yb[(size_t)(i+2)*NN];
    float r = (y2 - 2.f*y1 + y0)*Kc;
    float d = (i == 0) ? r*0.25f : (r - dprev)*cp[i];
    dp[i][c] = d; dprev = d;
    y0 = y1; y1 = y2;
  }
  float* Mb = M + (size_t)b*LK*NN + c;
  float xv = dp[m-1][c];
  Mb[(size_t)m*NN] = xv;
  for(int i=m-2;i>=0;i--){
    xv = dp[i][c] - cp[i]*xv;
    Mb[(size_t)(i+1)*NN] = xv;
  }
  Mb[0] = 0.f;
  Mb[(size_t)(LK-1)*NN] = 0.f;
}

// ---------------- spline point evaluation (device) ----------------
__device__ __forceinline__ float spline_pt(const float* __restrict__ y, const float* __restrict__ M,
                                           int LK, int l, int b, int c){
  float hh = 1.f/(LK-1);
  float q = (float)l * (1.f/(LL-1));
  int idx = (int)floorf(q*(LK-1));
  if(idx > LK-2) idx = LK-2;
  float s = q - idx*hh;
  float u = hh - s;
  const float* yb = y + ((size_t)b*LK + idx)*NN + c;
  const float* Mb = M + ((size_t)b*LK + idx)*NN + c;
  float yi = yb[0], yi1 = yb[NN], M0 = Mb[0], M1 = Mb[NN];
  float hh6 = hh*hh/6.f;
  return (M0*u*u*u + M1*s*s*s)*(1.f/(6.f*hh))
       + (yi  - M0*hh6)*(u*(1.f/hh))
       + (yi1 - M1*hh6)*(s*(1.f/hh));
}

// ---------------- K8: conv2 (coalesced wT, 4 j per block) ----------------
__global__ __launch_bounds__(512) void k_conv2(const float* __restrict__ tt, const float* __restrict__ wT,
                                               const float* __restrict__ bias, float* __restrict__ t2){
  __shared__ alignas(16) float ts[16*NN];
  int jt = blockIdx.x, b = blockIdx.y;
  int tid = threadIdx.x;
  int o = tid & 127, jj = tid >> 7;
  for(int i=tid;i<16*NN;i+=512)
    ts[i] = tt[((size_t)b*64 + jt*16)*NN + i];
  __syncthreads();
  float a0 = 0.f, a1 = 0.f, a2 = 0.f, a3 = 0.f;
  for(int ci=0;ci<NN;ci++){
    const float* wc = wT + (size_t)(ci*4)*NN + o;
    const float* tc2 = ts + (jj*4)*NN + ci;
    a0 = fmaf(tc2[0*NN], wc[0*NN], a0);
    a1 = fmaf(tc2[1*NN], wc[1*NN], a1);
    a2 = fmaf(tc2[2*NN], wc[2*NN], a2);
    a3 = fmaf(tc2[3*NN], wc[3*NN], a3);
  }
  int j = jt*4 + jj;
  t2[((size_t)b*NN + o)*16 + j] = (a0 + a1) + (a2 + a3) + bias[o];
}

// tap offset table for im2col: k = ci*9 + dy*3 + dx -> offset into as[3][12][36]
constexpr int KOFF[27] = {
    0,   1,   2,  36,  37,  38,  72,  73,  74,
  432, 433, 434, 468, 469, 470, 504, 505, 506,
  864, 865, 866, 900, 901, 902, 936, 937, 938
};

// ---------------- K_h12: fully-MFMA fused stage-1 conv + GELU + stage-2 conv + residual ----------------
// Planar LDS layout: Au has 4 planes (plane q = channels 8q..8q+7 as 4 bf16-pair uints per px),
// plane stride PBQ uints (pad +8 so plane bases land on banks {0,8,16,24}).
// Per block: 8x32 output tile. h1 tile = 10x34 px (padded to 352 = 22 m-tiles), 32 ch.
// Stage-1: h1[px][c] = gelu( patch1[px][k27] x W1[k][c] ) via mfma (K padded to 32).
// Stage-2: out[px] = patch2[px][k=9x32] x w2[k] via mfma, A=weights (row 0), B=pixels from planes.
#define PBQ 1416
__global__ __launch_bounds__(256, 5) void k_h12(const float* __restrict__ a0,
    const float* __restrict__ y64, const float* __restrict__ M64,
    const float* __restrict__ y16, const float* __restrict__ M16,
    const float* __restrict__ w0, const float* __restrict__ b0,
    const float* __restrict__ w1, const float* __restrict__ b1,
    const float* __restrict__ vwsT, const float* __restrict__ vb0,
    const float* __restrict__ vb1, float* __restrict__ co){
  constexpr int AR = 12, AC = 36;
  __shared__ alignas(16) float as[3][AR][AC];     // a-tile, rows l0-2..l0+9, cols n0-2..n0+33
  __shared__ alignas(16) unsigned Au[4*PBQ];      // planar im2col/h1 buffer
  int tid = threadIdx.x;
  int l0 = blockIdx.x*8, n0 = blockIdx.y*32, b = blockIdx.z;
  int lane = tid & 63, wv = tid >> 6;

  // ---- Phase A: stage a-tile (ch0 = a0, ch1/ch2 = spline evals) ----
  float* asf = &as[0][0][0];
  for(int i=tid; i<3*AR*AC; i+=256){
    int ch = i/(AR*AC), rem = i%(AR*AC), yy = rem/AC, xx = rem%AC;
    int gl = l0 + yy - 2, gn = n0 + xx - 2;
    float v = 0.f;
    if(gl >= 0 && gl < LL && gn >= 0 && gn < NN){
      if(ch == 0)      v = a0[((size_t)b*LL + gl)*NN + gn];
      else if(ch == 1) v = spline_pt(y64, M64, 64, gl, b, gn);
      else             v = spline_pt(y16, M16, 16, gl, b, gn);
    }
    asf[i] = v;
  }

  // ---- stage-1 weight B-fragments: B[c][k], k = ci*9+dy*3+dx, pad k>=27 = 0 ----
  int colB = lane & 15, kq = (lane >> 4)*8;
  union { uint4 q; frag_ab f; } bw0, bw1;
  {
    float w8[2][8];
    #pragma unroll
    for(int nt=0;nt<2;nt++){
      #pragma unroll
      for(int j=0;j<8;j++){
        int k = kq + j;
        float w = 0.f;
        if(k < 27){
          int ci = k/9, r9 = k - ci*9, dy = r9/3, dx = r9 - dy*3;
          int c = nt*16 + colB;
          w = 0.5f*w1[((c*3+ci)*3+dy)*3+dx];
          if(dy==1 && dx==1) w += 0.5f*w0[c*3+ci];
        }
        w8[nt][j] = w;
      }
    }
    bw0.q = make_uint4(pbf2(w8[0][0],w8[0][1]), pbf2(w8[0][2],w8[0][3]),
                       pbf2(w8[0][4],w8[0][5]), pbf2(w8[0][6],w8[0][7]));
    bw1.q = make_uint4(pbf2(w8[1][0],w8[1][1]), pbf2(w8[1][2],w8[1][3]),
                       pbf2(w8[1][4],w8[1][5]), pbf2(w8[1][6],w8[1][7]));
  }
  float br0 = 0.5f*(b0[colB] + b1[colB]);
  float br1 = 0.5f*(b0[16 + colB] + b1[16 + colB]);
  __syncthreads();

  // ---- Phase B1: im2col build (2 threads per px, planes 2h and 2h+1) ----
  for(int base=0; base<352; base+=128){
    int px = base + (tid >> 1);
    int half = tid & 1;
    if(px < 352){
      uint4 oA, oB;
      if(px < 340){
        int yy = px/34, xx = px - yy*34;
        const float* bp = asf + yy*AC + xx;
        if(half == 0){
          oA.x = pbf2(bp[KOFF[0]],  bp[KOFF[1]]);
          oA.y = pbf2(bp[KOFF[2]],  bp[KOFF[3]]);
          oA.z = pbf2(bp[KOFF[4]],  bp[KOFF[5]]);
          oA.w = pbf2(bp[KOFF[6]],  bp[KOFF[7]]);
          oB.x = pbf2(bp[KOFF[8]],  bp[KOFF[9]]);
          oB.y = pbf2(bp[KOFF[10]], bp[KOFF[11]]);
          oB.z = pbf2(bp[KOFF[12]], bp[KOFF[13]]);
          oB.w = pbf2(bp[KOFF[14]], bp[KOFF[15]]);
        } else {
          oA.x = pbf2(bp[KOFF[16]], bp[KOFF[17]]);
          oA.y = pbf2(bp[KOFF[18]], bp[KOFF[19]]);
          oA.z = pbf2(bp[KOFF[20]], bp[KOFF[21]]);
          oA.w = pbf2(bp[KOFF[22]], bp[KOFF[23]]);
          oB.x = pbf2(bp[KOFF[24]], bp[KOFF[25]]);
          oB.y = pbf2(bp[KOFF[26]], 0.f);
          oB.z = 0u; oB.w = 0u;
        }
      } else {
        oA = make_uint4(0u,0u,0u,0u);
        oB = make_uint4(0u,0u,0u,0u);
      }
      *(uint4*)&Au[(2*half)*PBQ + px*4]     = oA;
      *(uint4*)&Au[(2*half+1)*PBQ + px*4]   = oB;
    }
  }
  __syncthreads();

  // ---- Phase B2: stage-1 MFMA per m-tile, gelu, pack bf16 back into planes ----
  unsigned short* h1h = (unsigned short*)Au;
  frag_cd zac = {0.f, 0.f, 0.f, 0.f};
  int qg = lane >> 4;
  int g0 = colB >> 3, s0 = colB & 7;
  for(int t = wv; t < 22; t += 4){
    int arow = t*16 + colB;
    union { uint4 q; frag_ab f; } av;
    av.q = *(const uint4*)&Au[qg*PBQ + arow*4];
    frag_cd d0 = __builtin_amdgcn_mfma_f32_16x16x32_bf16(av.f, bw0.f, zac, 0, 0, 0);
    frag_cd d1 = __builtin_amdgcn_mfma_f32_16x16x32_bf16(av.f, bw1.f, zac, 0, 0, 0);
    int px0 = t*16 + qg*4;
    #pragma unroll
    for(int r=0;r<4;r++){
      int px = px0 + r;
      h1h[(g0*PBQ + px*4)*2 + s0]     = bf16b(gelu_fast(d0[r] + br0));
      h1h[((g0+2)*PBQ + px*4)*2 + s0] = bf16b(gelu_fast(d1[r] + br1));
    }
  }
  __syncthreads();

  // ---- Phase B3: zero h1 at invalid borders (conv zero-padding semantics of stage 2) ----
  if(n0 == 0){
    for(int i=tid;i<10*32;i+=256){ int yy=i>>5, ch=i&31;
      h1h[((ch>>3)*PBQ + (yy*34)*4)*2 + (ch&7)] = 0; }
  }
  if(n0 == 96){
    for(int i=tid;i<10*32;i+=256){ int yy=i>>5, ch=i&31;
      h1h[((ch>>3)*PBQ + (yy*34+33)*4)*2 + (ch&7)] = 0; }
  }
  if(l0 == 0){
    for(int i=tid;i<34*32;i+=256){ int xx=i>>5, ch=i&31;
      h1h[((ch>>3)*PBQ + xx*4)*2 + (ch&7)] = 0; }
  }
  if(l0 == 760){
    for(int i=tid;i<34*32;i+=256){ int xx=i>>5, ch=i&31;
      h1h[((ch>>3)*PBQ + (9*34+xx)*4)*2 + (ch&7)] = 0; }
  }

  // ---- stage-2 weight A-fragments: A[m][c], only m==0 valid = w2[tap][c] ----
  union { uint4 q; frag_ab f; } aw[9];
  {
    bool wlane = (lane & 15) == 0;
    int c8 = qg*8;
    #pragma unroll
    for(int tap=0; tap<9; tap++){
      const float* wp = vwsT + tap*DMC + c8;
      float4 wa = *(const float4*)wp;
      float4 wb = *(const float4*)(wp+4);
      if(!wlane){ wa = make_float4(0.f,0.f,0.f,0.f); wb = make_float4(0.f,0.f,0.f,0.f); }
      aw[tap].q = make_uint4(pbf2(wa.x,wa.y), pbf2(wa.z,wa.w), pbf2(wb.x,wb.y), pbf2(wb.z,wb.w));
    }
  }
  float vbsum = vb0[0] + vb1[0];
  __syncthreads();

  // ---- Phase C: stage-2 conv via MFMA. A=weights (row 0), B=pixel patches from planes ----
  frag_cd cacc[4] = {};
  int baseoff[4];
  #pragma unroll
  for(int tt=0; tt<4; tt++){
    int px = (wv*4 + tt)*16 + (lane & 15);
    int yy = px >> 5, xx = px & 31;
    baseoff[tt] = qg*PBQ + (yy*34 + xx)*4;
  }
  #pragma unroll
  for(int dy=0; dy<3; dy++)
    #pragma unroll
    for(int dx=0; dx<3; dx++){
      int tap = dy*3 + dx;
      int off = (dy*34 + dx)*4;
      #pragma unroll
      for(int tt=0; tt<4; tt++){
        union { uint4 q; frag_ab f; } bv;
        bv.q = *(const uint4*)&Au[baseoff[tt] + off];
        cacc[tt] = __builtin_amdgcn_mfma_f32_16x16x32_bf16(aw[tap].f, bv.f, cacc[tt], 0, 0, 0);
      }
    }
  // D row 0 (= output channel 0) lives in lanes 0..15, reg 0
  if(lane < 16){
    #pragma unroll
    for(int tt=0; tt<4; tt++){
      int px = (wv*4 + tt)*16 + lane;
      int yy = px >> 5, xx = px & 31;
      float res = as[0][yy+2][xx+2];
      size_t idx = ((size_t)b*LL + l0 + yy)*NN + n0 + xx;
      co[idx] = cacc[tt][0] + vbsum + res;
    }
  }
}

// ---------------- K15: GEMM2 via bf16 MFMA 16x16x32, 64x32 tile + de-normalize ----------------
// A[m=(b,n)][k=l] = co[b][l][n], B[n'=p][k=l] = ldw[p][l]. 256 blocks -> full GPU.
__global__ __launch_bounds__(256) void k_gemm2(const float* __restrict__ a0, const float* __restrict__ ldw,
    const float* __restrict__ ldb, const float* __restrict__ sp, const float* __restrict__ s2p,
    float* __restrict__ out){
  __shared__ unsigned Asu[64*20];
  __shared__ unsigned Bsu[32*20];
  int tid = threadIdx.x;
  int row0 = blockIdx.x*64, p0 = blockIdx.y*32;
  int b = row0 >> 7, n0 = row0 & 127;
  int lane = tid & 63, wv = tid >> 6;
  frag_cd acc[2] = {};
  int an = tid & 63, akq = (tid >> 6)*8;
  int btk = tid & 15, blc = tid >> 4;
  unsigned ra[4], rbq[2];
  #pragma unroll
  for(int u=0;u<4;u++){
    float v0 = a0[((size_t)b*LL + akq + 2*u)*NN + n0 + an];
    float v1 = a0[((size_t)b*LL + akq + 2*u + 1)*NN + n0 + an];
    ra[u] = pbf2(v0, v1);
  }
  #pragma unroll
  for(int u=0;u<2;u++){
    const float* lp = ldw + (size_t)(p0 + blc + 16*u)*LL + 2*btk;
    rbq[u] = pbf2(lp[0], lp[1]);
  }
  int fr = wv*16 + (lane & 15);
  int fq = (lane >> 4)*4;
  for(int k0=0;k0<LL;k0+=32){
    *(uint4*)&Asu[an*20 + (akq>>1)] = make_uint4(ra[0], ra[1], ra[2], ra[3]);
    #pragma unroll
    for(int p=0;p<2;p++) Bsu[(blc + 16*p)*20 + btk] = rbq[p];
    __syncthreads();
    if(k0 + 32 < LL){
      #pragma unroll
      for(int u=0;u<4;u++){
        float v0 = a0[((size_t)b*LL + k0 + 32 + akq + 2*u)*NN + n0 + an];
        float v1 = a0[((size_t)b*LL + k0 + 32 + akq + 2*u + 1)*NN + n0 + an];
        ra[u] = pbf2(v0, v1);
      }
      #pragma unroll
      for(int u=0;u<2;u++){
        const float* lp = ldw + (size_t)(p0 + blc + 16*u)*LL + k0 + 32 + 2*btk;
        rbq[u] = pbf2(lp[0], lp[1]);
      }
    }
    frag_ab af = *(const frag_ab*)&Asu[fr*20 + fq];
    #pragma unroll
    for(int nt=0;nt<2;nt++){
      frag_ab bf = *(const frag_ab*)&Bsu[(nt*16 + (lane & 15))*20 + fq];
      acc[nt] = __builtin_amdgcn_mfma_f32_16x16x32_bf16(af, bf, acc[nt], 0, 0, 0);
    }
    __syncthreads();
  }
  int col = lane & 15, quad = lane >> 4;
  // de-norm constants for the 4 rows this lane owns
  float mu_r[4], sd_r[4];
  #pragma unroll
  for(int r=0;r<4;r++){
    int row = row0 + wv*16 + quad*4 + r;
    float ssum = 0.f, s2sum = 0.f;
    #pragma unroll
    for(int tq=0;tq<4;tq++){ ssum += sp[tq*2048 + row]; s2sum += s2p[tq*2048 + row]; }
    float mu = ssum*(1.f/512.f);
    float var = fmaxf(s2sum*(1.f/512.f) - mu*mu, 0.f);
    mu_r[r] = mu; sd_r[r] = sqrtf(var + EPSF);
  }
  #pragma unroll
  for(int nt=0;nt<2;nt++){
    int p = p0 + nt*16 + col;
    float lb = ldb[p];
    float4 st;
    st.x = (acc[nt][0] + lb)*sd_r[0] + mu_r[0];
    st.y = (acc[nt][1] + lb)*sd_r[1] + mu_r[1];
    st.z = (acc[nt][2] + lb)*sd_r[2] + mu_r[2];
    st.w = (acc[nt][3] + lb)*sd_r[3] + mu_r[3];
    *(float4*)&out[((size_t)b*PREDN + p)*NN + n0 + wv*16 + quad*4] = st;
  }
}

extern "C" void kernel_launch(void* const* d_in, const int* in_sizes, int n_in,
                              void* d_out, int out_size, void* d_ws, size_t ws_size,
                              hipStream_t stream){
  (void)in_sizes; (void)n_in; (void)out_size; (void)ws_size;
  const float* batch_x = (const float*)d_in[0];
  const float* le_w  = (const float*)d_in[4];
  const float* le_b  = (const float*)d_in[5];
  const float* c1_w  = (const float*)d_in[6];
  const float* c1_b  = (const float*)d_in[7];
  const float* bn1_g = (const float*)d_in[8];
  const float* bn1_b = (const float*)d_in[9];
  const float* c2_w  = (const float*)d_in[10];
  const float* c2_b  = (const float*)d_in[11];
  const float* bn2_g = (const float*)d_in[12];
  const float* bn2_b = (const float*)d_in[13];
  const float* i1_w0 = (const float*)d_in[14];
  const float* i1_b0 = (const float*)d_in[15];
  const float* i1_w1 = (const float*)d_in[16];
  const float* i1_b1 = (const float*)d_in[17];
  const float* i2_w0 = (const float*)d_in[18];
  const float* i2_b0 = (const float*)d_in[19];
  const float* i2_w1 = (const float*)d_in[20];
  const float* i2_b1 = (const float*)d_in[21];
  const float* ld_w  = (const float*)d_in[22];
  const float* ld_b  = (const float*)d_in[23];
  float* out = (float*)d_out;

  float* ws   = (float*)d_ws;
  float* sp   = ws;                        // 8192
  float* s2p  = sp + 8192;                 // 8192
  float* vwsT = s2p + 8192;                // 288 (+pad)
  float* wT1  = vwsT + 320;                // 196,608
  float* wT2  = wT1 + 196608;              // 65,536
  float* x    = wT2 + 65536;               // 1,572,864
  float* a0   = x + (size_t)BB*NN*LL;      // 1,572,864
  float* t1   = a0 + (size_t)BB*LL*NN;     // 131,072
  float* t1t  = t1 + (size_t)BB*NN*64;     // 131,072
  float* sc1  = t1t + (size_t)BB*64*NN;    // 128
  float* sh1  = sc1 + NN;                  // 128
  float* Msp1 = sh1 + NN;                  // 131,072
  float* t2   = Msp1 + (size_t)BB*64*NN;   // 32,768
  float* t2t  = t2 + (size_t)BB*NN*16;     // 32,768
  float* sc2  = t2t + (size_t)BB*16*NN;    // 128
  float* sh2  = sc2 + NN;                  // 128
  float* Msp2 = sh2 + NN;                  // 32,768
  float* co   = Msp2 + (size_t)BB*16*NN;   // 1,572,864 (h2 output + residual)

  k_pre<<<321, 128, 0, stream>>>(batch_x, i2_w0, i2_w1, c1_w, c2_w, sp, s2p, vwsT, wT1, wT2);
  k_gemm1<<<dim3(32,12), 256, 0, stream>>>(batch_x, le_w, le_b, sp, s2p, x, a0);
  k_conv1<<<dim3(16,BB), 512, 0, stream>>>(x, wT1, c1_b, t1);
  k_bnstats<<<NN, 256, 0, stream>>>(t1, bn1_g, bn1_b, BB, 64, sc1, sh1);
  k_bnelu_t<<<dim3(64,BB), NN, 0, stream>>>(t1, sc1, sh1, 64, t1t);
  k_spline_solve<64><<<BB, NN, 0, stream>>>(t1t, Msp1);
  k_conv2<<<dim3(4,BB), 512, 0, stream>>>(t1t, wT2, c2_b, t2);
  k_bnstats<<<NN, 256, 0, stream>>>(t2, bn2_g, bn2_b, BB, 16, sc2, sh2);
  k_bnelu_t<<<dim3(16,BB), NN, 0, stream>>>(t2, sc2, sh2, 16, t2t);
  k_spline_solve<16><<<BB, NN, 0, stream>>>(t2t, Msp2);
  k_h12<<<dim3(96,4,BB), 256, 0, stream>>>(a0, t1t, Msp1, t2t, Msp2,
                                           i1_w0, i1_b0, i1_w1, i1_b1,
                                           vwsT, i2_b0, i2_b1, co);
  k_gemm2<<<dim3(32,8), 256, 0, stream>>>(co, ld_w, ld_b, sp, s2p, out);
}

// Round 5
// 266.637 us; speedup vs baseline: 1.2174x; 1.1235x over previous
//
#include <hip/hip_runtime.h>
#include <hip/hip_bf16.h>
#include <math.h>

#define BB 16
#define TT 512
#define NN 128
#define PREDN 256
#define DMC 32
#define LL 768
constexpr float EPSF = 1e-5f;
using bf16 = __hip_bfloat16;
using frag_ab = __attribute__((ext_vector_type(8))) short;   // 8 bf16
using frag_cd = __attribute__((ext_vector_type(4))) float;   // 4 f32

__device__ __forceinline__ unsigned pbf2(float a, float b){
  union { bf16 h; unsigned short u; } x, y;
  x.h = __float2bfloat16(a); y.h = __float2bfloat16(b);
  return (unsigned)x.u | ((unsigned)y.u << 16);
}

__device__ __forceinline__ unsigned short bf16b(float v){
  union { bf16 h; unsigned short u; } x;
  x.h = __float2bfloat16(v);
  return x.u;
}

__device__ __forceinline__ float gelu_fast(float s){
  float s2v = s*s;
  float e = exp2f(s*fmaf(s2v, 0.10294396f, 2.30211806f));
  return s*e*__builtin_amdgcn_rcpf(e + 1.f);
}

// ---------------- K_pre: stats partials + weight transposes + ALL bf16 weight pre-packing ----------------
__global__ void k_pre(const float* __restrict__ bx, const float* __restrict__ v0,
                      const float* __restrict__ v1, const float* __restrict__ w1c,
                      const float* __restrict__ w2c, const float* __restrict__ w0s1,
                      const float* __restrict__ w1s1, const float* __restrict__ b0s1,
                      const float* __restrict__ b1s1, const float* __restrict__ lew,
                      const float* __restrict__ ldw,
                      float* __restrict__ sp, float* __restrict__ s2p,
                      float* __restrict__ wT1, float* __restrict__ wT2,
                      uint4* __restrict__ bwpk, uint4* __restrict__ awpk,
                      float* __restrict__ bsum, unsigned* __restrict__ lewbf,
                      unsigned* __restrict__ ldwbf){
  int blk = blockIdx.x;
  if(blk < 64){
    int b = blk >> 2, tq = blk & 3, n = threadIdx.x;
    const float* p = bx + (size_t)b*TT*NN + (size_t)tq*128*NN + n;
    float s = 0.f, s2 = 0.f;
    for(int t=0;t<128;t++){ float v = p[(size_t)t*NN]; s += v; s2 += v*v; }
    sp[tq*2048 + b*NN + n] = s;
    s2p[tq*2048 + b*NN + n] = s2;
  } else if(blk < 192){
    int o = blk - 64;
    for(int k=threadIdx.x; k<1536; k+=blockDim.x)
      wT1[(size_t)k*NN + o] = w1c[(size_t)o*1536 + k];
  } else if(blk < 320){
    int o = blk - 192;
    for(int k=threadIdx.x; k<512; k+=blockDim.x)
      wT2[(size_t)k*NN + o] = w2c[(size_t)o*512 + k];
  } else if(blk == 320){
    int i = threadIdx.x;
    // stage-1 weight fragments: bwpk[c*4+kq] = packed W1fold[k=kq*8+j][c]
    {
      int c = i >> 2, kq = i & 3;
      float w8[8];
      #pragma unroll
      for(int j=0;j<8;j++){
        int k = kq*8+j; float w = 0.f;
        if(k < 27){
          int ci = k/9, r9 = k - ci*9, dy = r9/3, dx = r9 - dy*3;
          w = 0.5f*w1s1[((c*3+ci)*3+dy)*3+dx];
          if(dy==1 && dx==1) w += 0.5f*w0s1[c*3+ci];
        }
        w8[j] = w;
      }
      bwpk[i] = make_uint4(pbf2(w8[0],w8[1]), pbf2(w8[2],w8[3]),
                           pbf2(w8[4],w8[5]), pbf2(w8[6],w8[7]));
    }
    // stage-2 weight fragments: awpk[tap*4+qg] = packed W2fold[tap][qg*8+j]
    if(i < 36){
      int tap = i >> 2, qq = i & 3, c8 = qq*8;
      float w8[8];
      #pragma unroll
      for(int j=0;j<8;j++){
        int c = c8 + j;
        w8[j] = 0.5f*v1[c*9 + tap] + ((tap==4) ? 0.5f*v0[c] : 0.f);
      }
      awpk[i] = make_uint4(pbf2(w8[0],w8[1]), pbf2(w8[2],w8[3]),
                           pbf2(w8[4],w8[5]), pbf2(w8[6],w8[7]));
    }
    if(i < 32) bsum[i] = 0.5f*(b0s1[i] + b1s1[i]);
  } else if(blk < 449){
    int o = blk - 321;              // 0..127, rows l = o*6..o*6+5
    for(int i=threadIdx.x; i<1536; i+=128){
      int l = o*6 + i/256, tp = i%256;
      lewbf[(size_t)l*256 + tp] = pbf2(lew[(size_t)l*TT + 2*tp], lew[(size_t)l*TT + 2*tp + 1]);
    }
  } else {
    int o = blk - 449;              // 0..63, rows p = o*4..o*4+3
    for(int i=threadIdx.x; i<1536; i+=128){
      int p = o*4 + i/384, tp = i%384;
      ldwbf[(size_t)p*384 + tp] = pbf2(ldw[(size_t)p*LL + 2*tp], ldw[(size_t)p*LL + 2*tp + 1]);
    }
  }
}

// ---------------- K_musd: per-row mu / rs ----------------
__global__ void k_musd(const float* __restrict__ sp, const float* __restrict__ s2p,
                       float* __restrict__ mu, float* __restrict__ rs){
  int i = blockIdx.x*256 + threadIdx.x;   // 0..2047
  float ss = 0.f, s2 = 0.f;
  #pragma unroll
  for(int tq=0;tq<4;tq++){ ss += sp[tq*2048 + i]; s2 += s2p[tq*2048 + i]; }
  float m = ss*(1.f/512.f);
  mu[i] = m;
  rs[i] = 1.f/sqrtf(fmaxf(s2*(1.f/512.f) - m*m, 0.f) + EPSF);
}

// ---------------- K_xbf: normalized input as bf16 [b][t][n] ----------------
__global__ __launch_bounds__(256) void k_xbf(const float* __restrict__ bx, const float* __restrict__ mu,
                                             const float* __restrict__ rs, unsigned short* __restrict__ xbf){
  int idx = blockIdx.x*256 + threadIdx.x;   // 0..131071
  int ng = idx & 15, t = (idx >> 4) & 511, b = idx >> 13;
  int n8 = ng*8;
  const float* p = bx + ((size_t)b*TT + t)*NN + n8;
  float4 va = *(const float4*)p, vb2 = *(const float4*)(p+4);
  const float* mp = mu + b*NN + n8;
  const float* rp = rs + b*NN + n8;
  float4 m0 = *(const float4*)mp, m1 = *(const float4*)(mp+4);
  float4 r0 = *(const float4*)rp, r1 = *(const float4*)(rp+4);
  uint4 o;
  o.x = pbf2((va.x - m0.x)*r0.x, (va.y - m0.y)*r0.y);
  o.y = pbf2((va.z - m0.z)*r0.z, (va.w - m0.w)*r0.w);
  o.z = pbf2((vb2.x - m1.x)*r1.x, (vb2.y - m1.y)*r1.y);
  o.w = pbf2((vb2.z - m1.z)*r1.z, (vb2.w - m1.w)*r1.w);
  *(uint4*)&xbf[((size_t)b*TT + t)*NN + n8] = o;
}

// ---------------- K1: GEMM1 via bf16 MFMA, A/B from pre-packed bf16 ----------------
__global__ __launch_bounds__(256) void k_gemm1(const unsigned short* __restrict__ xbf,
    const unsigned* __restrict__ lewbf, const float* __restrict__ leb,
    float* __restrict__ x, float* __restrict__ a0){
  __shared__ unsigned Asu[64*20];
  __shared__ unsigned Bsu[64*20];
  int tid = threadIdx.x;
  int row0 = blockIdx.x*64, l0 = blockIdx.y*64;
  int b = row0 >> 7, n0 = row0 & 127;
  int lane = tid & 63, wv = tid >> 6;
  frag_cd acc[4] = {};
  int an = tid & 63, akq = (tid >> 6)*8;
  int btk = tid & 15, blc = tid >> 4;
  unsigned ra[4], rbq[4];
  #pragma unroll
  for(int u=0;u<4;u++){
    unsigned lo = xbf[((size_t)b*TT + akq + 2*u)*NN + n0 + an];
    unsigned hi = xbf[((size_t)b*TT + akq + 2*u + 1)*NN + n0 + an];
    ra[u] = lo | (hi << 16);
    rbq[u] = lewbf[(size_t)(l0 + blc + 16*u)*256 + btk];
  }
  int fr = wv*16 + (lane & 15);
  int fq = (lane >> 4)*4;
  for(int k0=0;k0<TT;k0+=32){
    *(uint4*)&Asu[an*20 + (akq>>1)] = make_uint4(ra[0], ra[1], ra[2], ra[3]);
    #pragma unroll
    for(int p=0;p<4;p++) Bsu[(blc + 16*p)*20 + btk] = rbq[p];
    __syncthreads();
    if(k0 + 32 < TT){
      #pragma unroll
      for(int u=0;u<4;u++){
        unsigned lo = xbf[((size_t)b*TT + k0 + 32 + akq + 2*u)*NN + n0 + an];
        unsigned hi = xbf[((size_t)b*TT + k0 + 32 + akq + 2*u + 1)*NN + n0 + an];
        ra[u] = lo | (hi << 16);
        rbq[u] = lewbf[(size_t)(l0 + blc + 16*u)*256 + ((k0 + 32) >> 1) + btk];
      }
    }
    frag_ab af = *(const frag_ab*)&Asu[fr*20 + fq];
    #pragma unroll
    for(int nt=0;nt<4;nt++){
      frag_ab bf = *(const frag_ab*)&Bsu[(nt*16 + (lane & 15))*20 + fq];
      acc[nt] = __builtin_amdgcn_mfma_f32_16x16x32_bf16(af, bf, acc[nt], 0, 0, 0);
    }
    __syncthreads();
  }
  int col = lane & 15, quad = lane >> 4;
  #pragma unroll
  for(int nt=0;nt<4;nt++){
    int l = l0 + nt*16 + col;
    float lb = leb[l];
    #pragma unroll
    for(int r=0;r<4;r++){
      int m = wv*16 + quad*4 + r;
      x[(size_t)(row0 + m)*LL + l] = acc[nt][r] + lb;
    }
    float4 st;
    st.x = acc[nt][0] + lb;
    st.y = acc[nt][1] + lb;
    st.z = acc[nt][2] + lb;
    st.w = acc[nt][3] + lb;
    *(float4*)&a0[((size_t)b*LL + l)*NN + n0 + wv*16 + quad*4] = st;
  }
}

// ---------------- K3: conv1 (coalesced wT, 4 j per block) ----------------
__global__ __launch_bounds__(512) void k_conv1(const float* __restrict__ x, const float* __restrict__ wT,
                                               const float* __restrict__ bias, float* __restrict__ t1){
  __shared__ alignas(16) float xs[NN*48];
  int jt = blockIdx.x, b = blockIdx.y;
  int tid = threadIdx.x;
  int o = tid & 127, jj = tid >> 7;
  for(int i=tid;i<NN*48;i+=512){
    int ci = i/48, kk = i%48;
    xs[i] = x[((size_t)b*NN + ci)*LL + jt*48 + kk];
  }
  __syncthreads();
  float a0 = 0.f, a1 = 0.f, a2 = 0.f, a3 = 0.f;
  for(int ci=0;ci<NN;ci++){
    const float* xc = xs + ci*48 + jj*12;
    const float* wc = wT + (size_t)(ci*12)*NN + o;
    #pragma unroll
    for(int kk=0;kk<12;kk+=4){
      a0 = fmaf(xc[kk+0], wc[(size_t)(kk+0)*NN], a0);
      a1 = fmaf(xc[kk+1], wc[(size_t)(kk+1)*NN], a1);
      a2 = fmaf(xc[kk+2], wc[(size_t)(kk+2)*NN], a2);
      a3 = fmaf(xc[kk+3], wc[(size_t)(kk+3)*NN], a3);
    }
  }
  int j = jt*4 + jj;
  t1[((size_t)b*NN + o)*64 + j] = (a0 + a1) + (a2 + a3) + bias[o];
}

// ---------------- K4: BN stats per channel ----------------
__global__ void k_bnstats(const float* __restrict__ t, const float* __restrict__ g, const float* __restrict__ bb,
                          int Bcnt, int Jcnt, float* __restrict__ scale, float* __restrict__ shift){
  int o = blockIdx.x;
  int tot = Bcnt*Jcnt;
  float s = 0.f, s2 = 0.f;
  for(int i=threadIdx.x; i<tot; i+=blockDim.x){
    int b = i / Jcnt, j = i % Jcnt;
    float v = t[((size_t)b*NN + o)*Jcnt + j];
    s += v; s2 += v*v;
  }
  __shared__ float rs[256], rs2[256];
  rs[threadIdx.x] = s; rs2[threadIdx.x] = s2;
  __syncthreads();
  for(int st=128; st>0; st>>=1){
    if(threadIdx.x < st){ rs[threadIdx.x] += rs[threadIdx.x+st]; rs2[threadIdx.x] += rs2[threadIdx.x+st]; }
    __syncthreads();
  }
  if(threadIdx.x == 0){
    float mu = rs[0]/tot;
    float var = fmaxf(rs2[0]/tot - mu*mu, 0.f);
    float sc = g[o] * rsqrtf(var + EPSF);
    scale[o] = sc; shift[o] = bb[o] - mu*sc;
  }
}

// ---------------- K5: BN apply + ELU + transpose ----------------
__global__ void k_bnelu_t(const float* __restrict__ t, const float* __restrict__ scale,
                          const float* __restrict__ shift, int Jcnt, float* __restrict__ tt){
  int j = blockIdx.x, b = blockIdx.y, o = threadIdx.x;
  float v = t[((size_t)b*NN + o)*Jcnt + j]*scale[o] + shift[o];
  v = v > 0.f ? v : (expf(v) - 1.f);
  tt[((size_t)b*Jcnt + j)*NN + o] = v;
}

// ---------------- K6: spline tridiagonal solve (Thomas) ----------------
template<int LK>
__global__ void k_spline_solve(const float* __restrict__ y, float* __restrict__ M){
  constexpr int m = LK-2;
  const float Kc = 6.f*(LK-1)*(LK-1);
  __shared__ float cp[m];
  __shared__ float dp[m][NN];
  int b = blockIdx.x, c = threadIdx.x;
  if(c == 0){
    float cv = 0.25f; cp[0] = cv;
    for(int i=1;i<m;i++){ cv = 1.f/(4.f - cv); cp[i] = cv; }
  }
  __syncthreads();
  const float* yb = y + (size_t)b*LK*NN + c;
  float y0 = yb[0], y1 = yb[NN];
  float dprev = 0.f;
  for(int i=0;i<m;i++){
    float y2 = yb[(size_t)(i+2)*NN];
    float r = (y2 - 2.f*y1 + y0)*Kc;
    float d = (i == 0) ? r*0.25f : (r - dprev)*cp[i];
    dp[i][c] = d; dprev = d;
    y0 = y1; y1 = y2;
  }
  float* Mb = M + (size_t)b*LK*NN + c;
  float xv = dp[m-1][c];
  Mb[(size_t)m*NN] = xv;
  for(int i=m-2;i>=0;i--){
    xv = dp[i][c] - cp[i]*xv;
    Mb[(size_t)(i+1)*NN] = xv;
  }
  Mb[0] = 0.f;
  Mb[(size_t)(LK-1)*NN] = 0.f;
}

// ---------------- spline point evaluation (device) ----------------
__device__ __forceinline__ float spline_pt(const float* __restrict__ y, const float* __restrict__ M,
                                           int LK, int l, int b, int c){
  float hh = 1.f/(LK-1);
  float q = (float)l * (1.f/(LL-1));
  int idx = (int)floorf(q*(LK-1));
  if(idx > LK-2) idx = LK-2;
  float s = q - idx*hh;
  float u = hh - s;
  const float* yb = y + ((size_t)b*LK + idx)*NN + c;
  const float* Mb = M + ((size_t)b*LK + idx)*NN + c;
  float yi = yb[0], yi1 = yb[NN], M0 = Mb[0], M1 = Mb[NN];
  float hh6 = hh*hh/6.f;
  return (M0*u*u*u + M1*s*s*s)*(1.f/(6.f*hh))
       + (yi  - M0*hh6)*(u*(1.f/hh))
       + (yi1 - M1*hh6)*(s*(1.f/hh));
}

// ---------------- K8: conv2 (coalesced wT, 4 j per block) ----------------
__global__ __launch_bounds__(512) void k_conv2(const float* __restrict__ tt, const float* __restrict__ wT,
                                               const float* __restrict__ bias, float* __restrict__ t2){
  __shared__ alignas(16) float ts[16*NN];
  int jt = blockIdx.x, b = blockIdx.y;
  int tid = threadIdx.x;
  int o = tid & 127, jj = tid >> 7;
  for(int i=tid;i<16*NN;i+=512)
    ts[i] = tt[((size_t)b*64 + jt*16)*NN + i];
  __syncthreads();
  float a0 = 0.f, a1 = 0.f, a2 = 0.f, a3 = 0.f;
  for(int ci=0;ci<NN;ci++){
    const float* wc = wT + (size_t)(ci*4)*NN + o;
    const float* tc2 = ts + (jj*4)*NN + ci;
    a0 = fmaf(tc2[0*NN], wc[0*NN], a0);
    a1 = fmaf(tc2[1*NN], wc[1*NN], a1);
    a2 = fmaf(tc2[2*NN], wc[2*NN], a2);
    a3 = fmaf(tc2[3*NN], wc[3*NN], a3);
  }
  int j = jt*4 + jj;
  t2[((size_t)b*NN + o)*16 + j] = (a0 + a1) + (a2 + a3) + bias[o];
}

// tap offset table for im2col: k = ci*9 + dy*3 + dx -> ushort offset into AsBf[3][12][36]
constexpr int KOFF[27] = {
    0,   1,   2,  36,  37,  38,  72,  73,  74,
  432, 433, 434, 468, 469, 470, 504, 505, 506,
  864, 865, 866, 900, 901, 902, 936, 937, 938
};

// ---------------- K_h12: fully-MFMA fused stage-1 conv + GELU + stage-2 conv + residual ----------------
// All weight fragments pre-packed in k_pre. a-tile stored bf16 (converted once per element).
// B2 uses swapped operands mfma(W, patch) so each lane holds 4 consecutive channels of one px
// -> h1 writeback is 2x ds_write_b64 (bank-clean). co written as bf16 (bitwise = gemm2's rounding).
#define PBQ 1416
__global__ __launch_bounds__(256, 5) void k_h12(const float* __restrict__ a0,
    const float* __restrict__ y64, const float* __restrict__ M64,
    const float* __restrict__ y16, const float* __restrict__ M16,
    const uint4* __restrict__ bwpk, const uint4* __restrict__ awpk,
    const float* __restrict__ bsum, const float* __restrict__ vb0,
    const float* __restrict__ vb1, unsigned short* __restrict__ cobf){
  __shared__ alignas(16) unsigned short AsBf[3*12*36];   // bf16 a-tile [ch][yy][xx]
  __shared__ alignas(16) unsigned Au[4*PBQ];             // planar patch/h1 buffer
  int tid = threadIdx.x;
  int l0 = blockIdx.x*8, n0 = blockIdx.y*32, b = blockIdx.z;
  int lane = tid & 63, wv = tid >> 6;
  int colB = lane & 15, qg = lane >> 4;

  // ---- Phase A: stage a-tile as bf16 pairs (648 uint slots) ----
  for(int i=tid; i<648; i+=256){
    int ch = i/216, rem = i%216, yy = rem/18, xxp = rem%18;
    int xx = xxp*2;
    int gl = l0 + yy - 2, gn0 = n0 + xx - 2;
    float v0 = 0.f, v1 = 0.f;
    if(gl >= 0 && gl < LL){
      if(ch == 0){
        if((unsigned)gn0 < (unsigned)NN)     v0 = a0[((size_t)b*LL + gl)*NN + gn0];
        if((unsigned)(gn0+1) < (unsigned)NN) v1 = a0[((size_t)b*LL + gl)*NN + gn0 + 1];
      } else if(ch == 1){
        if((unsigned)gn0 < (unsigned)NN)     v0 = spline_pt(y64, M64, 64, gl, b, gn0);
        if((unsigned)(gn0+1) < (unsigned)NN) v1 = spline_pt(y64, M64, 64, gl, b, gn0+1);
      } else {
        if((unsigned)gn0 < (unsigned)NN)     v0 = spline_pt(y16, M16, 16, gl, b, gn0);
        if((unsigned)(gn0+1) < (unsigned)NN) v1 = spline_pt(y16, M16, 16, gl, b, gn0+1);
      }
    }
    *(unsigned*)&AsBf[i*2] = pbf2(v0, v1);
  }

  // ---- pre-packed stage-1 weight fragments + biases ----
  union U4 { uint4 q; frag_ab f; };
  U4 bw0, bw1;
  bw0.q = bwpk[colB*4 + qg];
  bw1.q = bwpk[(colB + 16)*4 + qg];
  float brA[4], brB[4];
  #pragma unroll
  for(int r=0;r<4;r++){ brA[r] = bsum[qg*4 + r]; brB[r] = bsum[16 + qg*4 + r]; }
  __syncthreads();

  // ---- Phase B1: build patches from bf16 tile (u16 reads + lshl_or, no conversions) ----
  for(int base=0; base<352; base+=128){
    int px = base + (tid >> 1);
    int half = tid & 1;
    if(px < 352){
      uint4 oA = make_uint4(0u,0u,0u,0u), oB = make_uint4(0u,0u,0u,0u);
      if(px < 340){
        int yy = px/34, xx = px - yy*34;
        const unsigned short* bp = AsBf + yy*36 + xx;
        if(half == 0){
          unsigned t0=bp[KOFF[0]],  t1=bp[KOFF[1]],  t2=bp[KOFF[2]],  t3=bp[KOFF[3]];
          unsigned t4=bp[KOFF[4]],  t5=bp[KOFF[5]],  t6=bp[KOFF[6]],  t7=bp[KOFF[7]];
          unsigned t8=bp[KOFF[8]],  t9=bp[KOFF[9]],  ta=bp[KOFF[10]], tb=bp[KOFF[11]];
          unsigned tc=bp[KOFF[12]], td=bp[KOFF[13]], te=bp[KOFF[14]], tf=bp[KOFF[15]];
          oA.x = t0 | (t1<<16); oA.y = t2 | (t3<<16); oA.z = t4 | (t5<<16); oA.w = t6 | (t7<<16);
          oB.x = t8 | (t9<<16); oB.y = ta | (tb<<16); oB.z = tc | (td<<16); oB.w = te | (tf<<16);
        } else {
          unsigned t0=bp[KOFF[16]], t1=bp[KOFF[17]], t2=bp[KOFF[18]], t3=bp[KOFF[19]];
          unsigned t4=bp[KOFF[20]], t5=bp[KOFF[21]], t6=bp[KOFF[22]], t7=bp[KOFF[23]];
          unsigned t8=bp[KOFF[24]], t9=bp[KOFF[25]], ta=bp[KOFF[26]];
          oA.x = t0 | (t1<<16); oA.y = t2 | (t3<<16); oA.z = t4 | (t5<<16); oA.w = t6 | (t7<<16);
          oB.x = t8 | (t9<<16); oB.y = ta;
        }
      }
      *(uint4*)&Au[(2*half)*PBQ + px*4]   = oA;
      *(uint4*)&Au[(2*half+1)*PBQ + px*4] = oB;
    }
  }
  __syncthreads();

  // ---- Phase B2: stage-1 MFMA (swapped: A=weights, B=patches), gelu, b64 writeback ----
  unsigned short* h1h = (unsigned short*)Au;
  frag_cd zac = {0.f, 0.f, 0.f, 0.f};
  for(int t = wv; t < 22; t += 4){
    int px = t*16 + colB;
    U4 av;
    av.q = *(const uint4*)&Au[qg*PBQ + px*4];
    frag_cd d0 = __builtin_amdgcn_mfma_f32_16x16x32_bf16(bw0.f, av.f, zac, 0, 0, 0);
    frag_cd d1 = __builtin_amdgcn_mfma_f32_16x16x32_bf16(bw1.f, av.f, zac, 0, 0, 0);
    unsigned u0 = pbf2(gelu_fast(d0[0] + brA[0]), gelu_fast(d0[1] + brA[1]));
    unsigned u1 = pbf2(gelu_fast(d0[2] + brA[2]), gelu_fast(d0[3] + brA[3]));
    unsigned u2 = pbf2(gelu_fast(d1[0] + brB[0]), gelu_fast(d1[1] + brB[1]));
    unsigned u3 = pbf2(gelu_fast(d1[2] + brB[2]), gelu_fast(d1[3] + brB[3]));
    int lo = (qg >> 1)*PBQ + px*4 + (qg & 1)*2;
    *(uint2*)&Au[lo]           = make_uint2(u0, u1);
    *(uint2*)&Au[2*PBQ + lo]   = make_uint2(u2, u3);
  }
  __syncthreads();

  // ---- Phase B3: zero h1 at invalid borders ----
  if(n0 == 0){
    for(int i=tid;i<10*32;i+=256){ int yy=i>>5, ch=i&31;
      h1h[((ch>>3)*PBQ + (yy*34)*4)*2 + (ch&7)] = 0; }
  }
  if(n0 == 96){
    for(int i=tid;i<10*32;i+=256){ int yy=i>>5, ch=i&31;
      h1h[((ch>>3)*PBQ + (yy*34+33)*4)*2 + (ch&7)] = 0; }
  }
  if(l0 == 0){
    for(int i=tid;i<34*32;i+=256){ int xx=i>>5, ch=i&31;
      h1h[((ch>>3)*PBQ + xx*4)*2 + (ch&7)] = 0; }
  }
  if(l0 == 760){
    for(int i=tid;i<34*32;i+=256){ int xx=i>>5, ch=i&31;
      h1h[((ch>>3)*PBQ + (9*34+xx)*4)*2 + (ch&7)] = 0; }
  }

  // ---- pre-packed stage-2 weight fragments (rows 1-15 of D never read -> no lane masking) ----
  U4 aw[9];
  #pragma unroll
  for(int tap=0; tap<9; tap++) aw[tap].q = awpk[tap*4 + qg];
  float vbsum = vb0[0] + vb1[0];
  __syncthreads();

  // ---- Phase C: stage-2 conv via MFMA, B-frags direct from planar h1 ----
  frag_cd cacc[4] = {};
  int baseoff[4];
  #pragma unroll
  for(int tt=0; tt<4; tt++){
    int px = (wv*4 + tt)*16 + colB;
    int yy = px >> 5, xx = px & 31;
    baseoff[tt] = qg*PBQ + (yy*34 + xx)*4;
  }
  #pragma unroll
  for(int dy=0; dy<3; dy++)
    #pragma unroll
    for(int dx=0; dx<3; dx++){
      int tap = dy*3 + dx;
      int off = (dy*34 + dx)*4;
      #pragma unroll
      for(int tt=0; tt<4; tt++){
        U4 bv;
        bv.q = *(const uint4*)&Au[baseoff[tt] + off];
        cacc[tt] = __builtin_amdgcn_mfma_f32_16x16x32_bf16(aw[tap].f, bv.f, cacc[tt], 0, 0, 0);
      }
    }
  if(lane < 16){
    #pragma unroll
    for(int tt=0; tt<4; tt++){
      int px = (wv*4 + tt)*16 + lane;
      int yy = px >> 5, xx = px & 31;
      size_t idx = ((size_t)b*LL + l0 + yy)*NN + n0 + xx;
      cobf[idx] = bf16b(cacc[tt][0] + vbsum + a0[idx]);
    }
  }
}

// ---------------- K15: GEMM2, A from bf16 co, B pre-packed + de-normalize ----------------
__global__ __launch_bounds__(256) void k_gemm2(const unsigned short* __restrict__ cobf,
    const unsigned* __restrict__ ldwbf, const float* __restrict__ ldb,
    const float* __restrict__ sp, const float* __restrict__ s2p,
    float* __restrict__ out){
  __shared__ unsigned Asu[64*20];
  __shared__ unsigned Bsu[32*20];
  int tid = threadIdx.x;
  int row0 = blockIdx.x*64, p0 = blockIdx.y*32;
  int b = row0 >> 7, n0 = row0 & 127;
  int lane = tid & 63, wv = tid >> 6;
  frag_cd acc[2] = {};
  int an = tid & 63, akq = (tid >> 6)*8;
  int btk = tid & 15, blc = tid >> 4;
  unsigned ra[4], rbq[2];
  #pragma unroll
  for(int u=0;u<4;u++){
    unsigned lo = cobf[((size_t)b*LL + akq + 2*u)*NN + n0 + an];
    unsigned hi = cobf[((size_t)b*LL + akq + 2*u + 1)*NN + n0 + an];
    ra[u] = lo | (hi << 16);
  }
  #pragma unroll
  for(int u=0;u<2;u++)
    rbq[u] = ldwbf[(size_t)(p0 + blc + 16*u)*384 + btk];
  int fr = wv*16 + (lane & 15);
  int fq = (lane >> 4)*4;
  for(int k0=0;k0<LL;k0+=32){
    *(uint4*)&Asu[an*20 + (akq>>1)] = make_uint4(ra[0], ra[1], ra[2], ra[3]);
    #pragma unroll
    for(int p=0;p<2;p++) Bsu[(blc + 16*p)*20 + btk] = rbq[p];
    __syncthreads();
    if(k0 + 32 < LL){
      #pragma unroll
      for(int u=0;u<4;u++){
        unsigned lo = cobf[((size_t)b*LL + k0 + 32 + akq + 2*u)*NN + n0 + an];
        unsigned hi = cobf[((size_t)b*LL + k0 + 32 + akq + 2*u + 1)*NN + n0 + an];
        ra[u] = lo | (hi << 16);
      }
      #pragma unroll
      for(int u=0;u<2;u++)
        rbq[u] = ldwbf[(size_t)(p0 + blc + 16*u)*384 + ((k0 + 32) >> 1) + btk];
    }
    frag_ab af = *(const frag_ab*)&Asu[fr*20 + fq];
    #pragma unroll
    for(int nt=0;nt<2;nt++){
      frag_ab bf = *(const frag_ab*)&Bsu[(nt*16 + (lane & 15))*20 + fq];
      acc[nt] = __builtin_amdgcn_mfma_f32_16x16x32_bf16(af, bf, acc[nt], 0, 0, 0);
    }
    __syncthreads();
  }
  int col = lane & 15, quad = lane >> 4;
  float mu_r[4], sd_r[4];
  #pragma unroll
  for(int r=0;r<4;r++){
    int row = row0 + wv*16 + quad*4 + r;
    float ssum = 0.f, s2sum = 0.f;
    #pragma unroll
    for(int tq=0;tq<4;tq++){ ssum += sp[tq*2048 + row]; s2sum += s2p[tq*2048 + row]; }
    float mu = ssum*(1.f/512.f);
    float var = fmaxf(s2sum*(1.f/512.f) - mu*mu, 0.f);
    mu_r[r] = mu; sd_r[r] = sqrtf(var + EPSF);
  }
  #pragma unroll
  for(int nt=0;nt<2;nt++){
    int p = p0 + nt*16 + col;
    float lb = ldb[p];
    float4 st;
    st.x = (acc[nt][0] + lb)*sd_r[0] + mu_r[0];
    st.y = (acc[nt][1] + lb)*sd_r[1] + mu_r[1];
    st.z = (acc[nt][2] + lb)*sd_r[2] + mu_r[2];
    st.w = (acc[nt][3] + lb)*sd_r[3] + mu_r[3];
    *(float4*)&out[((size_t)b*PREDN + p)*NN + n0 + wv*16 + quad*4] = st;
  }
}

extern "C" void kernel_launch(void* const* d_in, const int* in_sizes, int n_in,
                              void* d_out, int out_size, void* d_ws, size_t ws_size,
                              hipStream_t stream){
  (void)in_sizes; (void)n_in; (void)out_size; (void)ws_size;
  const float* batch_x = (const float*)d_in[0];
  const float* le_w  = (const float*)d_in[4];
  const float* le_b  = (const float*)d_in[5];
  const float* c1_w  = (const float*)d_in[6];
  const float* c1_b  = (const float*)d_in[7];
  const float* bn1_g = (const float*)d_in[8];
  const float* bn1_b = (const float*)d_in[9];
  const float* c2_w  = (const float*)d_in[10];
  const float* c2_b  = (const float*)d_in[11];
  const float* bn2_g = (const float*)d_in[12];
  const float* bn2_b = (const float*)d_in[13];
  const float* i1_w0 = (const float*)d_in[14];
  const float* i1_b0 = (const float*)d_in[15];
  const float* i1_w1 = (const float*)d_in[16];
  const float* i1_b1 = (const float*)d_in[17];
  const float* i2_w0 = (const float*)d_in[18];
  const float* i2_b0 = (const float*)d_in[19];
  const float* i2_w1 = (const float*)d_in[20];
  const float* i2_b1 = (const float*)d_in[21];
  const float* ld_w  = (const float*)d_in[22];
  const float* ld_b  = (const float*)d_in[23];
  float* out = (float*)d_out;

  float* ws   = (float*)d_ws;
  float* sp   = ws;                          // 8192
  float* s2p  = sp + 8192;                   // 8192
  float* wT1  = s2p + 8192;                  // 196,608
  float* wT2  = wT1 + 196608;                // 65,536
  float* x    = wT2 + 65536;                 // 1,572,864
  float* a0   = x + (size_t)BB*NN*LL;        // 1,572,864
  float* t1   = a0 + (size_t)BB*LL*NN;       // 131,072
  float* t1t  = t1 + (size_t)BB*NN*64;       // 131,072
  float* sc1  = t1t + (size_t)BB*64*NN;      // 128
  float* sh1  = sc1 + NN;                    // 128
  float* Msp1 = sh1 + NN;                    // 131,072
  float* t2   = Msp1 + (size_t)BB*64*NN;     // 32,768
  float* t2t  = t2 + (size_t)BB*NN*16;       // 32,768
  float* sc2  = t2t + (size_t)BB*16*NN;      // 128
  float* sh2  = sc2 + NN;                    // 128
  float* Msp2 = sh2 + NN;                    // 32,768
  float* muv  = Msp2 + (size_t)BB*16*NN;     // 2048
  float* rsv  = muv + 2048;                  // 2048
  float* fB1  = rsv + 2048;
  unsigned short* xbf = (unsigned short*)fB1;       // 1,048,576 ushorts = 524,288 floats
  float* fB2  = fB1 + 524288;
  unsigned* lewbf = (unsigned*)fB2;                 // 196,608 uints
  float* fB3  = fB2 + 196608;
  unsigned* ldwbf = (unsigned*)fB3;                 // 98,304 uints
  float* fB4  = fB3 + 98304;
  uint4* bwpk = (uint4*)fB4;                        // 128 uint4 = 512 floats
  float* fB5  = fB4 + 512;
  uint4* awpk = (uint4*)fB5;                        // 36 uint4 = 144 floats
  float* fB6  = fB5 + 144;
  float* bsum = fB6;                                // 32
  float* fB7  = fB6 + 32;
  unsigned short* cobf = (unsigned short*)fB7;      // 1,572,864 ushorts = 786,432 floats

  k_pre<<<513, 128, 0, stream>>>(batch_x, i2_w0, i2_w1, c1_w, c2_w,
                                 i1_w0, i1_w1, i1_b0, i1_b1, le_w, ld_w,
                                 sp, s2p, wT1, wT2, bwpk, awpk, bsum, lewbf, ldwbf);
  k_musd<<<8, 256, 0, stream>>>(sp, s2p, muv, rsv);
  k_xbf<<<512, 256, 0, stream>>>(batch_x, muv, rsv, xbf);
  k_gemm1<<<dim3(32,12), 256, 0, stream>>>(xbf, lewbf, le_b, x, a0);
  k_conv1<<<dim3(16,BB), 512, 0, stream>>>(x, wT1, c1_b, t1);
  k_bnstats<<<NN, 256, 0, stream>>>(t1, bn1_g, bn1_b, BB, 64, sc1, sh1);
  k_bnelu_t<<<dim3(64,BB), NN, 0, stream>>>(t1, sc1, sh1, 64, t1t);
  k_spline_solve<64><<<BB, NN, 0, stream>>>(t1t, Msp1);
  k_conv2<<<dim3(4,BB), 512, 0, stream>>>(t1t, wT2, c2_b, t2);
  k_bnstats<<<NN, 256, 0, stream>>>(t2, bn2_g, bn2_b, BB, 16, sc2, sh2);
  k_bnelu_t<<<dim3(16,BB), NN, 0, stream>>>(t2, sc2, sh2, 16, t2t);
  k_spline_solve<16><<<BB, NN, 0, stream>>>(t2t, Msp2);
  k_h12<<<dim3(96,4,BB), 256, 0, stream>>>(a0, t1t, Msp1, t2t, Msp2,
                                           bwpk, awpk, bsum, i2_b0, i2_b1, cobf);
  k_gemm2<<<dim3(32,8), 256, 0, stream>>>(cobf, ldwbf, ld_b, sp, s2p, out);
}

// Round 6
// 258.367 us; speedup vs baseline: 1.2564x; 1.0320x over previous
//
#include <hip/hip_runtime.h>
#include <hip/hip_bf16.h>
#include <math.h>

#define BB 16
#define TT 512
#define NN 128
#define PREDN 256
#define DMC 32
#define LL 768
constexpr float EPSF = 1e-5f;
using bf16 = __hip_bfloat16;
using frag_ab = __attribute__((ext_vector_type(8))) short;   // 8 bf16
using frag_cd = __attribute__((ext_vector_type(4))) float;   // 4 f32

__device__ __forceinline__ unsigned pbf2(float a, float b){
  union { bf16 h; unsigned short u; } x, y;
  x.h = __float2bfloat16(a); y.h = __float2bfloat16(b);
  return (unsigned)x.u | ((unsigned)y.u << 16);
}

__device__ __forceinline__ unsigned short bf16b(float v){
  union { bf16 h; unsigned short u; } x;
  x.h = __float2bfloat16(v);
  return x.u;
}

__device__ __forceinline__ float gelu_fast(float s){
  float s2v = s*s;
  float e = exp2f(s*fmaf(s2v, 0.10294396f, 2.30211806f));
  return s*e*__builtin_amdgcn_rcpf(e + 1.f);
}

// ---------------- K_pre: stats partials + weight transposes + ALL bf16 weight pre-packing ----------------
__global__ void k_pre(const float* __restrict__ bx, const float* __restrict__ v0,
                      const float* __restrict__ v1, const float* __restrict__ w1c,
                      const float* __restrict__ w2c, const float* __restrict__ w0s1,
                      const float* __restrict__ w1s1, const float* __restrict__ b0s1,
                      const float* __restrict__ b1s1, const float* __restrict__ lew,
                      const float* __restrict__ ldw,
                      float* __restrict__ sp, float* __restrict__ s2p,
                      float* __restrict__ wT1, float* __restrict__ wT2,
                      uint4* __restrict__ bwpk, uint4* __restrict__ awpk,
                      float* __restrict__ bsum, unsigned* __restrict__ lewbf,
                      unsigned* __restrict__ ldwbf){
  int blk = blockIdx.x;
  if(blk < 64){
    int b = blk >> 2, tq = blk & 3, n = threadIdx.x;
    const float* p = bx + (size_t)b*TT*NN + (size_t)tq*128*NN + n;
    float s = 0.f, s2 = 0.f;
    for(int t=0;t<128;t++){ float v = p[(size_t)t*NN]; s += v; s2 += v*v; }
    sp[tq*2048 + b*NN + n] = s;
    s2p[tq*2048 + b*NN + n] = s2;
  } else if(blk < 192){
    int o = blk - 64;
    for(int k=threadIdx.x; k<1536; k+=blockDim.x)
      wT1[(size_t)k*NN + o] = w1c[(size_t)o*1536 + k];
  } else if(blk < 320){
    int o = blk - 192;
    for(int k=threadIdx.x; k<512; k+=blockDim.x)
      wT2[(size_t)k*NN + o] = w2c[(size_t)o*512 + k];
  } else if(blk == 320){
    int i = threadIdx.x;
    // stage-1 weight fragments: bwpk[c*4+kq] = packed W1fold[k=kq*8+j][c]
    {
      int c = i >> 2, kq = i & 3;
      float w8[8];
      #pragma unroll
      for(int j=0;j<8;j++){
        int k = kq*8+j; float w = 0.f;
        if(k < 27){
          int ci = k/9, r9 = k - ci*9, dy = r9/3, dx = r9 - dy*3;
          w = 0.5f*w1s1[((c*3+ci)*3+dy)*3+dx];
          if(dy==1 && dx==1) w += 0.5f*w0s1[c*3+ci];
        }
        w8[j] = w;
      }
      bwpk[i] = make_uint4(pbf2(w8[0],w8[1]), pbf2(w8[2],w8[3]),
                           pbf2(w8[4],w8[5]), pbf2(w8[6],w8[7]));
    }
    // stage-2 weight fragments: awpk[tap*4+qg] = packed W2fold[tap][qg*8+j]
    if(i < 36){
      int tap = i >> 2, qq = i & 3, c8 = qq*8;
      float w8[8];
      #pragma unroll
      for(int j=0;j<8;j++){
        int c = c8 + j;
        w8[j] = 0.5f*v1[c*9 + tap] + ((tap==4) ? 0.5f*v0[c] : 0.f);
      }
      awpk[i] = make_uint4(pbf2(w8[0],w8[1]), pbf2(w8[2],w8[3]),
                           pbf2(w8[4],w8[5]), pbf2(w8[6],w8[7]));
    }
    if(i < 32) bsum[i] = 0.5f*(b0s1[i] + b1s1[i]);
  } else if(blk < 449){
    int o = blk - 321;              // 0..127, rows l = o*6..o*6+5
    for(int i=threadIdx.x; i<1536; i+=128){
      int l = o*6 + i/256, tp = i%256;
      lewbf[(size_t)l*256 + tp] = pbf2(lew[(size_t)l*TT + 2*tp], lew[(size_t)l*TT + 2*tp + 1]);
    }
  } else {
    int o = blk - 449;              // 0..63, rows p = o*4..o*4+3
    for(int i=threadIdx.x; i<1536; i+=128){
      int p = o*4 + i/384, tp = i%384;
      ldwbf[(size_t)p*384 + tp] = pbf2(ldw[(size_t)p*LL + 2*tp], ldw[(size_t)p*LL + 2*tp + 1]);
    }
  }
}

// ---------------- K_musd: per-row mu / rs ----------------
__global__ void k_musd(const float* __restrict__ sp, const float* __restrict__ s2p,
                       float* __restrict__ mu, float* __restrict__ rs){
  int i = blockIdx.x*256 + threadIdx.x;   // 0..2047
  float ss = 0.f, s2 = 0.f;
  #pragma unroll
  for(int tq=0;tq<4;tq++){ ss += sp[tq*2048 + i]; s2 += s2p[tq*2048 + i]; }
  float m = ss*(1.f/512.f);
  mu[i] = m;
  rs[i] = 1.f/sqrtf(fmaxf(s2*(1.f/512.f) - m*m, 0.f) + EPSF);
}

// ---------------- K_xbf: normalized input as bf16 [b][t][n] ----------------
__global__ __launch_bounds__(256) void k_xbf(const float* __restrict__ bx, const float* __restrict__ mu,
                                             const float* __restrict__ rs, unsigned short* __restrict__ xbf){
  int idx = blockIdx.x*256 + threadIdx.x;   // 0..131071
  int ng = idx & 15, t = (idx >> 4) & 511, b = idx >> 13;
  int n8 = ng*8;
  const float* p = bx + ((size_t)b*TT + t)*NN + n8;
  float4 va = *(const float4*)p, vb2 = *(const float4*)(p+4);
  const float* mp = mu + b*NN + n8;
  const float* rp = rs + b*NN + n8;
  float4 m0 = *(const float4*)mp, m1 = *(const float4*)(mp+4);
  float4 r0 = *(const float4*)rp, r1 = *(const float4*)(rp+4);
  uint4 o;
  o.x = pbf2((va.x - m0.x)*r0.x, (va.y - m0.y)*r0.y);
  o.y = pbf2((va.z - m0.z)*r0.z, (va.w - m0.w)*r0.w);
  o.z = pbf2((vb2.x - m1.x)*r1.x, (vb2.y - m1.y)*r1.y);
  o.w = pbf2((vb2.z - m1.z)*r1.z, (vb2.w - m1.w)*r1.w);
  *(uint4*)&xbf[((size_t)b*TT + t)*NN + n8] = o;
}

// ---------------- K1: GEMM1 via bf16 MFMA, A/B from pre-packed bf16 ----------------
__global__ __launch_bounds__(256) void k_gemm1(const unsigned short* __restrict__ xbf,
    const unsigned* __restrict__ lewbf, const float* __restrict__ leb,
    float* __restrict__ x, float* __restrict__ a0){
  __shared__ unsigned Asu[64*20];
  __shared__ unsigned Bsu[64*20];
  int tid = threadIdx.x;
  int row0 = blockIdx.x*64, l0 = blockIdx.y*64;
  int b = row0 >> 7, n0 = row0 & 127;
  int lane = tid & 63, wv = tid >> 6;
  frag_cd acc[4] = {};
  int an = tid & 63, akq = (tid >> 6)*8;
  int btk = tid & 15, blc = tid >> 4;
  unsigned ra[4], rbq[4];
  #pragma unroll
  for(int u=0;u<4;u++){
    unsigned lo = xbf[((size_t)b*TT + akq + 2*u)*NN + n0 + an];
    unsigned hi = xbf[((size_t)b*TT + akq + 2*u + 1)*NN + n0 + an];
    ra[u] = lo | (hi << 16);
    rbq[u] = lewbf[(size_t)(l0 + blc + 16*u)*256 + btk];
  }
  int fr = wv*16 + (lane & 15);
  int fq = (lane >> 4)*4;
  for(int k0=0;k0<TT;k0+=32){
    *(uint4*)&Asu[an*20 + (akq>>1)] = make_uint4(ra[0], ra[1], ra[2], ra[3]);
    #pragma unroll
    for(int p=0;p<4;p++) Bsu[(blc + 16*p)*20 + btk] = rbq[p];
    __syncthreads();
    if(k0 + 32 < TT){
      #pragma unroll
      for(int u=0;u<4;u++){
        unsigned lo = xbf[((size_t)b*TT + k0 + 32 + akq + 2*u)*NN + n0 + an];
        unsigned hi = xbf[((size_t)b*TT + k0 + 32 + akq + 2*u + 1)*NN + n0 + an];
        ra[u] = lo | (hi << 16);
        rbq[u] = lewbf[(size_t)(l0 + blc + 16*u)*256 + ((k0 + 32) >> 1) + btk];
      }
    }
    frag_ab af = *(const frag_ab*)&Asu[fr*20 + fq];
    #pragma unroll
    for(int nt=0;nt<4;nt++){
      frag_ab bf = *(const frag_ab*)&Bsu[(nt*16 + (lane & 15))*20 + fq];
      acc[nt] = __builtin_amdgcn_mfma_f32_16x16x32_bf16(af, bf, acc[nt], 0, 0, 0);
    }
    __syncthreads();
  }
  int col = lane & 15, quad = lane >> 4;
  #pragma unroll
  for(int nt=0;nt<4;nt++){
    int l = l0 + nt*16 + col;
    float lb = leb[l];
    #pragma unroll
    for(int r=0;r<4;r++){
      int m = wv*16 + quad*4 + r;
      x[(size_t)(row0 + m)*LL + l] = acc[nt][r] + lb;
    }
    float4 st;
    st.x = acc[nt][0] + lb;
    st.y = acc[nt][1] + lb;
    st.z = acc[nt][2] + lb;
    st.w = acc[nt][3] + lb;
    *(float4*)&a0[((size_t)b*LL + l)*NN + n0 + wv*16 + quad*4] = st;
  }
}

// ---------------- K3: conv1 (coalesced wT, 4 j per block) ----------------
__global__ __launch_bounds__(512) void k_conv1(const float* __restrict__ x, const float* __restrict__ wT,
                                               const float* __restrict__ bias, float* __restrict__ t1){
  __shared__ alignas(16) float xs[NN*48];
  int jt = blockIdx.x, b = blockIdx.y;
  int tid = threadIdx.x;
  int o = tid & 127, jj = tid >> 7;
  for(int i=tid;i<NN*48;i+=512){
    int ci = i/48, kk = i%48;
    xs[i] = x[((size_t)b*NN + ci)*LL + jt*48 + kk];
  }
  __syncthreads();
  float a0 = 0.f, a1 = 0.f, a2 = 0.f, a3 = 0.f;
  for(int ci=0;ci<NN;ci++){
    const float* xc = xs + ci*48 + jj*12;
    const float* wc = wT + (size_t)(ci*12)*NN + o;
    #pragma unroll
    for(int kk=0;kk<12;kk+=4){
      a0 = fmaf(xc[kk+0], wc[(size_t)(kk+0)*NN], a0);
      a1 = fmaf(xc[kk+1], wc[(size_t)(kk+1)*NN], a1);
      a2 = fmaf(xc[kk+2], wc[(size_t)(kk+2)*NN], a2);
      a3 = fmaf(xc[kk+3], wc[(size_t)(kk+3)*NN], a3);
    }
  }
  int j = jt*4 + jj;
  t1[((size_t)b*NN + o)*64 + j] = (a0 + a1) + (a2 + a3) + bias[o];
}

// ---------------- K4: BN stats per channel ----------------
__global__ void k_bnstats(const float* __restrict__ t, const float* __restrict__ g, const float* __restrict__ bb,
                          int Bcnt, int Jcnt, float* __restrict__ scale, float* __restrict__ shift){
  int o = blockIdx.x;
  int tot = Bcnt*Jcnt;
  float s = 0.f, s2 = 0.f;
  for(int i=threadIdx.x; i<tot; i+=blockDim.x){
    int b = i / Jcnt, j = i % Jcnt;
    float v = t[((size_t)b*NN + o)*Jcnt + j];
    s += v; s2 += v*v;
  }
  __shared__ float rs[256], rs2[256];
  rs[threadIdx.x] = s; rs2[threadIdx.x] = s2;
  __syncthreads();
  for(int st=128; st>0; st>>=1){
    if(threadIdx.x < st){ rs[threadIdx.x] += rs[threadIdx.x+st]; rs2[threadIdx.x] += rs2[threadIdx.x+st]; }
    __syncthreads();
  }
  if(threadIdx.x == 0){
    float mu = rs[0]/tot;
    float var = fmaxf(rs2[0]/tot - mu*mu, 0.f);
    float sc = g[o] * rsqrtf(var + EPSF);
    scale[o] = sc; shift[o] = bb[o] - mu*sc;
  }
}

// ---------------- K_bnspl: fused BN apply + ELU + transpose + spline Thomas solve ----------------
template<int LK>
__global__ __launch_bounds__(256) void k_bnspl(const float* __restrict__ t, const float* __restrict__ scale,
    const float* __restrict__ shift, float* __restrict__ tt, float* __restrict__ M){
  constexpr int m = LK-2;
  __shared__ float yt[LK][NN+1];
  __shared__ float cp[m];
  __shared__ float dp[m][NN];
  int b = blockIdx.x, tid = threadIdx.x;
  // phase 1: BN+ELU, t[b][o][LK] -> yt[j][o] (coalesced global reads)
  for(int i=tid; i<LK*NN; i+=256){
    int o = i / LK, j = i - o*LK;
    float v = t[((size_t)b*NN + o)*LK + j]*scale[o] + shift[o];
    v = v > 0.f ? v : (expf(v) - 1.f);
    yt[j][o] = v;
  }
  if(tid == 0){
    float cv = 0.25f; cp[0] = cv;
    for(int i=1;i<m;i++){ cv = 1.f/(4.f - cv); cp[i] = cv; }
  }
  __syncthreads();
  // phase 1b: coalesced tt writeback [b][j][o]
  for(int i=tid; i<LK*NN; i+=256){
    int j = i >> 7, o = i & 127;
    tt[((size_t)b*LK + j)*NN + o] = yt[j][o];
  }
  // phase 2: Thomas solve per channel c (threads 0..127)
  if(tid < NN){
    int c = tid;
    const float Kc = 6.f*(LK-1)*(LK-1);
    float y0 = yt[0][c], y1 = yt[1][c];
    float dprev = 0.f;
    for(int i=0;i<m;i++){
      float y2 = yt[i+2][c];
      float r = (y2 - 2.f*y1 + y0)*Kc;
      float d = (i == 0) ? r*0.25f : (r - dprev)*cp[i];
      dp[i][c] = d; dprev = d;
      y0 = y1; y1 = y2;
    }
    float* Mb = M + (size_t)b*LK*NN + c;
    float xv = dp[m-1][c];
    Mb[(size_t)m*NN] = xv;
    for(int i=m-2;i>=0;i--){
      xv = dp[i][c] - cp[i]*xv;
      Mb[(size_t)(i+1)*NN] = xv;
    }
    Mb[0] = 0.f;
    Mb[(size_t)(LK-1)*NN] = 0.f;
  }
}

// ---------------- spline pair evaluation (compile-time LK; shared coefficients for 2 adjacent channels) ----------------
template<int LK>
__device__ __forceinline__ void spline_pair(const float* __restrict__ y, const float* __restrict__ M,
    int l, int b, int c0, bool ok0, bool ok1, float& v0, float& v1){
  const float hh = 1.f/(LK-1);
  float q = (float)l * (1.f/(LL-1));
  int idx = (int)floorf(q*(LK-1));
  if(idx > LK-2) idx = LK-2;
  float s = q - idx*hh;
  float u = hh - s;
  const float hh6 = hh*hh/6.f;
  const float i6h = 1.f/(6.f*hh);
  const float ih = 1.f/hh;
  float cu = u*u*u, cs = s*s*s;
  float uh = u*ih, sh = s*ih;
  const float* yb = y + ((size_t)b*LK + idx)*NN + c0;
  const float* Mb = M + ((size_t)b*LK + idx)*NN + c0;
  v0 = 0.f; v1 = 0.f;
  if(ok0){
    float yi = yb[0], yi1 = yb[NN], M0 = Mb[0], M1 = Mb[NN];
    v0 = (M0*cu + M1*cs)*i6h + (yi - M0*hh6)*uh + (yi1 - M1*hh6)*sh;
  }
  if(ok1){
    float yi = yb[1], yi1 = yb[NN+1], M0 = Mb[1], M1 = Mb[NN+1];
    v1 = (M0*cu + M1*cs)*i6h + (yi - M0*hh6)*uh + (yi1 - M1*hh6)*sh;
  }
}

// ---------------- K8: conv2 (coalesced wT, 4 j per block) ----------------
__global__ __launch_bounds__(512) void k_conv2(const float* __restrict__ tt, const float* __restrict__ wT,
                                               const float* __restrict__ bias, float* __restrict__ t2){
  __shared__ alignas(16) float ts[16*NN];
  int jt = blockIdx.x, b = blockIdx.y;
  int tid = threadIdx.x;
  int o = tid & 127, jj = tid >> 7;
  for(int i=tid;i<16*NN;i+=512)
    ts[i] = tt[((size_t)b*64 + jt*16)*NN + i];
  __syncthreads();
  float a0 = 0.f, a1 = 0.f, a2 = 0.f, a3 = 0.f;
  for(int ci=0;ci<NN;ci++){
    const float* wc = wT + (size_t)(ci*4)*NN + o;
    const float* tc2 = ts + (jj*4)*NN + ci;
    a0 = fmaf(tc2[0*NN], wc[0*NN], a0);
    a1 = fmaf(tc2[1*NN], wc[1*NN], a1);
    a2 = fmaf(tc2[2*NN], wc[2*NN], a2);
    a3 = fmaf(tc2[3*NN], wc[3*NN], a3);
  }
  int j = jt*4 + jj;
  t2[((size_t)b*NN + o)*16 + j] = (a0 + a1) + (a2 + a3) + bias[o];
}

// ---------------- K_h12: fully-MFMA fused stage-1 conv + GELU + stage-2 conv + residual ----------------
// Planar Au layout (4 planes of uint4/px, plane stride PBQ uints, bases on banks {0,8,16,24}).
// Phase A: a-tile as bf16 pairs. Phase B1: 1 thread builds 2 adjacent px via aligned u32 pair reads
// (9 LDS reads/px vs 27 u16). Phase B2: mfma(W,patch)+gelu -> b64 writeback. Phase C: stage-2 MFMA.
#define PBQ 1416
__global__ __launch_bounds__(256, 5) void k_h12(const float* __restrict__ a0,
    const float* __restrict__ y64, const float* __restrict__ M64,
    const float* __restrict__ y16, const float* __restrict__ M16,
    const uint4* __restrict__ bwpk, const uint4* __restrict__ awpk,
    const float* __restrict__ bsum, const float* __restrict__ vb0,
    const float* __restrict__ vb1, unsigned short* __restrict__ cobf){
  __shared__ alignas(16) unsigned short AsBf[3*12*36];   // bf16 a-tile [ch][yy][xx]
  __shared__ alignas(16) unsigned Au[4*PBQ];             // planar patch/h1 buffer
  int tid = threadIdx.x;
  int l0 = blockIdx.x*8, n0 = blockIdx.y*32, b = blockIdx.z;
  int lane = tid & 63, wv = tid >> 6;
  int colB = lane & 15, qg = lane >> 4;

  // ---- Phase A: stage a-tile as bf16 pairs (648 uint slots) ----
  for(int i=tid; i<648; i+=256){
    int ch = i/216, rem = i%216, yy = rem/18, xxp = rem%18;
    int xx = xxp*2;
    int gl = l0 + yy - 2, gn0 = n0 + xx - 2;
    bool okl = (gl >= 0 && gl < LL);
    bool ok0 = okl && ((unsigned)gn0 < (unsigned)NN);
    bool ok1 = okl && ((unsigned)(gn0+1) < (unsigned)NN);
    float v0 = 0.f, v1 = 0.f;
    if(ch == 0){
      if(ok0) v0 = a0[((size_t)b*LL + gl)*NN + gn0];
      if(ok1) v1 = a0[((size_t)b*LL + gl)*NN + gn0 + 1];
    } else if(okl){
      if(ch == 1) spline_pair<64>(y64, M64, gl, b, gn0, ok0, ok1, v0, v1);
      else        spline_pair<16>(y16, M16, gl, b, gn0, ok0, ok1, v0, v1);
    }
    *(unsigned*)&AsBf[i*2] = pbf2(v0, v1);
  }

  // ---- pre-packed stage-1 weight fragments + biases ----
  union U4 { uint4 q; frag_ab f; };
  U4 bw0, bw1;
  bw0.q = bwpk[colB*4 + qg];
  bw1.q = bwpk[(colB + 16)*4 + qg];
  float brA[4], brB[4];
  #pragma unroll
  for(int r=0;r<4;r++){ brA[r] = bsum[qg*4 + r]; brB[r] = bsum[16 + qg*4 + r]; }
  __syncthreads();

  // ---- Phase B1: build patches, 1 thread per 2 adjacent px (aligned u32 pair reads) ----
  {
    const unsigned* Uv = (const unsigned*)AsBf;   // u32 view: [3][12][18]
    if(tid < 176){
      if(tid < 170){
        int yy = tid/17, xp = tid - yy*17;        // px pair (yy, 2xp), (yy, 2xp+1)
        unsigned g[3][3][2];
        #pragma unroll
        for(int ci=0;ci<3;ci++)
          #pragma unroll
          for(int dy=0;dy<3;dy++){
            int base = (ci*12 + yy + dy)*18 + xp;
            g[ci][dy][0] = Uv[base];
            g[ci][dy][1] = Uv[base+1];
          }
        int px0 = yy*34 + 2*xp;
        uint4 pq;
        // px0: cols c0..c2 per row
        pq.x = g[0][0][0];
        pq.y = (g[0][0][1]&0xffffu) | (g[0][1][0]<<16);
        pq.z = (g[0][1][0]>>16) | (g[0][1][1]<<16);
        pq.w = g[0][2][0];
        *(uint4*)&Au[0*PBQ + px0*4] = pq;
        pq.x = (g[0][2][1]&0xffffu) | (g[1][0][0]<<16);
        pq.y = (g[1][0][0]>>16) | (g[1][0][1]<<16);
        pq.z = g[1][1][0];
        pq.w = (g[1][1][1]&0xffffu) | (g[1][2][0]<<16);
        *(uint4*)&Au[1*PBQ + px0*4] = pq;
        pq.x = (g[1][2][0]>>16) | (g[1][2][1]<<16);
        pq.y = g[2][0][0];
        pq.z = (g[2][0][1]&0xffffu) | (g[2][1][0]<<16);
        pq.w = (g[2][1][0]>>16) | (g[2][1][1]<<16);
        *(uint4*)&Au[2*PBQ + px0*4] = pq;
        pq.x = g[2][2][0];
        pq.y = g[2][2][1]&0xffffu;
        pq.z = 0u; pq.w = 0u;
        *(uint4*)&Au[3*PBQ + px0*4] = pq;
        // px1: cols c1..c3 per row
        int px1 = px0 + 1;
        pq.x = (g[0][0][0]>>16) | (g[0][0][1]<<16);
        pq.y = (g[0][0][1]>>16) | (g[0][1][0]&0xffff0000u);
        pq.z = g[0][1][1];
        pq.w = (g[0][2][0]>>16) | (g[0][2][1]<<16);
        *(uint4*)&Au[0*PBQ + px1*4] = pq;
        pq.x = (g[0][2][1]>>16) | (g[1][0][0]&0xffff0000u);
        pq.y = g[1][0][1];
        pq.z = (g[1][1][0]>>16) | (g[1][1][1]<<16);
        pq.w = (g[1][1][1]>>16) | (g[1][2][0]&0xffff0000u);
        *(uint4*)&Au[1*PBQ + px1*4] = pq;
        pq.x = g[1][2][1];
        pq.y = (g[2][0][0]>>16) | (g[2][0][1]<<16);
        pq.z = (g[2][0][1]>>16) | (g[2][1][0]&0xffff0000u);
        pq.w = g[2][1][1];
        *(uint4*)&Au[2*PBQ + px1*4] = pq;
        pq.x = (g[2][2][0]>>16) | (g[2][2][1]<<16);
        pq.y = g[2][2][1]>>16;
        pq.z = 0u; pq.w = 0u;
        *(uint4*)&Au[3*PBQ + px1*4] = pq;
      } else {
        int px = 340 + (tid-170)*2;
        uint4 z = make_uint4(0u,0u,0u,0u);
        #pragma unroll
        for(int q=0;q<4;q++){
          *(uint4*)&Au[q*PBQ + px*4]     = z;
          *(uint4*)&Au[q*PBQ + (px+1)*4] = z;
        }
      }
    }
  }
  __syncthreads();

  // ---- Phase B2: stage-1 MFMA (A=weights, B=patches), gelu, b64 writeback ----
  unsigned short* h1h = (unsigned short*)Au;
  frag_cd zac = {0.f, 0.f, 0.f, 0.f};
  for(int t = wv; t < 22; t += 4){
    int px = t*16 + colB;
    U4 av;
    av.q = *(const uint4*)&Au[qg*PBQ + px*4];
    frag_cd d0 = __builtin_amdgcn_mfma_f32_16x16x32_bf16(bw0.f, av.f, zac, 0, 0, 0);
    frag_cd d1 = __builtin_amdgcn_mfma_f32_16x16x32_bf16(bw1.f, av.f, zac, 0, 0, 0);
    unsigned u0 = pbf2(gelu_fast(d0[0] + brA[0]), gelu_fast(d0[1] + brA[1]));
    unsigned u1 = pbf2(gelu_fast(d0[2] + brA[2]), gelu_fast(d0[3] + brA[3]));
    unsigned u2 = pbf2(gelu_fast(d1[0] + brB[0]), gelu_fast(d1[1] + brB[1]));
    unsigned u3 = pbf2(gelu_fast(d1[2] + brB[2]), gelu_fast(d1[3] + brB[3]));
    int lo = (qg >> 1)*PBQ + px*4 + (qg & 1)*2;
    *(uint2*)&Au[lo]           = make_uint2(u0, u1);
    *(uint2*)&Au[2*PBQ + lo]   = make_uint2(u2, u3);
  }
  __syncthreads();

  // ---- Phase B3: zero h1 at invalid borders ----
  if(n0 == 0){
    for(int i=tid;i<10*32;i+=256){ int yy=i>>5, ch=i&31;
      h1h[((ch>>3)*PBQ + (yy*34)*4)*2 + (ch&7)] = 0; }
  }
  if(n0 == 96){
    for(int i=tid;i<10*32;i+=256){ int yy=i>>5, ch=i&31;
      h1h[((ch>>3)*PBQ + (yy*34+33)*4)*2 + (ch&7)] = 0; }
  }
  if(l0 == 0){
    for(int i=tid;i<34*32;i+=256){ int xx=i>>5, ch=i&31;
      h1h[((ch>>3)*PBQ + xx*4)*2 + (ch&7)] = 0; }
  }
  if(l0 == 760){
    for(int i=tid;i<34*32;i+=256){ int xx=i>>5, ch=i&31;
      h1h[((ch>>3)*PBQ + (9*34+xx)*4)*2 + (ch&7)] = 0; }
  }

  // ---- pre-packed stage-2 weight fragments ----
  U4 aw[9];
  #pragma unroll
  for(int tap=0; tap<9; tap++) aw[tap].q = awpk[tap*4 + qg];
  float vbsum = vb0[0] + vb1[0];
  __syncthreads();

  // ---- Phase C: stage-2 conv via MFMA, B-frags direct from planar h1 ----
  frag_cd cacc[4] = {};
  int baseoff[4];
  #pragma unroll
  for(int tt=0; tt<4; tt++){
    int px = (wv*4 + tt)*16 + colB;
    int yy = px >> 5, xx = px & 31;
    baseoff[tt] = qg*PBQ + (yy*34 + xx)*4;
  }
  #pragma unroll
  for(int dy=0; dy<3; dy++)
    #pragma unroll
    for(int dx=0; dx<3; dx++){
      int tap = dy*3 + dx;
      int off = (dy*34 + dx)*4;
      #pragma unroll
      for(int tt=0; tt<4; tt++){
        U4 bv;
        bv.q = *(const uint4*)&Au[baseoff[tt] + off];
        cacc[tt] = __builtin_amdgcn_mfma_f32_16x16x32_bf16(aw[tap].f, bv.f, cacc[tt], 0, 0, 0);
      }
    }
  if(lane < 16){
    #pragma unroll
    for(int tt=0; tt<4; tt++){
      int px = (wv*4 + tt)*16 + lane;
      int yy = px >> 5, xx = px & 31;
      size_t idx = ((size_t)b*LL + l0 + yy)*NN + n0 + xx;
      cobf[idx] = bf16b(cacc[tt][0] + vbsum + a0[idx]);
    }
  }
}

// ---------------- K15: GEMM2, A from bf16 co, B pre-packed + de-normalize ----------------
__global__ __launch_bounds__(256) void k_gemm2(const unsigned short* __restrict__ cobf,
    const unsigned* __restrict__ ldwbf, const float* __restrict__ ldb,
    const float* __restrict__ sp, const float* __restrict__ s2p,
    float* __restrict__ out){
  __shared__ unsigned Asu[64*20];
  __shared__ unsigned Bsu[32*20];
  int tid = threadIdx.x;
  int row0 = blockIdx.x*64, p0 = blockIdx.y*32;
  int b = row0 >> 7, n0 = row0 & 127;
  int lane = tid & 63, wv = tid >> 6;
  frag_cd acc[2] = {};
  int an = tid & 63, akq = (tid >> 6)*8;
  int btk = tid & 15, blc = tid >> 4;
  unsigned ra[4], rbq[2];
  #pragma unroll
  for(int u=0;u<4;u++){
    unsigned lo = cobf[((size_t)b*LL + akq + 2*u)*NN + n0 + an];
    unsigned hi = cobf[((size_t)b*LL + akq + 2*u + 1)*NN + n0 + an];
    ra[u] = lo | (hi << 16);
  }
  #pragma unroll
  for(int u=0;u<2;u++)
    rbq[u] = ldwbf[(size_t)(p0 + blc + 16*u)*384 + btk];
  int fr = wv*16 + (lane & 15);
  int fq = (lane >> 4)*4;
  for(int k0=0;k0<LL;k0+=32){
    *(uint4*)&Asu[an*20 + (akq>>1)] = make_uint4(ra[0], ra[1], ra[2], ra[3]);
    #pragma unroll
    for(int p=0;p<2;p++) Bsu[(blc + 16*p)*20 + btk] = rbq[p];
    __syncthreads();
    if(k0 + 32 < LL){
      #pragma unroll
      for(int u=0;u<4;u++){
        unsigned lo = cobf[((size_t)b*LL + k0 + 32 + akq + 2*u)*NN + n0 + an];
        unsigned hi = cobf[((size_t)b*LL + k0 + 32 + akq + 2*u + 1)*NN + n0 + an];
        ra[u] = lo | (hi << 16);
      }
      #pragma unroll
      for(int u=0;u<2;u++)
        rbq[u] = ldwbf[(size_t)(p0 + blc + 16*u)*384 + ((k0 + 32) >> 1) + btk];
    }
    frag_ab af = *(const frag_ab*)&Asu[fr*20 + fq];
    #pragma unroll
    for(int nt=0;nt<2;nt++){
      frag_ab bf = *(const frag_ab*)&Bsu[(nt*16 + (lane & 15))*20 + fq];
      acc[nt] = __builtin_amdgcn_mfma_f32_16x16x32_bf16(af, bf, acc[nt], 0, 0, 0);
    }
    __syncthreads();
  }
  int col = lane & 15, quad = lane >> 4;
  float mu_r[4], sd_r[4];
  #pragma unroll
  for(int r=0;r<4;r++){
    int row = row0 + wv*16 + quad*4 + r;
    float ssum = 0.f, s2sum = 0.f;
    #pragma unroll
    for(int tq=0;tq<4;tq++){ ssum += sp[tq*2048 + row]; s2sum += s2p[tq*2048 + row]; }
    float mu = ssum*(1.f/512.f);
    float var = fmaxf(s2sum*(1.f/512.f) - mu*mu, 0.f);
    mu_r[r] = mu; sd_r[r] = sqrtf(var + EPSF);
  }
  #pragma unroll
  for(int nt=0;nt<2;nt++){
    int p = p0 + nt*16 + col;
    float lb = ldb[p];
    float4 st;
    st.x = (acc[nt][0] + lb)*sd_r[0] + mu_r[0];
    st.y = (acc[nt][1] + lb)*sd_r[1] + mu_r[1];
    st.z = (acc[nt][2] + lb)*sd_r[2] + mu_r[2];
    st.w = (acc[nt][3] + lb)*sd_r[3] + mu_r[3];
    *(float4*)&out[((size_t)b*PREDN + p)*NN + n0 + wv*16 + quad*4] = st;
  }
}

extern "C" void kernel_launch(void* const* d_in, const int* in_sizes, int n_in,
                              void* d_out, int out_size, void* d_ws, size_t ws_size,
                              hipStream_t stream){
  (void)in_sizes; (void)n_in; (void)out_size; (void)ws_size;
  const float* batch_x = (const float*)d_in[0];
  const float* le_w  = (const float*)d_in[4];
  const float* le_b  = (const float*)d_in[5];
  const float* c1_w  = (const float*)d_in[6];
  const float* c1_b  = (const float*)d_in[7];
  const float* bn1_g = (const float*)d_in[8];
  const float* bn1_b = (const float*)d_in[9];
  const float* c2_w  = (const float*)d_in[10];
  const float* c2_b  = (const float*)d_in[11];
  const float* bn2_g = (const float*)d_in[12];
  const float* bn2_b = (const float*)d_in[13];
  const float* i1_w0 = (const float*)d_in[14];
  const float* i1_b0 = (const float*)d_in[15];
  const float* i1_w1 = (const float*)d_in[16];
  const float* i1_b1 = (const float*)d_in[17];
  const float* i2_w0 = (const float*)d_in[18];
  const float* i2_b0 = (const float*)d_in[19];
  const float* i2_w1 = (const float*)d_in[20];
  const float* i2_b1 = (const float*)d_in[21];
  const float* ld_w  = (const float*)d_in[22];
  const float* ld_b  = (const float*)d_in[23];
  float* out = (float*)d_out;

  float* ws   = (float*)d_ws;
  float* sp   = ws;                          // 8192
  float* s2p  = sp + 8192;                   // 8192
  float* wT1  = s2p + 8192;                  // 196,608
  float* wT2  = wT1 + 196608;                // 65,536
  float* x    = wT2 + 65536;                 // 1,572,864
  float* a0   = x + (size_t)BB*NN*LL;        // 1,572,864
  float* t1   = a0 + (size_t)BB*LL*NN;       // 131,072
  float* t1t  = t1 + (size_t)BB*NN*64;       // 131,072
  float* sc1  = t1t + (size_t)BB*64*NN;      // 128
  float* sh1  = sc1 + NN;                    // 128
  float* Msp1 = sh1 + NN;                    // 131,072
  float* t2   = Msp1 + (size_t)BB*64*NN;     // 32,768
  float* t2t  = t2 + (size_t)BB*NN*16;       // 32,768
  float* sc2  = t2t + (size_t)BB*16*NN;      // 128
  float* sh2  = sc2 + NN;                    // 128
  float* Msp2 = sh2 + NN;                    // 32,768
  float* muv  = Msp2 + (size_t)BB*16*NN;     // 2048
  float* rsv  = muv + 2048;                  // 2048
  float* fB1  = rsv + 2048;
  unsigned short* xbf = (unsigned short*)fB1;       // 1,048,576 ushorts = 524,288 floats
  float* fB2  = fB1 + 524288;
  unsigned* lewbf = (unsigned*)fB2;                 // 196,608 uints
  float* fB3  = fB2 + 196608;
  unsigned* ldwbf = (unsigned*)fB3;                 // 98,304 uints
  float* fB4  = fB3 + 98304;
  uint4* bwpk = (uint4*)fB4;                        // 128 uint4 = 512 floats
  float* fB5  = fB4 + 512;
  uint4* awpk = (uint4*)fB5;                        // 36 uint4 = 144 floats
  float* fB6  = fB5 + 144;
  float* bsum = fB6;                                // 32
  float* fB7  = fB6 + 32;
  unsigned short* cobf = (unsigned short*)fB7;      // 1,572,864 ushorts = 786,432 floats

  k_pre<<<513, 128, 0, stream>>>(batch_x, i2_w0, i2_w1, c1_w, c2_w,
                                 i1_w0, i1_w1, i1_b0, i1_b1, le_w, ld_w,
                                 sp, s2p, wT1, wT2, bwpk, awpk, bsum, lewbf, ldwbf);
  k_musd<<<8, 256, 0, stream>>>(sp, s2p, muv, rsv);
  k_xbf<<<512, 256, 0, stream>>>(batch_x, muv, rsv, xbf);
  k_gemm1<<<dim3(32,12), 256, 0, stream>>>(xbf, lewbf, le_b, x, a0);
  k_conv1<<<dim3(16,BB), 512, 0, stream>>>(x, wT1, c1_b, t1);
  k_bnstats<<<NN, 256, 0, stream>>>(t1, bn1_g, bn1_b, BB, 64, sc1, sh1);
  k_bnspl<64><<<BB, 256, 0, stream>>>(t1, sc1, sh1, t1t, Msp1);
  k_conv2<<<dim3(4,BB), 512, 0, stream>>>(t1t, wT2, c2_b, t2);
  k_bnstats<<<NN, 256, 0, stream>>>(t2, bn2_g, bn2_b, BB, 16, sc2, sh2);
  k_bnspl<16><<<BB, 256, 0, stream>>>(t2, sc2, sh2, t2t, Msp2);
  k_h12<<<dim3(96,4,BB), 256, 0, stream>>>(a0, t1t, Msp1, t2t, Msp2,
                                           bwpk, awpk, bsum, i2_b0, i2_b1, cobf);
  k_gemm2<<<dim3(32,8), 256, 0, stream>>>(cobf, ldwbf, ld_b, sp, s2p, out);
}